// Round 1
// 365.996 us; speedup vs baseline: 1.0487x; 1.0487x over previous
//
#include <hip/hip_runtime.h>
#include <math.h>

#define B 8
#define N 512
#define D 128
#define H 4
#define TOK (B*N)   // 4096

typedef __attribute__((ext_vector_type(8))) short bfrag;   // 8 bf16 (4 VGPRs)
typedef __attribute__((ext_vector_type(4))) float facc;    // 4 fp32 acc
typedef unsigned short u16;
typedef unsigned int u32;

__device__ __forceinline__ float lrelu(float x){ return x > 0.f ? x : 0.01f*x; }
__device__ __forceinline__ u16 f2bf(float f){
  u32 u = __float_as_uint(f);
  u += 0x7fffu + ((u >> 16) & 1u);     // RTNE
  return (u16)(u >> 16);
}
__device__ __forceinline__ u32 pk2(float a, float b){
  return (u32)f2bf(a) | ((u32)f2bf(b) << 16);
}

// LDS row stride for bf16 tiles: 72 u16 (16B-aligned, breaks pow2 banks)
#define LS 72

// ---------------- unified prep: adj bitmasks + all weight bf16-transposes -----
// mask is consumed only as bits by pv32: pack both orientations, drop adjT ints.
__global__ void prep_kernel(const int* __restrict__ adj,
    u32* __restrict__ mbits, u32* __restrict__ mtbits,
    const float* s0, const float* s1_, const float* s2_, const float* s3,
    const float* s4, const float* s5, const float* s6, const float* s7,
    const float* s8,
    u16* d0, u16* d1, u16* d2, u16* d3, u16* d4, u16* d5, u16* d6, u16* d7, u16* d8)
{
  __shared__ float ftile[32][33];
  const int tid = threadIdx.x;
  const int tx = tid & 31, ty = tid >> 5;
  if (blockIdx.x < 128){
    int* it = (int*)&ftile[0][0];
    const int b = blockIdx.x >> 4, i0 = (blockIdx.x & 15)*32;
    const int lane6 = tid & 63;
    for (int j0 = 0; j0 < N; j0 += 32){
      for (int r = ty; r < 32; r += 8)
        it[r*33 + tx] = adj[((size_t)b*N + i0 + r)*N + j0 + tx];
      __syncthreads();
      #pragma unroll
      for (int half = 0; half < 4; ++half){
        const int r = half*8 + (tid >> 5);     // row within 32x32 tile
        const int c = tid & 31;
        // forward: mask[i0+r][j0 + 0..31] bits
        unsigned long long bl = __ballot(it[r*33 + c] > 0);
        if (lane6 == 0 || lane6 == 32)
          mbits[((size_t)b*N + i0 + r)*16 + (j0>>5)] = (u32)(lane6 ? (bl >> 32) : bl);
        // transposed: maskT[j0+r][i0 + 0..31] bits  (bit c = adj[i0+c][j0+r])
        unsigned long long bt = __ballot(it[c*33 + r] > 0);
        if (lane6 == 0 || lane6 == 32)
          mtbits[((size_t)b*N + j0 + r)*16 + (i0>>5)] = (u32)(lane6 ? (bt >> 32) : bt);
      }
      __syncthreads();
    }
  } else {
    const float* srcs[9] = {s0,s1_,s2_,s3,s4,s5,s6,s7,s8};
    u16* dsts[9] = {d0,d1,d2,d3,d4,d5,d6,d7,d8};
    const int Ks[9] = {32,128,128,256,128,256,128,128,512};
    const int Ns[9] = {128,128,256,128,256,128,128,128,128};
    const int zs[9] = {1,1,1,1,1,1,24,2,6};
    for (int job = (int)blockIdx.x - 128; job < 948; job += 384){
      int m = 0, base = 0;
      for (; m < 9; ++m){
        int cnt = (Ks[m]>>5)*(Ns[m]>>5)*zs[m];
        if (job < base + cnt) break;
        base += cnt;
      }
      const int rem = job - base;
      const int tn = Ns[m] >> 5;
      const int per = (Ks[m] >> 5)*tn;
      const int z = rem / per, t = rem % per;
      const int k0 = (t / tn)*32, n0 = (t % tn)*32;
      const float* src = srcs[m] + (size_t)z*Ks[m]*Ns[m];
      u16* dst = dsts[m] + (size_t)z*Ks[m]*Ns[m];
      __syncthreads();
      for (int r = ty; r < 32; r += 8)
        ftile[r][tx] = src[(size_t)(k0+r)*Ns[m] + n0 + tx];
      __syncthreads();
      for (int r = ty; r < 32; r += 8)
        dst[(size_t)(n0+r)*Ks[m] + k0 + tx] = f2bf(ftile[tx][r]);
    }
  }
}

// ---- B staging helpers (used by gemm32 / wh32) -------------------------------
__device__ __forceinline__ void stageB64(const u16* __restrict__ BTn, int ldb,
                                         int k0, u16* Bs, int tid){
  const int n = tid >> 1, part = tid & 1;
  const u16* wp = BTn + (size_t)n*ldb + k0 + part*32;
  uint4 w0 = *(const uint4*)wp,      w1 = *(const uint4*)(wp+8);
  uint4 w2 = *(const uint4*)(wp+16), w3 = *(const uint4*)(wp+24);
  *(uint4*)&Bs[n*LS + part*32]      = w0;
  *(uint4*)&Bs[n*LS + part*32 + 8]  = w1;
  *(uint4*)&Bs[n*LS + part*32 + 16] = w2;
  *(uint4*)&Bs[n*LS + part*32 + 24] = w3;
}
__device__ __forceinline__ void stageB32(const u16* __restrict__ BTn, int ldb,
                                         int k0, u16* Bs, int tid){
  const int n = tid >> 1, part = tid & 1;
  const u16* wp = BTn + (size_t)n*ldb + k0 + part*16;
  uint4 w0 = *(const uint4*)wp, w1 = *(const uint4*)(wp+8);
  *(uint4*)&Bs[n*LS + part*16]     = w0;
  *(uint4*)&Bs[n*LS + part*16 + 8] = w1;
}

// ---- 16x16x32 core, wave = 16 rows x 64 cols (gemm32 / wh32) -----------------
__device__ __forceinline__ void mfma64(const u16* As, const u16* Bs,
                                       facc acc[4], int r0, int c0,
                                       int quad, int l15){
  #pragma unroll
  for (int kk = 0; kk < 2; ++kk){
    bfrag af = *(const bfrag*)&As[(r0 + l15)*LS + kk*32 + quad*8];
    #pragma unroll
    for (int g = 0; g < 4; ++g){
      bfrag bf = *(const bfrag*)&Bs[(c0 + g*16 + l15)*LS + kk*32 + quad*8];
      acc[g] = __builtin_amdgcn_mfma_f32_16x16x32_bf16(af, bf, acc[g], 0,0,0);
    }
  }
}
__device__ __forceinline__ void mfma32(const u16* As, const u16* Bs,
                                       facc acc[4], int r0, int c0,
                                       int quad, int l15){
  bfrag af = *(const bfrag*)&As[(r0 + l15)*LS + quad*8];
  #pragma unroll
  for (int g = 0; g < 4; ++g){
    bfrag bf = *(const bfrag*)&Bs[(c0 + g*16 + l15)*LS + quad*8];
    acc[g] = __builtin_amdgcn_mfma_f32_16x16x32_bf16(af, bf, acc[g], 0,0,0);
  }
}

// ---- 16x16x32 core, wave = 32 rows x 32 cols (pv32 / gemm32b) ----------------
__device__ __forceinline__ void mfma64w(const u16* As, const u16* Bs,
                                        facc acc[2][2], int c0,
                                        int quad, int l15){
  #pragma unroll
  for (int kk = 0; kk < 2; ++kk){
    bfrag af0 = *(const bfrag*)&As[(l15)*LS      + kk*32 + quad*8];
    bfrag af1 = *(const bfrag*)&As[(16 + l15)*LS + kk*32 + quad*8];
    #pragma unroll
    for (int f = 0; f < 2; ++f){
      bfrag bf = *(const bfrag*)&Bs[(c0 + f*16 + l15)*LS + kk*32 + quad*8];
      acc[0][f] = __builtin_amdgcn_mfma_f32_16x16x32_bf16(af0, bf, acc[0][f], 0,0,0);
      acc[1][f] = __builtin_amdgcn_mfma_f32_16x16x32_bf16(af1, bf, acc[1][f], 0,0,0);
    }
  }
}

// ---------------- generic 32x128-tile GEMM, fp32 A (FEL; old core) ------------
template<int ACT, int FIN>
__global__ __launch_bounds__(256) void gemm32(
    const float* __restrict__ A, int lda, int K,
    const u16* __restrict__ BT, const float* __restrict__ bias,
    const float* __restrict__ res, float* __restrict__ out, int ldo)
{
  const int tid = threadIdx.x;
  const int t0 = blockIdx.x * 32;
  const int n0 = blockIdx.y * 128;
  __shared__ __align__(16) u16 As[32*LS];
  __shared__ __align__(16) u16 Bs[128*LS];
  __shared__ float scrS[4][16], scrQ[4][16];
  const int wave = tid >> 6, lane = tid & 63, quad = lane >> 4, l15 = lane & 15;
  const int r0 = (wave & 1)*16, c0 = (wave >> 1)*64;
  facc acc[4];
  #pragma unroll
  for (int g = 0; g < 4; ++g) acc[g] = (facc){0.f,0.f,0.f,0.f};
  const u16* BTn = BT + (size_t)n0*K;

  int k0 = 0;
  for (; k0 + 64 <= K; k0 += 64){
    { const int row = tid >> 3, ko = tid & 7;
      const float* ap = A + (size_t)(t0+row)*lda + k0 + ko*8;
      float4 a0 = *(const float4*)ap, a1 = *(const float4*)(ap+4);
      uint4 u = { pk2(a0.x,a0.y), pk2(a0.z,a0.w), pk2(a1.x,a1.y), pk2(a1.z,a1.w) };
      *(uint4*)&As[row*LS + ko*8] = u;
    }
    stageB64(BTn, K, k0, Bs, tid);
    __syncthreads();
    mfma64(As, Bs, acc, r0, c0, quad, l15);
    __syncthreads();
  }
  if (k0 < K){   // 32-wide remainder (K=32 case)
    { const int row = tid >> 3, ko = tid & 7;
      float4 a0 = *(const float4*)(A + (size_t)(t0+row)*lda + k0 + ko*4);
      uint2 u = { pk2(a0.x,a0.y), pk2(a0.z,a0.w) };
      *(uint2*)&As[row*LS + ko*4] = u;
    }
    stageB32(BTn, K, k0, Bs, tid);
    __syncthreads();
    mfma32(As, Bs, acc, r0, c0, quad, l15);
    __syncthreads();
  }

  float bv[4];
  #pragma unroll
  for (int g = 0; g < 4; ++g) bv[g] = bias[n0 + c0 + g*16 + l15];

  if (FIN == 0){
    #pragma unroll
    for (int g = 0; g < 4; ++g){
      const int c = n0 + c0 + g*16 + l15;
      #pragma unroll
      for (int q = 0; q < 4; ++q){
        const int rq = t0 + r0 + quad*4 + q;
        float xv = acc[g][q] + bv[g];
        if (ACT) xv = lrelu(xv);
        out[(size_t)rq*ldo + c] = xv;
      }
    }
  } else {
    float v[4][4], s[4] = {0,0,0,0}, sq[4] = {0,0,0,0};
    #pragma unroll
    for (int g = 0; g < 4; ++g){
      const int c = c0 + g*16 + l15;
      #pragma unroll
      for (int q = 0; q < 4; ++q){
        const int rq = t0 + r0 + quad*4 + q;
        float xv = acc[g][q] + bv[g];
        if (ACT) xv = lrelu(xv);
        xv += res[(size_t)rq*128 + c];
        v[g][q] = xv; s[q] += xv; sq[q] += xv*xv;
      }
    }
    #pragma unroll
    for (int m = 1; m < 16; m <<= 1){
      #pragma unroll
      for (int q = 0; q < 4; ++q){ s[q] += __shfl_xor(s[q], m, 64); sq[q] += __shfl_xor(sq[q], m, 64); }
    }
    if (l15 == 0){
      #pragma unroll
      for (int q = 0; q < 4; ++q){ scrS[wave][quad*4+q] = s[q]; scrQ[wave][quad*4+q] = sq[q]; }
    }
    __syncthreads();
    #pragma unroll
    for (int q = 0; q < 4; ++q){
      const int rq = t0 + r0 + quad*4 + q;
      const float fs = s[q] + scrS[wave^2][quad*4+q];
      const float fq = sq[q] + scrQ[wave^2][quad*4+q];
      const float mean = fs*(1.f/D);
      const float rstd = rsqrtf(fq*(1.f/D) - mean*mean + 1e-5f);
      #pragma unroll
      for (int g = 0; g < 4; ++g)
        out[(size_t)rq*128 + c0 + g*16 + l15] = (v[g][q] - mean)*rstd;
    }
  }
}

// ---------------- resh: bf16-A GEMM + bias + residual + LN --------------------
// NEW: double-buffered LDS + register prefetch, ONE barrier per K-step.
__global__ __launch_bounds__(256) void gemm32b(
    const u16* __restrict__ A, int lda, int K,
    const u16* __restrict__ BT, const float* __restrict__ bias,
    const float* __restrict__ res, float* __restrict__ out)
{
  const int tid = threadIdx.x;
  const int t0 = blockIdx.x * 32;
  __shared__ __align__(16) u16 As[2][32*LS];
  __shared__ __align__(16) u16 Bs[2][128*LS];
  __shared__ float scrS[4][32], scrQ[4][32];
  const int wave = tid >> 6, lane = tid & 63, quad = lane >> 4, l15 = lane & 15;
  const int c0 = wave*32;
  facc acc[2][2];
  #pragma unroll
  for (int rg = 0; rg < 2; ++rg)
    #pragma unroll
    for (int f = 0; f < 2; ++f) acc[rg][f] = (facc){0.f,0.f,0.f,0.f};

  const int arow = tid >> 3, ako = tid & 7;
  const u16* aptr = A + (size_t)(t0+arow)*lda + ako*8;
  const int bn = tid >> 1, bpart = tid & 1;
  const u16* bptr = BT + (size_t)bn*K + bpart*32;

  // prologue: stage K-tile 0
  { uint4 ga = *(const uint4*)aptr;
    uint4 g0 = *(const uint4*)bptr,      g1 = *(const uint4*)(bptr+8);
    uint4 g2 = *(const uint4*)(bptr+16), g3 = *(const uint4*)(bptr+24);
    *(uint4*)&As[0][arow*LS + ako*8] = ga;
    u16* bp = &Bs[0][bn*LS + bpart*32];
    *(uint4*)bp = g0; *(uint4*)(bp+8) = g1; *(uint4*)(bp+16) = g2; *(uint4*)(bp+24) = g3;
  }
  __syncthreads();

  const int nt = K >> 6;
  for (int k = 0; k < nt - 1; ++k){
    const int cur = k & 1, nxt = cur ^ 1;
    // issue next tile's global loads (latency hides under MFMA below)
    uint4 na = *(const uint4*)(aptr + (k+1)*64);
    const u16* wp = bptr + (k+1)*64;
    uint4 n0 = *(const uint4*)wp,      n1 = *(const uint4*)(wp+8);
    uint4 n2 = *(const uint4*)(wp+16), n3 = *(const uint4*)(wp+24);
    mfma64w(As[cur], Bs[cur], acc, c0, quad, l15);
    *(uint4*)&As[nxt][arow*LS + ako*8] = na;
    { u16* bp = &Bs[nxt][bn*LS + bpart*32];
      *(uint4*)bp = n0; *(uint4*)(bp+8) = n1; *(uint4*)(bp+16) = n2; *(uint4*)(bp+24) = n3; }
    __syncthreads();
  }
  mfma64w(As[(nt-1)&1], Bs[(nt-1)&1], acc, c0, quad, l15);

  float bv[2];
  #pragma unroll
  for (int f = 0; f < 2; ++f) bv[f] = bias[c0 + f*16 + l15];
  float v[2][2][4], s[2][4], sq[2][4];
  #pragma unroll
  for (int rg = 0; rg < 2; ++rg)
    #pragma unroll
    for (int q = 0; q < 4; ++q){ s[rg][q] = 0.f; sq[rg][q] = 0.f; }
  #pragma unroll
  for (int rg = 0; rg < 2; ++rg){
    #pragma unroll
    for (int f = 0; f < 2; ++f){
      const int c = c0 + f*16 + l15;
      #pragma unroll
      for (int q = 0; q < 4; ++q){
        const int rq = t0 + rg*16 + quad*4 + q;
        float xv = acc[rg][f][q] + bv[f] + res[(size_t)rq*128 + c];
        v[rg][f][q] = xv; s[rg][q] += xv; sq[rg][q] += xv*xv;
      }
    }
  }
  #pragma unroll
  for (int m = 1; m < 16; m <<= 1){
    #pragma unroll
    for (int rg = 0; rg < 2; ++rg)
      #pragma unroll
      for (int q = 0; q < 4; ++q){ s[rg][q] += __shfl_xor(s[rg][q], m, 64); sq[rg][q] += __shfl_xor(sq[rg][q], m, 64); }
  }
  if (l15 == 0){
    #pragma unroll
    for (int rg = 0; rg < 2; ++rg)
      #pragma unroll
      for (int q = 0; q < 4; ++q){
        scrS[wave][rg*16 + quad*4 + q] = s[rg][q];
        scrQ[wave][rg*16 + quad*4 + q] = sq[rg][q];
      }
  }
  __syncthreads();
  #pragma unroll
  for (int rg = 0; rg < 2; ++rg){
    #pragma unroll
    for (int q = 0; q < 4; ++q){
      const int row = rg*16 + quad*4 + q;
      const float fs = scrS[0][row] + scrS[1][row] + scrS[2][row] + scrS[3][row];
      const float fq = scrQ[0][row] + scrQ[1][row] + scrQ[2][row] + scrQ[3][row];
      const float mean = fs*(1.f/D);
      const float rstd = rsqrtf(fq*(1.f/D) - mean*mean + 1e-5f);
      #pragma unroll
      for (int f = 0; f < 2; ++f)
        out[(size_t)(t0+row)*128 + c0 + f*16 + l15] = (v[rg][f][q] - mean)*rstd;
    }
  }
}

// ---------------- Wh (32x128 tiles; old core) + fused s1/s2 -------------------
__global__ __launch_bounds__(256) void wh32(
    const float* __restrict__ hin, const u16* __restrict__ WT,
    const float* __restrict__ a, u16* __restrict__ WhT,
    float* __restrict__ s1, float* __restrict__ s2)
{
  const int tid = threadIdx.x;
  const int h  = blockIdx.x >> 7;
  const int t0 = (blockIdx.x & 127) * 32;
  const int b = t0 >> 9, j0 = t0 & (N-1);
  __shared__ __align__(16) u16 As[32*LS];
  __shared__ __align__(16) u16 Bs[128*LS];
  __shared__ float r1s[2][32], r2s[2][32];
  const int wave = tid >> 6, lane = tid & 63, quad = lane >> 4, l15 = lane & 15;
  const int r0 = (wave & 1)*16, c0 = (wave >> 1)*64;
  facc acc[4];
  #pragma unroll
  for (int g = 0; g < 4; ++g) acc[g] = (facc){0.f,0.f,0.f,0.f};
  const u16* BTn = WT + (size_t)h*D*D;

  #pragma unroll
  for (int k0 = 0; k0 < D; k0 += 64){
    { const int row = tid >> 3, ko = tid & 7;
      const float* ap = hin + (size_t)(t0+row)*D + k0 + ko*8;
      float4 a0 = *(const float4*)ap, a1 = *(const float4*)(ap+4);
      uint4 u = { pk2(a0.x,a0.y), pk2(a0.z,a0.w), pk2(a1.x,a1.y), pk2(a1.z,a1.w) };
      *(uint4*)&As[row*LS + ko*8] = u;
    }
    stageB64(BTn, D, k0, Bs, tid);
    __syncthreads();
    mfma64(As, Bs, acc, r0, c0, quad, l15);
    __syncthreads();
  }

  const float* ah = a + (size_t)h*2*D;
  const size_t obase = (size_t)(h*8 + b)*128;
  float p1[4] = {0,0,0,0}, p2[4] = {0,0,0,0};
  #pragma unroll
  for (int g = 0; g < 4; ++g){
    const int c = c0 + g*16 + l15;
    const float a1v = ah[c], a2v = ah[D + c];
    ushort4 wv;
    wv.x = f2bf(acc[g][0]); wv.y = f2bf(acc[g][1]);
    wv.z = f2bf(acc[g][2]); wv.w = f2bf(acc[g][3]);
    *(ushort4*)&WhT[(obase + c)*N + j0 + r0 + quad*4] = wv;
    #pragma unroll
    for (int q = 0; q < 4; ++q){
      p1[q] = fmaf(acc[g][q], a1v, p1[q]);
      p2[q] = fmaf(acc[g][q], a2v, p2[q]);
    }
  }
  #pragma unroll
  for (int m = 1; m < 16; m <<= 1){
    #pragma unroll
    for (int q = 0; q < 4; ++q){ p1[q] += __shfl_xor(p1[q], m, 64); p2[q] += __shfl_xor(p2[q], m, 64); }
  }
  if (l15 == 0){
    #pragma unroll
    for (int q = 0; q < 4; ++q){
      r1s[wave>>1][r0 + quad*4 + q] = p1[q];
      r2s[wave>>1][r0 + quad*4 + q] = p2[q];
    }
  }
  __syncthreads();
  if (tid < 32){
    s1[(size_t)h*TOK + t0 + tid] = r1s[0][tid] + r1s[1][tid];
    s2[(size_t)h*TOK + t0 + tid] = r2s[0][tid] + r2s[1][tid];
  }
}

// ---- score phase helper: 8 cols of one row, bitmask from LDS -----------------
__device__ __forceinline__ float score8(const float* s2s, const unsigned char* mrow,
                                        float s1lr, int k0, int lq, u16* asp){
  float4 sa = *(const float4*)&s2s[k0 + lq*8];
  float4 sb = *(const float4*)&s2s[k0 + lq*8 + 4];
  const u32 mm = mrow[(k0 >> 3) + lq];
  float ss[8] = {sa.x,sa.y,sa.z,sa.w,sb.x,sb.y,sb.z,sb.w};
  float v[8]; float p = 0.f;
  #pragma unroll
  for (int i = 0; i < 8; ++i){
    float e = lrelu(s1lr * ss[i]);
    float ex = ((mm >> i) & 1u) ? __expf(e) : 0.f;
    v[i] = ex; p += ex;
  }
  uint4 u = { pk2(v[0],v[1]), pk2(v[2],v[3]), pk2(v[4],v[5]), pk2(v[6],v[7]) };
  *(uint4*)asp = u;
  return p;
}

// ---------------- fused score+softmax+PV (dbuf, 1 barrier/K-step) -------------
// MODE 0: elu, MODE 1: lrelu. OBF 1: bf16 out, OBF 0: fp32 out.
template<int MODE, int OBF>
__global__ __launch_bounds__(256) void pv32(
    const float* __restrict__ s1, const float* __restrict__ s2,
    const u32* __restrict__ mbits, const u16* __restrict__ WhT,
    void* __restrict__ out_, int ldo, int hcs)
{
  const int tid = threadIdx.x;
  const int h  = blockIdx.x >> 7;
  const int t0 = (blockIdx.x & 127) * 32;
  const int b = t0 >> 9, i0 = t0 & (N-1);
  __shared__ float s2s[N];
  __shared__ float s1s[32], sums[32];
  __shared__ u32 mbs[32*16];                 // 32 rows x 512 bits
  __shared__ __align__(16) u16 As[2][32*LS];
  __shared__ __align__(16) u16 Bs[2][128*LS];

  s2s[tid]     = s2[(size_t)h*TOK + b*N + tid];
  s2s[tid+256] = s2[(size_t)h*TOK + b*N + tid + 256];
  if (tid < 32) s1s[tid] = s1[(size_t)h*TOK + t0 + tid];
  { const int r = tid >> 3, wd = (tid & 7)*2;   // one coalesced 2KB bitmask stage
    *(uint2*)&mbs[r*16 + wd] = *(const uint2*)&mbits[((size_t)b*N + i0 + r)*16 + wd];
  }

  const u16* BTn = WhT + (size_t)(h*8 + b)*128*N;   // [o=128][j=512] bf16
  const int wave = tid >> 6, lane = tid & 63, quad = lane >> 4, l15 = lane & 15;
  const int c0 = wave*32;
  facc acc[2][2];
  #pragma unroll
  for (int rg = 0; rg < 2; ++rg)
    #pragma unroll
    for (int f = 0; f < 2; ++f) acc[rg][f] = (facc){0.f,0.f,0.f,0.f};

  const int lr = tid >> 3, lq = tid & 7;
  const unsigned char* mrow = (const unsigned char*)&mbs[lr*16];
  const int bn = tid >> 1, bpart = tid & 1;
  const u16* bwp = BTn + (size_t)bn*N + bpart*32;
  float psum = 0.f;

  // prologue: issue K-tile 0 B-loads, then stage tile 0
  uint4 g0 = *(const uint4*)bwp,      g1 = *(const uint4*)(bwp+8);
  uint4 g2 = *(const uint4*)(bwp+16), g3 = *(const uint4*)(bwp+24);
  __syncthreads();                            // s2s/s1s/mbs visible
  const float s1lr = s1s[lr];
  psum += score8(s2s, mrow, s1lr, 0, lq, &As[0][lr*LS + lq*8]);
  { u16* bp = &Bs[0][bn*LS + bpart*32];
    *(uint4*)bp = g0; *(uint4*)(bp+8) = g1; *(uint4*)(bp+16) = g2; *(uint4*)(bp+24) = g3; }
  __syncthreads();

  #pragma unroll
  for (int k = 0; k < 7; ++k){
    const int cur = k & 1, nxt = cur ^ 1;
    // issue next tile's WhT loads; latency hides under scores+MFMA
    const u16* wp = bwp + (k+1)*64;
    uint4 n0 = *(const uint4*)wp,      n1 = *(const uint4*)(wp+8);
    uint4 n2 = *(const uint4*)(wp+16), n3 = *(const uint4*)(wp+24);
    // next tile's scores (LDS + VALU only) -> As[nxt]
    psum += score8(s2s, mrow, s1lr, (k+1)*64, lq, &As[nxt][lr*LS + lq*8]);
    // current tile MFMA
    mfma64w(As[cur], Bs[cur], acc, c0, quad, l15);
    // land prefetched B into Bs[nxt]
    { u16* bp = &Bs[nxt][bn*LS + bpart*32];
      *(uint4*)bp = n0; *(uint4*)(bp+8) = n1; *(uint4*)(bp+16) = n2; *(uint4*)(bp+24) = n3; }
    __syncthreads();
  }
  mfma64w(As[1], Bs[1], acc, c0, quad, l15);

  #pragma unroll
  for (int m = 1; m < 8; m <<= 1) psum += __shfl_xor(psum, m, 64);
  if (lq == 0) sums[lr] = psum;
  __syncthreads();

  #pragma unroll
  for (int rg = 0; rg < 2; ++rg){
    #pragma unroll
    for (int q = 0; q < 4; ++q){
      const int row = rg*16 + quad*4 + q;
      const float sv = sums[row];
      const float inv = sv > 0.f ? 1.f/sv : 0.f;
      const int rq = t0 + row;
      #pragma unroll
      for (int f = 0; f < 2; ++f){
        float xv = acc[rg][f][q] * inv;
        xv = (MODE == 0) ? (xv > 0.f ? xv : __expf(xv) - 1.f) : lrelu(xv);
        const size_t idx = (size_t)rq*ldo + h*hcs + c0 + f*16 + l15;
        if (OBF) ((u16*)out_)[idx] = f2bf(xv);
        else     ((float*)out_)[idx] = xv;
      }
    }
  }
}

// ---------------- mean over n + projection -----------------------------------
__global__ void final_kernel(const float* __restrict__ hF, const float* __restrict__ hT,
                             const float* __restrict__ pW, const float* __restrict__ pb,
                             float* __restrict__ out)
{
  const int b = blockIdx.x, c = threadIdx.x;
  __shared__ float scr[4];
  const float* src = (c < D) ? (hF + (size_t)b*N*D + c) : (hT + (size_t)b*N*D + (c - D));
  float s = 0.f;
  for (int n = 0; n < N; ++n) s += src[(size_t)n*D];
  s *= (1.f/N);
  float p = s * pW[c];
  #pragma unroll
  for (int m = 32; m; m >>= 1) p += __shfl_xor(p, m, 64);
  __syncthreads();
  if ((c & 63) == 0) scr[c >> 6] = p;
  __syncthreads();
  if (c == 0) out[b] = scr[0] + scr[1] + scr[2] + scr[3] + pb[0];
}

extern "C" void kernel_launch(void* const* d_in, const int* in_sizes, int n_in,
                              void* d_out, int out_size, void* d_ws, size_t ws_size,
                              hipStream_t stream)
{
  (void)in_sizes; (void)n_in; (void)out_size; (void)ws_size;
  const float* x    = (const float*)d_in[0];
  const int*   adj  = (const int*)d_in[1];
  const float* f1w1 = (const float*)d_in[3];
  const float* f1b1 = (const float*)d_in[4];
  const float* f1w2 = (const float*)d_in[5];
  const float* f1b2 = (const float*)d_in[6];
  const float* f2w1 = (const float*)d_in[7];
  const float* f2b1 = (const float*)d_in[8];
  const float* f2w2 = (const float*)d_in[9];
  const float* f2b2 = (const float*)d_in[10];
  const float* f3w1 = (const float*)d_in[11];
  const float* f3b1 = (const float*)d_in[12];
  const float* f3w2 = (const float*)d_in[13];
  const float* f3b2 = (const float*)d_in[14];
  const float* attW = (const float*)d_in[15];
  const float* attA = (const float*)d_in[16];
  const float* rshW = (const float*)d_in[17];
  const float* rshB = (const float*)d_in[18];
  const float* outW = (const float*)d_in[19];
  const float* outA = (const float*)d_in[20];
  const float* pW   = (const float*)d_in[21];
  const float* pb   = (const float*)d_in[22];

  char* w = (char*)d_ws;
  float* hA  = (float*)w; w += (size_t)TOK*128*4;
  float* hB  = (float*)w; w += (size_t)TOK*128*4;
  float* hF  = (float*)w; w += (size_t)TOK*128*4;
  float* hq  = (float*)w; w += (size_t)TOK*256*4;   // FEL 256-wide fp32 scratch
  u16*  hp2  = (u16*)w;  w += (size_t)TOK*512*2;    // pv bf16 output
  u16*  WhT  = (u16*)w;  w += (size_t)H*8*128*N*2;
  float* s1  = (float*)w; w += (size_t)H*TOK*4;
  float* s2  = (float*)w; w += (size_t)H*TOK*4;
  u32* mbits = (u32*)w;  w += (size_t)B*N*16*4;     // bit-packed mask
  u32* mtbits= (u32*)w;  w += (size_t)B*N*16*4;     // bit-packed mask^T
  u16* f1w1T = (u16*)w; w += 128*32*2;
  u16* f1w2T = (u16*)w; w += 128*128*2;
  u16* f2w1T = (u16*)w; w += 256*128*2;
  u16* f2w2T = (u16*)w; w += 128*256*2;
  u16* f3w1T = (u16*)w; w += 256*128*2;
  u16* f3w2T = (u16*)w; w += 128*256*2;
  u16* attWT = (u16*)w; w += (size_t)24*128*128*2;
  u16* outWT = (u16*)w; w += (size_t)2*128*128*2;
  u16* rshWT = (u16*)w; w += (size_t)6*128*512*2;

  prep_kernel<<<512,256,0,stream>>>(adj, mbits, mtbits,
      f1w1, f1w2, f2w1, f2w2, f3w1, f3w2, attW, outW, rshW,
      f1w1T, f1w2T, f2w1T, f2w2T, f3w1T, f3w2T, attWT, outWT, rshWT);

  // ---- FEL: 6 GEMM stages ----
  gemm32<1,0><<<dim3(128,1),256,0,stream>>>(x,   32, 32,  f1w1T, f1b1, nullptr, hF, 128);
  gemm32<1,0><<<dim3(128,1),256,0,stream>>>(hF, 128, 128, f1w2T, f1b2, nullptr, hB, 128);
  gemm32<1,0><<<dim3(128,2),256,0,stream>>>(hB, 128, 128, f2w1T, f2b1, nullptr, hq, 256);
  gemm32<1,1><<<dim3(128,1),256,0,stream>>>(hq, 256, 256, f2w2T, f2b2, hB, hF, 128);
  gemm32<1,0><<<dim3(128,2),256,0,stream>>>(hF, 128, 128, f3w1T, f3b1, nullptr, hq, 256);
  gemm32<0,1><<<dim3(128,1),256,0,stream>>>(hq, 256, 256, f3w2T, f3b2, hF, hA, 128);

  // ---- forward attention blocks 0..2 ----
  float* cur = hA; float* nxt = hB;
  for (int i = 0; i < 3; ++i){
    wh32<<<H*128,256,0,stream>>>(cur, attWT + (size_t)i*H*D*D,
                                 attA + (size_t)i*H*2*D, WhT, s1, s2);
    pv32<0,1><<<H*128,256,0,stream>>>(s1, s2, mbits, WhT, hp2, 512, 128);
    gemm32b<<<128,256,0,stream>>>(hp2, 512, 512,
        rshWT + (size_t)i*128*512, rshB + (size_t)i*D, cur, nxt);
    float* t_ = cur; cur = nxt; nxt = t_;
  }
  // forward output GAT (single head, lrelu) -> hF
  wh32<<<128,256,0,stream>>>(cur, outWT, outA, WhT, s1, s2);
  pv32<1,0><<<128,256,0,stream>>>(s1, s2, mbits, WhT, hF, 128, 0);

  // ---- transposed attention blocks 3..5 ----
  cur = hF; nxt = hA;
  for (int i = 3; i < 6; ++i){
    wh32<<<H*128,256,0,stream>>>(cur, attWT + (size_t)i*H*D*D,
                                 attA + (size_t)i*H*2*D, WhT, s1, s2);
    pv32<0,1><<<H*128,256,0,stream>>>(s1, s2, mtbits, WhT, hp2, 512, 128);
    gemm32b<<<128,256,0,stream>>>(hp2, 512, 512,
        rshWT + (size_t)i*128*512, rshB + (size_t)i*D, cur, nxt);
    cur = nxt; nxt = (cur == hA) ? hB : hA;
  }
  // transposed output GAT -> nxt (distinct from hF and cur)
  wh32<<<128,256,0,stream>>>(cur, outWT + 128*128, outA + 2*D, WhT, s1, s2);
  pv32<1,0><<<128,256,0,stream>>>(s1, s2, mtbits, WhT, nxt, 128, 0);

  final_kernel<<<B,2*D,0,stream>>>(hF, nxt, pW, pb, (float*)d_out);
}

// Round 2
// 333.912 us; speedup vs baseline: 1.1494x; 1.0961x over previous
//
#include <hip/hip_runtime.h>
#include <math.h>

#define B 8
#define N 512
#define D 128
#define H 4
#define TOK (B*N)   // 4096

typedef __attribute__((ext_vector_type(8))) short bfrag;   // 8 bf16 (4 VGPRs)
typedef __attribute__((ext_vector_type(4))) float facc;    // 4 fp32 acc
typedef unsigned short u16;
typedef unsigned int u32;
typedef unsigned long long u64;

__device__ __forceinline__ float lrelu(float x){ return x > 0.f ? x : 0.01f*x; }
__device__ __forceinline__ u16 f2bf(float f){
  u32 u = __float_as_uint(f);
  u += 0x7fffu + ((u >> 16) & 1u);     // RTNE
  return (u16)(u >> 16);
}
__device__ __forceinline__ u32 pk2(float a, float b){
  return (u32)f2bf(a) | ((u32)f2bf(b) << 16);
}

// LDS row stride for bf16 tiles: 72 u16 (16B-aligned, breaks pow2 banks)
#define LS 72

// ---------------- prep: fully parallel, 1 job per block -----------------------
// blocks [0,512): adj 64x64 tile -> forward + transposed bitmask (1 barrier)
// blocks [512,1460): one 32x32 weight transpose job each (1 barrier)
__global__ void prep_kernel(const int* __restrict__ adj,
    u32* __restrict__ mbits, u32* __restrict__ mtbits,
    const float* s0, const float* s1_, const float* s2_, const float* s3,
    const float* s4, const float* s5, const float* s6, const float* s7,
    const float* s8,
    u16* d0, u16* d1, u16* d2, u16* d3, u16* d4, u16* d5, u16* d6, u16* d7, u16* d8)
{
  __shared__ int smem[64*65];           // 16.6 KB; reused as float tile below
  const int tid = threadIdx.x;
  if (blockIdx.x < 512){
    const int tb = blockIdx.x;
    const int b = tb >> 6, i0 = ((tb >> 3) & 7)*64, j0 = (tb & 7)*64;
    #pragma unroll
    for (int i = 0; i < 4; ++i){
      const int r = i*16 + (tid >> 4);
      const int c = (tid & 15)*4;
      int4 v = *(const int4*)&adj[((size_t)b*N + i0 + r)*N + j0 + c];
      smem[r*65 + c]     = v.x; smem[r*65 + c + 1] = v.y;
      smem[r*65 + c + 2] = v.z; smem[r*65 + c + 3] = v.w;
    }
    __syncthreads();
    const int wv = tid >> 6, lane = tid & 63;
    #pragma unroll
    for (int q = 0; q < 16; ++q){
      const int r = wv*16 + q;
      // forward: row i0+r, cols j0+lane
      u64 bf_ = __ballot(smem[r*65 + lane] > 0);
      if (lane == 0)
        *(u64*)&mbits[((size_t)b*N + i0 + r)*16 + (j0 >> 5)] = bf_;
      // transposed: row j0+r of mask^T, cols i0+lane  (stride-65 read, conflict-free)
      u64 bt_ = __ballot(smem[lane*65 + r] > 0);
      if (lane == 0)
        *(u64*)&mtbits[((size_t)b*N + j0 + r)*16 + (i0 >> 5)] = bt_;
    }
  } else {
    float* ftile = (float*)smem;        // [32][33]
    const int tx = tid & 31, ty = tid >> 5;
    const float* srcs[9] = {s0,s1_,s2_,s3,s4,s5,s6,s7,s8};
    u16* dsts[9] = {d0,d1,d2,d3,d4,d5,d6,d7,d8};
    const int Ks[9] = {32,128,128,256,128,256,128,128,512};
    const int Ns[9] = {128,128,256,128,256,128,128,128,128};
    const int zs[9] = {1,1,1,1,1,1,24,2,6};
    const int job = (int)blockIdx.x - 512;      // [0,948)
    int m = 0, base = 0;
    for (; m < 9; ++m){
      int cnt = (Ks[m]>>5)*(Ns[m]>>5)*zs[m];
      if (job < base + cnt) break;
      base += cnt;
    }
    const int rem = job - base;
    const int tn = Ns[m] >> 5;
    const int per = (Ks[m] >> 5)*tn;
    const int z = rem / per, t = rem % per;
    const int k0 = (t / tn)*32, n0 = (t % tn)*32;
    const float* src = srcs[m] + (size_t)z*Ks[m]*Ns[m];
    u16* dst = dsts[m] + (size_t)z*Ks[m]*Ns[m];
    for (int r = ty; r < 32; r += 8)
      ftile[r*33 + tx] = src[(size_t)(k0+r)*Ns[m] + n0 + tx];
    __syncthreads();
    for (int r = ty; r < 32; r += 8)
      dst[(size_t)(n0+r)*Ks[m] + k0 + tx] = f2bf(ftile[tx*33 + r]);
  }
}

// ---- B staging helpers -------------------------------------------------------
__device__ __forceinline__ void stageB64(const u16* __restrict__ BTn, int ldb,
                                         int k0, u16* Bs, int tid){
  const int n = tid >> 1, part = tid & 1;
  const u16* wp = BTn + (size_t)n*ldb + k0 + part*32;
  uint4 w0 = *(const uint4*)wp,      w1 = *(const uint4*)(wp+8);
  uint4 w2 = *(const uint4*)(wp+16), w3 = *(const uint4*)(wp+24);
  *(uint4*)&Bs[n*LS + part*32]      = w0;
  *(uint4*)&Bs[n*LS + part*32 + 8]  = w1;
  *(uint4*)&Bs[n*LS + part*32 + 16] = w2;
  *(uint4*)&Bs[n*LS + part*32 + 24] = w3;
}
__device__ __forceinline__ void stageB32(const u16* __restrict__ BTn, int ldb,
                                         int k0, u16* Bs, int tid){
  const int n = tid >> 1, part = tid & 1;
  const u16* wp = BTn + (size_t)n*ldb + k0 + part*16;
  uint4 w0 = *(const uint4*)wp, w1 = *(const uint4*)(wp+8);
  *(uint4*)&Bs[n*LS + part*16]     = w0;
  *(uint4*)&Bs[n*LS + part*16 + 8] = w1;
}

// ---- 16x16x32 core, wave = 16 rows x 64 cols (gemm32 / wh32) -----------------
__device__ __forceinline__ void mfma64(const u16* As, const u16* Bs,
                                       facc acc[4], int r0, int c0,
                                       int quad, int l15){
  #pragma unroll
  for (int kk = 0; kk < 2; ++kk){
    bfrag af = *(const bfrag*)&As[(r0 + l15)*LS + kk*32 + quad*8];
    #pragma unroll
    for (int g = 0; g < 4; ++g){
      bfrag bf = *(const bfrag*)&Bs[(c0 + g*16 + l15)*LS + kk*32 + quad*8];
      acc[g] = __builtin_amdgcn_mfma_f32_16x16x32_bf16(af, bf, acc[g], 0,0,0);
    }
  }
}
__device__ __forceinline__ void mfma32(const u16* As, const u16* Bs,
                                       facc acc[4], int r0, int c0,
                                       int quad, int l15){
  bfrag af = *(const bfrag*)&As[(r0 + l15)*LS + quad*8];
  #pragma unroll
  for (int g = 0; g < 4; ++g){
    bfrag bf = *(const bfrag*)&Bs[(c0 + g*16 + l15)*LS + quad*8];
    acc[g] = __builtin_amdgcn_mfma_f32_16x16x32_bf16(af, bf, acc[g], 0,0,0);
  }
}

// ---- 16x16x32 core, wave = 32 rows x 32 cols (pv32 / gemm32b) ----------------
__device__ __forceinline__ void mfma64w(const u16* As, const u16* Bs,
                                        facc acc[2][2], int c0,
                                        int quad, int l15){
  #pragma unroll
  for (int kk = 0; kk < 2; ++kk){
    bfrag af0 = *(const bfrag*)&As[(l15)*LS      + kk*32 + quad*8];
    bfrag af1 = *(const bfrag*)&As[(16 + l15)*LS + kk*32 + quad*8];
    #pragma unroll
    for (int f = 0; f < 2; ++f){
      bfrag bf = *(const bfrag*)&Bs[(c0 + f*16 + l15)*LS + kk*32 + quad*8];
      acc[0][f] = __builtin_amdgcn_mfma_f32_16x16x32_bf16(af0, bf, acc[0][f], 0,0,0);
      acc[1][f] = __builtin_amdgcn_mfma_f32_16x16x32_bf16(af1, bf, acc[1][f], 0,0,0);
    }
  }
}

// ---------------- generic 32x128-tile GEMM, fp32 A (FEL) ----------------------
// dbuf + register prefetch, 1 barrier per K-step.
template<int ACT, int FIN>
__global__ __launch_bounds__(256) void gemm32(
    const float* __restrict__ A, int lda, int K,
    const u16* __restrict__ BT, const float* __restrict__ bias,
    const float* __restrict__ res, float* __restrict__ out, int ldo)
{
  const int tid = threadIdx.x;
  const int t0 = blockIdx.x * 32;
  const int n0 = blockIdx.y * 128;
  __shared__ __align__(16) u16 As[2][32*LS];
  __shared__ __align__(16) u16 Bs[2][128*LS];
  __shared__ float scrS[4][16], scrQ[4][16];
  const int wave = tid >> 6, lane = tid & 63, quad = lane >> 4, l15 = lane & 15;
  const int r0 = (wave & 1)*16, c0 = (wave >> 1)*64;
  facc acc[4];
  #pragma unroll
  for (int g = 0; g < 4; ++g) acc[g] = (facc){0.f,0.f,0.f,0.f};
  const u16* BTn = BT + (size_t)n0*K;

  const int arow = tid >> 3, ako = tid & 7;
  const float* aptr = A + (size_t)(t0+arow)*lda;
  const int bn = tid >> 1, bpart = tid & 1;
  const u16* bptr = BTn + (size_t)bn*K;

  const int nt = K >> 6;
  int kfin = 0;   // LDS buffer holding the last staged tile
  if (nt > 0){
    // prologue: stage K-tile 0
    { const float* ap = aptr + ako*8;
      float4 a0 = *(const float4*)ap, a1 = *(const float4*)(ap+4);
      uint4 u = { pk2(a0.x,a0.y), pk2(a0.z,a0.w), pk2(a1.x,a1.y), pk2(a1.z,a1.w) };
      *(uint4*)&As[0][arow*LS + ako*8] = u;
      const u16* wp = bptr + bpart*32;
      uint4 g0 = *(const uint4*)wp,      g1 = *(const uint4*)(wp+8);
      uint4 g2 = *(const uint4*)(wp+16), g3 = *(const uint4*)(wp+24);
      u16* bp = &Bs[0][bn*LS + bpart*32];
      *(uint4*)bp = g0; *(uint4*)(bp+8) = g1; *(uint4*)(bp+16) = g2; *(uint4*)(bp+24) = g3;
    }
    __syncthreads();
    for (int k = 0; k < nt - 1; ++k){
      const int cur = k & 1, nxt = cur ^ 1;
      const float* ap = aptr + (k+1)*64 + ako*8;
      float4 a0 = *(const float4*)ap, a1 = *(const float4*)(ap+4);
      const u16* wp = bptr + (k+1)*64 + bpart*32;
      uint4 n0v = *(const uint4*)wp,      n1v = *(const uint4*)(wp+8);
      uint4 n2v = *(const uint4*)(wp+16), n3v = *(const uint4*)(wp+24);
      mfma64(As[cur], Bs[cur], acc, r0, c0, quad, l15);
      { uint4 u = { pk2(a0.x,a0.y), pk2(a0.z,a0.w), pk2(a1.x,a1.y), pk2(a1.z,a1.w) };
        *(uint4*)&As[nxt][arow*LS + ako*8] = u;
        u16* bp = &Bs[nxt][bn*LS + bpart*32];
        *(uint4*)bp = n0v; *(uint4*)(bp+8) = n1v; *(uint4*)(bp+16) = n2v; *(uint4*)(bp+24) = n3v; }
      __syncthreads();
    }
    kfin = (nt-1) & 1;
    mfma64(As[kfin], Bs[kfin], acc, r0, c0, quad, l15);
  }
  if (K & 63){   // 32-wide remainder (K=32 case: nt==0, kfin==0)
    if (nt > 0) __syncthreads();
    const int k0 = nt*64;
    { float4 a0 = *(const float4*)(aptr + k0 + ako*4);
      uint2 u = { pk2(a0.x,a0.y), pk2(a0.z,a0.w) };
      *(uint2*)&As[kfin][arow*LS + ako*4] = u;
    }
    stageB32(BTn, K, k0, Bs[kfin], tid);
    __syncthreads();
    mfma32(As[kfin], Bs[kfin], acc, r0, c0, quad, l15);
  }

  float bv[4];
  #pragma unroll
  for (int g = 0; g < 4; ++g) bv[g] = bias[n0 + c0 + g*16 + l15];

  if (FIN == 0){
    #pragma unroll
    for (int g = 0; g < 4; ++g){
      const int c = n0 + c0 + g*16 + l15;
      #pragma unroll
      for (int q = 0; q < 4; ++q){
        const int rq = t0 + r0 + quad*4 + q;
        float xv = acc[g][q] + bv[g];
        if (ACT) xv = lrelu(xv);
        out[(size_t)rq*ldo + c] = xv;
      }
    }
  } else {
    float v[4][4], s[4] = {0,0,0,0}, sq[4] = {0,0,0,0};
    #pragma unroll
    for (int g = 0; g < 4; ++g){
      const int c = c0 + g*16 + l15;
      #pragma unroll
      for (int q = 0; q < 4; ++q){
        const int rq = t0 + r0 + quad*4 + q;
        float xv = acc[g][q] + bv[g];
        if (ACT) xv = lrelu(xv);
        xv += res[(size_t)rq*128 + c];
        v[g][q] = xv; s[q] += xv; sq[q] += xv*xv;
      }
    }
    #pragma unroll
    for (int m = 1; m < 16; m <<= 1){
      #pragma unroll
      for (int q = 0; q < 4; ++q){ s[q] += __shfl_xor(s[q], m, 64); sq[q] += __shfl_xor(sq[q], m, 64); }
    }
    __syncthreads();   // scr reuse safety after K-loop
    if (l15 == 0){
      #pragma unroll
      for (int q = 0; q < 4; ++q){ scrS[wave][quad*4+q] = s[q]; scrQ[wave][quad*4+q] = sq[q]; }
    }
    __syncthreads();
    #pragma unroll
    for (int q = 0; q < 4; ++q){
      const int rq = t0 + r0 + quad*4 + q;
      const float fs = s[q] + scrS[wave^2][quad*4+q];
      const float fq = sq[q] + scrQ[wave^2][quad*4+q];
      const float mean = fs*(1.f/D);
      const float rstd = rsqrtf(fq*(1.f/D) - mean*mean + 1e-5f);
      #pragma unroll
      for (int g = 0; g < 4; ++g)
        out[(size_t)rq*128 + c0 + g*16 + l15] = (v[g][q] - mean)*rstd;
    }
  }
}

// ---------------- resh: bf16-A GEMM + bias + residual + LN (dbuf) -------------
__global__ __launch_bounds__(256) void gemm32b(
    const u16* __restrict__ A, int lda, int K,
    const u16* __restrict__ BT, const float* __restrict__ bias,
    const float* __restrict__ res, float* __restrict__ out)
{
  const int tid = threadIdx.x;
  const int t0 = blockIdx.x * 32;
  __shared__ __align__(16) u16 As[2][32*LS];
  __shared__ __align__(16) u16 Bs[2][128*LS];
  __shared__ float scrS[4][32], scrQ[4][32];
  const int wave = tid >> 6, lane = tid & 63, quad = lane >> 4, l15 = lane & 15;
  const int c0 = wave*32;
  facc acc[2][2];
  #pragma unroll
  for (int rg = 0; rg < 2; ++rg)
    #pragma unroll
    for (int f = 0; f < 2; ++f) acc[rg][f] = (facc){0.f,0.f,0.f,0.f};

  const int arow = tid >> 3, ako = tid & 7;
  const u16* aptr = A + (size_t)(t0+arow)*lda + ako*8;
  const int bn = tid >> 1, bpart = tid & 1;
  const u16* bptr = BT + (size_t)bn*K + bpart*32;

  { uint4 ga = *(const uint4*)aptr;
    uint4 g0 = *(const uint4*)bptr,      g1 = *(const uint4*)(bptr+8);
    uint4 g2 = *(const uint4*)(bptr+16), g3 = *(const uint4*)(bptr+24);
    *(uint4*)&As[0][arow*LS + ako*8] = ga;
    u16* bp = &Bs[0][bn*LS + bpart*32];
    *(uint4*)bp = g0; *(uint4*)(bp+8) = g1; *(uint4*)(bp+16) = g2; *(uint4*)(bp+24) = g3;
  }
  __syncthreads();

  const int nt = K >> 6;
  for (int k = 0; k < nt - 1; ++k){
    const int cur = k & 1, nxt = cur ^ 1;
    uint4 na = *(const uint4*)(aptr + (k+1)*64);
    const u16* wp = bptr + (k+1)*64;
    uint4 n0 = *(const uint4*)wp,      n1 = *(const uint4*)(wp+8);
    uint4 n2 = *(const uint4*)(wp+16), n3 = *(const uint4*)(wp+24);
    mfma64w(As[cur], Bs[cur], acc, c0, quad, l15);
    *(uint4*)&As[nxt][arow*LS + ako*8] = na;
    { u16* bp = &Bs[nxt][bn*LS + bpart*32];
      *(uint4*)bp = n0; *(uint4*)(bp+8) = n1; *(uint4*)(bp+16) = n2; *(uint4*)(bp+24) = n3; }
    __syncthreads();
  }
  mfma64w(As[(nt-1)&1], Bs[(nt-1)&1], acc, c0, quad, l15);

  float bv[2];
  #pragma unroll
  for (int f = 0; f < 2; ++f) bv[f] = bias[c0 + f*16 + l15];
  float v[2][2][4], s[2][4], sq[2][4];
  #pragma unroll
  for (int rg = 0; rg < 2; ++rg)
    #pragma unroll
    for (int q = 0; q < 4; ++q){ s[rg][q] = 0.f; sq[rg][q] = 0.f; }
  #pragma unroll
  for (int rg = 0; rg < 2; ++rg){
    #pragma unroll
    for (int f = 0; f < 2; ++f){
      const int c = c0 + f*16 + l15;
      #pragma unroll
      for (int q = 0; q < 4; ++q){
        const int rq = t0 + rg*16 + quad*4 + q;
        float xv = acc[rg][f][q] + bv[f] + res[(size_t)rq*128 + c];
        v[rg][f][q] = xv; s[rg][q] += xv; sq[rg][q] += xv*xv;
      }
    }
  }
  #pragma unroll
  for (int m = 1; m < 16; m <<= 1){
    #pragma unroll
    for (int rg = 0; rg < 2; ++rg)
      #pragma unroll
      for (int q = 0; q < 4; ++q){ s[rg][q] += __shfl_xor(s[rg][q], m, 64); sq[rg][q] += __shfl_xor(sq[rg][q], m, 64); }
  }
  if (l15 == 0){
    #pragma unroll
    for (int rg = 0; rg < 2; ++rg)
      #pragma unroll
      for (int q = 0; q < 4; ++q){
        scrS[wave][rg*16 + quad*4 + q] = s[rg][q];
        scrQ[wave][rg*16 + quad*4 + q] = sq[rg][q];
      }
  }
  __syncthreads();
  #pragma unroll
  for (int rg = 0; rg < 2; ++rg){
    #pragma unroll
    for (int q = 0; q < 4; ++q){
      const int row = rg*16 + quad*4 + q;
      const float fs = scrS[0][row] + scrS[1][row] + scrS[2][row] + scrS[3][row];
      const float fq = scrQ[0][row] + scrQ[1][row] + scrQ[2][row] + scrQ[3][row];
      const float mean = fs*(1.f/D);
      const float rstd = rsqrtf(fq*(1.f/D) - mean*mean + 1e-5f);
      #pragma unroll
      for (int f = 0; f < 2; ++f)
        out[(size_t)(t0+row)*128 + c0 + f*16 + l15] = (v[rg][f][q] - mean)*rstd;
    }
  }
}

// ---------------- Wh + fused s1/s2 (dbuf: K=128 = exactly 2 tiles) ------------
__global__ __launch_bounds__(256) void wh32(
    const float* __restrict__ hin, const u16* __restrict__ WT,
    const float* __restrict__ a, u16* __restrict__ WhT,
    float* __restrict__ s1, float* __restrict__ s2)
{
  const int tid = threadIdx.x;
  const int h  = blockIdx.x >> 7;
  const int t0 = (blockIdx.x & 127) * 32;
  const int b = t0 >> 9, j0 = t0 & (N-1);
  __shared__ __align__(16) u16 As[2][32*LS];
  __shared__ __align__(16) u16 Bs[2][128*LS];
  __shared__ float r1s[2][32], r2s[2][32];
  const int wave = tid >> 6, lane = tid & 63, quad = lane >> 4, l15 = lane & 15;
  const int r0 = (wave & 1)*16, c0 = (wave >> 1)*64;
  facc acc[4];
  #pragma unroll
  for (int g = 0; g < 4; ++g) acc[g] = (facc){0.f,0.f,0.f,0.f};

  const int arow = tid >> 3, ako = tid & 7;
  const float* aptr = hin + (size_t)(t0+arow)*D + ako*8;
  const int bn = tid >> 1, bpart = tid & 1;
  const u16* bwp = WT + (size_t)h*D*D + (size_t)bn*D + bpart*32;

  // stage tile 0
  { float4 a0 = *(const float4*)aptr, a1 = *(const float4*)(aptr+4);
    uint4 u = { pk2(a0.x,a0.y), pk2(a0.z,a0.w), pk2(a1.x,a1.y), pk2(a1.z,a1.w) };
    *(uint4*)&As[0][arow*LS + ako*8] = u;
    uint4 g0 = *(const uint4*)bwp,      g1 = *(const uint4*)(bwp+8);
    uint4 g2 = *(const uint4*)(bwp+16), g3 = *(const uint4*)(bwp+24);
    u16* bp = &Bs[0][bn*LS + bpart*32];
    *(uint4*)bp = g0; *(uint4*)(bp+8) = g1; *(uint4*)(bp+16) = g2; *(uint4*)(bp+24) = g3;
  }
  __syncthreads();
  // prefetch tile 1, mfma tile 0, land tile 1
  { float4 a0 = *(const float4*)(aptr+64), a1 = *(const float4*)(aptr+68);
    uint4 g0 = *(const uint4*)(bwp+64),    g1 = *(const uint4*)(bwp+72);
    uint4 g2 = *(const uint4*)(bwp+80),    g3 = *(const uint4*)(bwp+88);
    mfma64(As[0], Bs[0], acc, r0, c0, quad, l15);
    uint4 u = { pk2(a0.x,a0.y), pk2(a0.z,a0.w), pk2(a1.x,a1.y), pk2(a1.z,a1.w) };
    *(uint4*)&As[1][arow*LS + ako*8] = u;
    u16* bp = &Bs[1][bn*LS + bpart*32];
    *(uint4*)bp = g0; *(uint4*)(bp+8) = g1; *(uint4*)(bp+16) = g2; *(uint4*)(bp+24) = g3;
  }
  __syncthreads();
  mfma64(As[1], Bs[1], acc, r0, c0, quad, l15);

  const float* ah = a + (size_t)h*2*D;
  const size_t obase = (size_t)(h*8 + b)*128;
  float p1[4] = {0,0,0,0}, p2[4] = {0,0,0,0};
  #pragma unroll
  for (int g = 0; g < 4; ++g){
    const int c = c0 + g*16 + l15;
    const float a1v = ah[c], a2v = ah[D + c];
    ushort4 wv;
    wv.x = f2bf(acc[g][0]); wv.y = f2bf(acc[g][1]);
    wv.z = f2bf(acc[g][2]); wv.w = f2bf(acc[g][3]);
    *(ushort4*)&WhT[(obase + c)*N + j0 + r0 + quad*4] = wv;
    #pragma unroll
    for (int q = 0; q < 4; ++q){
      p1[q] = fmaf(acc[g][q], a1v, p1[q]);
      p2[q] = fmaf(acc[g][q], a2v, p2[q]);
    }
  }
  #pragma unroll
  for (int m = 1; m < 16; m <<= 1){
    #pragma unroll
    for (int q = 0; q < 4; ++q){ p1[q] += __shfl_xor(p1[q], m, 64); p2[q] += __shfl_xor(p2[q], m, 64); }
  }
  if (l15 == 0){
    #pragma unroll
    for (int q = 0; q < 4; ++q){
      r1s[wave>>1][r0 + quad*4 + q] = p1[q];
      r2s[wave>>1][r0 + quad*4 + q] = p2[q];
    }
  }
  __syncthreads();
  if (tid < 32){
    s1[(size_t)h*TOK + t0 + tid] = r1s[0][tid] + r1s[1][tid];
    s2[(size_t)h*TOK + t0 + tid] = r2s[0][tid] + r2s[1][tid];
  }
}

// ---- score phase helper: 8 cols of one row, bitmask from LDS -----------------
__device__ __forceinline__ float score8(const float* s2s, const unsigned char* mrow,
                                        float s1lr, int k0, int lq, u16* asp){
  float4 sa = *(const float4*)&s2s[k0 + lq*8];
  float4 sb = *(const float4*)&s2s[k0 + lq*8 + 4];
  const u32 mm = mrow[(k0 >> 3) + lq];
  float ss[8] = {sa.x,sa.y,sa.z,sa.w,sb.x,sb.y,sb.z,sb.w};
  float v[8]; float p = 0.f;
  #pragma unroll
  for (int i = 0; i < 8; ++i){
    float e = lrelu(s1lr * ss[i]);
    float ex = ((mm >> i) & 1u) ? __expf(e) : 0.f;
    v[i] = ex; p += ex;
  }
  uint4 u = { pk2(v[0],v[1]), pk2(v[2],v[3]), pk2(v[4],v[5]), pk2(v[6],v[7]) };
  *(uint4*)asp = u;
  return p;
}

// ---------------- fused score+softmax+PV (dbuf, 1 barrier/K-step) -------------
// MODE 0: elu, MODE 1: lrelu. OBF 1: bf16 out, OBF 0: fp32 out.
template<int MODE, int OBF>
__global__ __launch_bounds__(256) void pv32(
    const float* __restrict__ s1, const float* __restrict__ s2,
    const u32* __restrict__ mbits, const u16* __restrict__ WhT,
    void* __restrict__ out_, int ldo, int hcs)
{
  const int tid = threadIdx.x;
  const int h  = blockIdx.x >> 7;
  const int t0 = (blockIdx.x & 127) * 32;
  const int b = t0 >> 9, i0 = t0 & (N-1);
  __shared__ float s2s[N];
  __shared__ float s1s[32], sums[32];
  __shared__ u32 mbs[32*16];                 // 32 rows x 512 bits
  __shared__ __align__(16) u16 As[2][32*LS];
  __shared__ __align__(16) u16 Bs[2][128*LS];

  s2s[tid]     = s2[(size_t)h*TOK + b*N + tid];
  s2s[tid+256] = s2[(size_t)h*TOK + b*N + tid + 256];
  if (tid < 32) s1s[tid] = s1[(size_t)h*TOK + t0 + tid];
  { const int r = tid >> 3, wd = (tid & 7)*2;   // one coalesced 2KB bitmask stage
    *(uint2*)&mbs[r*16 + wd] = *(const uint2*)&mbits[((size_t)b*N + i0 + r)*16 + wd];
  }

  const u16* BTn = WhT + (size_t)(h*8 + b)*128*N;   // [o=128][j=512] bf16
  const int wave = tid >> 6, lane = tid & 63, quad = lane >> 4, l15 = lane & 15;
  const int c0 = wave*32;
  facc acc[2][2];
  #pragma unroll
  for (int rg = 0; rg < 2; ++rg)
    #pragma unroll
    for (int f = 0; f < 2; ++f) acc[rg][f] = (facc){0.f,0.f,0.f,0.f};

  const int lr = tid >> 3, lq = tid & 7;
  const unsigned char* mrow = (const unsigned char*)&mbs[lr*16];
  const int bn = tid >> 1, bpart = tid & 1;
  const u16* bwp = BTn + (size_t)bn*N + bpart*32;
  float psum = 0.f;

  // prologue: issue K-tile 0 B-loads, then stage tile 0
  uint4 g0 = *(const uint4*)bwp,      g1 = *(const uint4*)(bwp+8);
  uint4 g2 = *(const uint4*)(bwp+16), g3 = *(const uint4*)(bwp+24);
  __syncthreads();                            // s2s/s1s/mbs visible
  const float s1lr = s1s[lr];
  psum += score8(s2s, mrow, s1lr, 0, lq, &As[0][lr*LS + lq*8]);
  { u16* bp = &Bs[0][bn*LS + bpart*32];
    *(uint4*)bp = g0; *(uint4*)(bp+8) = g1; *(uint4*)(bp+16) = g2; *(uint4*)(bp+24) = g3; }
  __syncthreads();

  #pragma unroll
  for (int k = 0; k < 7; ++k){
    const int cur = k & 1, nxt = cur ^ 1;
    const u16* wp = bwp + (k+1)*64;
    uint4 n0 = *(const uint4*)wp,      n1 = *(const uint4*)(wp+8);
    uint4 n2 = *(const uint4*)(wp+16), n3 = *(const uint4*)(wp+24);
    psum += score8(s2s, mrow, s1lr, (k+1)*64, lq, &As[nxt][lr*LS + lq*8]);
    mfma64w(As[cur], Bs[cur], acc, c0, quad, l15);
    { u16* bp = &Bs[nxt][bn*LS + bpart*32];
      *(uint4*)bp = n0; *(uint4*)(bp+8) = n1; *(uint4*)(bp+16) = n2; *(uint4*)(bp+24) = n3; }
    __syncthreads();
  }
  mfma64w(As[1], Bs[1], acc, c0, quad, l15);

  #pragma unroll
  for (int m = 1; m < 8; m <<= 1) psum += __shfl_xor(psum, m, 64);
  if (lq == 0) sums[lr] = psum;
  __syncthreads();

  #pragma unroll
  for (int rg = 0; rg < 2; ++rg){
    #pragma unroll
    for (int q = 0; q < 4; ++q){
      const int row = rg*16 + quad*4 + q;
      const float sv = sums[row];
      const float inv = sv > 0.f ? 1.f/sv : 0.f;
      const int rq = t0 + row;
      #pragma unroll
      for (int f = 0; f < 2; ++f){
        float xv = acc[rg][f][q] * inv;
        xv = (MODE == 0) ? (xv > 0.f ? xv : __expf(xv) - 1.f) : lrelu(xv);
        const size_t idx = (size_t)rq*ldo + h*hcs + c0 + f*16 + l15;
        if (OBF) ((u16*)out_)[idx] = f2bf(xv);
        else     ((float*)out_)[idx] = xv;
      }
    }
  }
}

// ---------------- mean over n + projection -----------------------------------
__global__ void final_kernel(const float* __restrict__ hF, const float* __restrict__ hT,
                             const float* __restrict__ pW, const float* __restrict__ pb,
                             float* __restrict__ out)
{
  const int b = blockIdx.x, c = threadIdx.x;
  __shared__ float scr[4];
  const float* src = (c < D) ? (hF + (size_t)b*N*D + c) : (hT + (size_t)b*N*D + (c - D));
  float s = 0.f;
  for (int n = 0; n < N; ++n) s += src[(size_t)n*D];
  s *= (1.f/N);
  float p = s * pW[c];
  #pragma unroll
  for (int m = 32; m; m >>= 1) p += __shfl_xor(p, m, 64);
  __syncthreads();
  if ((c & 63) == 0) scr[c >> 6] = p;
  __syncthreads();
  if (c == 0) out[b] = scr[0] + scr[1] + scr[2] + scr[3] + pb[0];
}

extern "C" void kernel_launch(void* const* d_in, const int* in_sizes, int n_in,
                              void* d_out, int out_size, void* d_ws, size_t ws_size,
                              hipStream_t stream)
{
  (void)in_sizes; (void)n_in; (void)out_size; (void)ws_size;
  const float* x    = (const float*)d_in[0];
  const int*   adj  = (const int*)d_in[1];
  const float* f1w1 = (const float*)d_in[3];
  const float* f1b1 = (const float*)d_in[4];
  const float* f1w2 = (const float*)d_in[5];
  const float* f1b2 = (const float*)d_in[6];
  const float* f2w1 = (const float*)d_in[7];
  const float* f2b1 = (const float*)d_in[8];
  const float* f2w2 = (const float*)d_in[9];
  const float* f2b2 = (const float*)d_in[10];
  const float* f3w1 = (const float*)d_in[11];
  const float* f3b1 = (const float*)d_in[12];
  const float* f3w2 = (const float*)d_in[13];
  const float* f3b2 = (const float*)d_in[14];
  const float* attW = (const float*)d_in[15];
  const float* attA = (const float*)d_in[16];
  const float* rshW = (const float*)d_in[17];
  const float* rshB = (const float*)d_in[18];
  const float* outW = (const float*)d_in[19];
  const float* outA = (const float*)d_in[20];
  const float* pW   = (const float*)d_in[21];
  const float* pb   = (const float*)d_in[22];

  char* w = (char*)d_ws;
  float* hA  = (float*)w; w += (size_t)TOK*128*4;
  float* hB  = (float*)w; w += (size_t)TOK*128*4;
  float* hF  = (float*)w; w += (size_t)TOK*128*4;
  float* hq  = (float*)w; w += (size_t)TOK*256*4;   // FEL 256-wide fp32 scratch
  u16*  hp2  = (u16*)w;  w += (size_t)TOK*512*2;    // pv bf16 output
  u16*  WhT  = (u16*)w;  w += (size_t)H*8*128*N*2;
  float* s1  = (float*)w; w += (size_t)H*TOK*4;
  float* s2  = (float*)w; w += (size_t)H*TOK*4;
  u32* mbits = (u32*)w;  w += (size_t)B*N*16*4;     // bit-packed mask
  u32* mtbits= (u32*)w;  w += (size_t)B*N*16*4;     // bit-packed mask^T
  u16* f1w1T = (u16*)w; w += 128*32*2;
  u16* f1w2T = (u16*)w; w += 128*128*2;
  u16* f2w1T = (u16*)w; w += 256*128*2;
  u16* f2w2T = (u16*)w; w += 128*256*2;
  u16* f3w1T = (u16*)w; w += 256*128*2;
  u16* f3w2T = (u16*)w; w += 128*256*2;
  u16* attWT = (u16*)w; w += (size_t)24*128*128*2;
  u16* outWT = (u16*)w; w += (size_t)2*128*128*2;
  u16* rshWT = (u16*)w; w += (size_t)6*128*512*2;

  prep_kernel<<<1460,256,0,stream>>>(adj, mbits, mtbits,
      f1w1, f1w2, f2w1, f2w2, f3w1, f3w2, attW, outW, rshW,
      f1w1T, f1w2T, f2w1T, f2w2T, f3w1T, f3w2T, attWT, outWT, rshWT);

  // ---- FEL: 6 GEMM stages ----
  gemm32<1,0><<<dim3(128,1),256,0,stream>>>(x,   32, 32,  f1w1T, f1b1, nullptr, hF, 128);
  gemm32<1,0><<<dim3(128,1),256,0,stream>>>(hF, 128, 128, f1w2T, f1b2, nullptr, hB, 128);
  gemm32<1,0><<<dim3(128,2),256,0,stream>>>(hB, 128, 128, f2w1T, f2b1, nullptr, hq, 256);
  gemm32<1,1><<<dim3(128,1),256,0,stream>>>(hq, 256, 256, f2w2T, f2b2, hB, hF, 128);
  gemm32<1,0><<<dim3(128,2),256,0,stream>>>(hF, 128, 128, f3w1T, f3b1, nullptr, hq, 256);
  gemm32<0,1><<<dim3(128,1),256,0,stream>>>(hq, 256, 256, f3w2T, f3b2, hF, hA, 128);

  // ---- forward attention blocks 0..2 ----
  float* cur = hA; float* nxt = hB;
  for (int i = 0; i < 3; ++i){
    wh32<<<H*128,256,0,stream>>>(cur, attWT + (size_t)i*H*D*D,
                                 attA + (size_t)i*H*2*D, WhT, s1, s2);
    pv32<0,1><<<H*128,256,0,stream>>>(s1, s2, mbits, WhT, hp2, 512, 128);
    gemm32b<<<128,256,0,stream>>>(hp2, 512, 512,
        rshWT + (size_t)i*128*512, rshB + (size_t)i*D, cur, nxt);
    float* t_ = cur; cur = nxt; nxt = t_;
  }
  // forward output GAT (single head, lrelu) -> hF
  wh32<<<128,256,0,stream>>>(cur, outWT, outA, WhT, s1, s2);
  pv32<1,0><<<128,256,0,stream>>>(s1, s2, mbits, WhT, hF, 128, 0);

  // ---- transposed attention blocks 3..5 ----
  cur = hF; nxt = hA;
  for (int i = 3; i < 6; ++i){
    wh32<<<H*128,256,0,stream>>>(cur, attWT + (size_t)i*H*D*D,
                                 attA + (size_t)i*H*2*D, WhT, s1, s2);
    pv32<0,1><<<H*128,256,0,stream>>>(s1, s2, mtbits, WhT, hp2, 512, 128);
    gemm32b<<<128,256,0,stream>>>(hp2, 512, 512,
        rshWT + (size_t)i*128*512, rshB + (size_t)i*D, cur, nxt);
    cur = nxt; nxt = (cur == hA) ? hB : hA;
  }
  // transposed output GAT -> nxt (distinct from hF and cur)
  wh32<<<128,256,0,stream>>>(cur, outWT + 128*128, outA + 2*D, WhT, s1, s2);
  pv32<1,0><<<128,256,0,stream>>>(s1, s2, mtbits, WhT, nxt, 128, 0);

  final_kernel<<<B,2*D,0,stream>>>(hF, nxt, pW, pb, (float*)d_out);
}

// Round 4
// 307.538 us; speedup vs baseline: 1.2480x; 1.0858x over previous
//
#include <hip/hip_runtime.h>
#include <math.h>

#define B 8
#define N 512
#define D 128
#define H 4
#define TOK (B*N)   // 4096

typedef __attribute__((ext_vector_type(8))) short bfrag;   // 8 bf16 (4 VGPRs)
typedef __attribute__((ext_vector_type(4))) float facc;    // 4 fp32 acc
typedef unsigned short u16;
typedef unsigned int u32;
typedef unsigned long long u64;

__device__ __forceinline__ float lrelu(float x){ return x > 0.f ? x : 0.01f*x; }
__device__ __forceinline__ u16 f2bf(float f){
  u32 u = __float_as_uint(f);
  u += 0x7fffu + ((u >> 16) & 1u);     // RTNE
  return (u16)(u >> 16);
}
__device__ __forceinline__ u32 pk2(float a, float b){
  return (u32)f2bf(a) | ((u32)f2bf(b) << 16);
}

// LDS row strides (u16): all give bank skew 4/row, 16B-aligned rows
#define LS 72        // B tiles / staged A tiles
#define ASF 264      // fel A tiles (K up to 256)
#define ASW 136      // wh-phase A tiles (K=128)

// ---------------- prep: fully parallel, 1 job per block -----------------------
__global__ void prep_kernel(const int* __restrict__ adj,
    u32* __restrict__ mbits, u32* __restrict__ mtbits,
    float* __restrict__ colsumF, float* __restrict__ colsumT,
    const float* s0, const float* s1_, const float* s2_, const float* s3,
    const float* s4, const float* s5, const float* s6, const float* s7,
    const float* s8,
    u16* d0, u16* d1, u16* d2, u16* d3, u16* d4, u16* d5, u16* d6, u16* d7, u16* d8)
{
  __shared__ int smem[64*65];
  const int tid = threadIdx.x;
  if (blockIdx.x < 512){
    const int tb = blockIdx.x;
    const int b = tb >> 6, i0 = ((tb >> 3) & 7)*64, j0 = (tb & 7)*64;
    #pragma unroll
    for (int i = 0; i < 4; ++i){
      const int r = i*16 + (tid >> 4);
      const int c = (tid & 15)*4;
      int4 v = *(const int4*)&adj[((size_t)b*N + i0 + r)*N + j0 + c];
      smem[r*65 + c]     = v.x; smem[r*65 + c + 1] = v.y;
      smem[r*65 + c + 2] = v.z; smem[r*65 + c + 3] = v.w;
    }
    __syncthreads();
    const int wv = tid >> 6, lane = tid & 63;
    #pragma unroll
    for (int q = 0; q < 16; ++q){
      const int r = wv*16 + q;
      u64 bf_ = __ballot(smem[r*65 + lane] > 0);
      if (lane == 0)
        *(u64*)&mbits[((size_t)b*N + i0 + r)*16 + (j0 >> 5)] = bf_;
      u64 bt_ = __ballot(smem[lane*65 + r] > 0);
      if (lane == 0)
        *(u64*)&mtbits[((size_t)b*N + j0 + r)*16 + (i0 >> 5)] = bt_;
    }
  } else if (blockIdx.x < 1460){
    float* ftile = (float*)smem;        // [32][33]
    const int tx = tid & 31, ty = tid >> 5;
    const float* srcs[9] = {s0,s1_,s2_,s3,s4,s5,s6,s7,s8};
    u16* dsts[9] = {d0,d1,d2,d3,d4,d5,d6,d7,d8};
    const int Ks[9] = {32,128,128,256,128,256,128,128,512};
    const int Ns[9] = {128,128,256,128,256,128,128,128,128};
    const int zs[9] = {1,1,1,1,1,1,24,2,6};
    const int job = (int)blockIdx.x - 512;      // [0,948)
    int m = 0, base = 0;
    for (; m < 9; ++m){
      int cnt = (Ks[m]>>5)*(Ns[m]>>5)*zs[m];
      if (job < base + cnt) break;
      base += cnt;
    }
    const int rem = job - base;
    const int tn = Ns[m] >> 5;
    const int per = (Ks[m] >> 5)*tn;
    const int z = rem / per, t = rem % per;
    const int k0 = (t / tn)*32, n0 = (t % tn)*32;
    const float* src = srcs[m] + (size_t)z*Ks[m]*Ns[m];
    u16* dst = dsts[m] + (size_t)z*Ks[m]*Ns[m];
    for (int r = ty; r < 32; r += 8)
      ftile[r*33 + tx] = src[(size_t)(k0+r)*Ns[m] + n0 + tx];
    __syncthreads();
    for (int r = ty; r < 32; r += 8)
      dst[(size_t)(n0+r)*Ks[m] + k0 + tx] = f2bf(ftile[tx*33 + r]);
  } else {
    float4 z = {0.f,0.f,0.f,0.f};
    *(float4*)&colsumF[tid*4] = z;
    *(float4*)&colsumT[tid*4] = z;
  }
}

// ---- staging helpers ---------------------------------------------------------
struct BPre { uint4 a,b,c,d; };
__device__ __forceinline__ BPre preB64(const u16* __restrict__ BTn, int ldb, int k0, int tid){
  const int n = tid >> 1, part = tid & 1;
  const u16* wp = BTn + (size_t)n*ldb + k0 + part*32;
  BPre r;
  r.a = *(const uint4*)wp;      r.b = *(const uint4*)(wp+8);
  r.c = *(const uint4*)(wp+16); r.d = *(const uint4*)(wp+24);
  return r;
}
__device__ __forceinline__ void landB64(const BPre& p, u16* Bs, int tid){
  const int n = tid >> 1, part = tid & 1;
  u16* bp = &Bs[n*LS + part*32];
  *(uint4*)bp = p.a; *(uint4*)(bp+8) = p.b; *(uint4*)(bp+16) = p.c; *(uint4*)(bp+24) = p.d;
}
__device__ __forceinline__ void stageB32(const u16* __restrict__ BTn, int ldb,
                                         int k0, u16* Bs, int tid){
  const int n = tid >> 1, part = tid & 1;
  const u16* wp = BTn + (size_t)n*ldb + k0 + part*16;
  uint4 w0 = *(const uint4*)wp, w1 = *(const uint4*)(wp+8);
  *(uint4*)&Bs[n*LS + part*16]     = w0;
  *(uint4*)&Bs[n*LS + part*16 + 8] = w1;
}

// ---- MFMA cores --------------------------------------------------------------
// 4-wave 32x128 mapping (stride-parameterized A)
__device__ __forceinline__ void mfma64s(const u16* As, int sA, const u16* Bs,
                                        facc acc[4], int r0, int c0, int quad, int l15){
  #pragma unroll
  for (int kk = 0; kk < 2; ++kk){
    bfrag af = *(const bfrag*)&As[(r0 + l15)*sA + kk*32 + quad*8];
    #pragma unroll
    for (int g = 0; g < 4; ++g){
      bfrag bf = *(const bfrag*)&Bs[(c0 + g*16 + l15)*LS + kk*32 + quad*8];
      acc[g] = __builtin_amdgcn_mfma_f32_16x16x32_bf16(af, bf, acc[g], 0,0,0);
    }
  }
}
__device__ __forceinline__ void mfma32s(const u16* As, int sA, const u16* Bs,
                                        facc acc[4], int r0, int c0, int quad, int l15){
  bfrag af = *(const bfrag*)&As[(r0 + l15)*sA + quad*8];
  #pragma unroll
  for (int g = 0; g < 4; ++g){
    bfrag bf = *(const bfrag*)&Bs[(c0 + g*16 + l15)*LS + quad*8];
    acc[g] = __builtin_amdgcn_mfma_f32_16x16x32_bf16(af, bf, acc[g], 0,0,0);
  }
}
// wave = 32 rows x 32 cols (pv / resh phase)
__device__ __forceinline__ void mfma64w(const u16* As, const u16* Bs,
                                        facc acc[2][2], int c0,
                                        int quad, int l15){
  #pragma unroll
  for (int kk = 0; kk < 2; ++kk){
    bfrag af0 = *(const bfrag*)&As[(l15)*LS      + kk*32 + quad*8];
    bfrag af1 = *(const bfrag*)&As[(16 + l15)*LS + kk*32 + quad*8];
    #pragma unroll
    for (int f = 0; f < 2; ++f){
      bfrag bf = *(const bfrag*)&Bs[(c0 + f*16 + l15)*LS + kk*32 + quad*8];
      acc[0][f] = __builtin_amdgcn_mfma_f32_16x16x32_bf16(af0, bf, acc[0][f], 0,0,0);
      acc[1][f] = __builtin_amdgcn_mfma_f32_16x16x32_bf16(af1, bf, acc[1][f], 0,0,0);
    }
  }
}

// ---- single-buffer A-in-LDS GEMM over T 64-wide K tiles ----------------------
// reg-prefetch next B tile; 2 barriers per tile. No trailing barrier.
template<int T>
__device__ __forceinline__ void gemmAs(const u16* Aw, int sA,
    const u16* __restrict__ BT, int ldb, u16* Bs,
    facc acc[4], int tid, int r0, int c0, int quad, int l15){
  BPre p = preB64(BT, ldb, 0, tid);
  #pragma unroll
  for (int t = 0; t < T; ++t){
    __syncthreads();                       // Bs writable; A writes visible below
    landB64(p, Bs, tid);
    if (t + 1 < T) p = preB64(BT, ldb, (t+1)*64, tid);
    __syncthreads();
    mfma64s(Aw + t*64, sA, Bs, acc, r0, c0, quad, l15);
  }
}

// ---- WH phase (single-buffer): A-tile (bf16, stride sA) -> NH head Wh GEMMs --
// writes WhT (transposed) + s1/s2.
template<int NH>
__device__ __forceinline__ void wh_phaseS(const u16* Aw, int sA, u16* Bs,
    const u16* __restrict__ WT, const float* __restrict__ aatt,
    int t0, u16* __restrict__ WhT, float* __restrict__ s1, float* __restrict__ s2,
    float (*r1s4)[2][32], float (*r2s4)[2][32], int tid)
{
  const int wave = tid >> 6, lane = tid & 63, quad = lane >> 4, l15 = lane & 15;
  const int r0 = (wave & 1)*16, c0 = (wave >> 1)*64;
  const int b = t0 >> 9, j0 = t0 & (N-1);
  BPre p = preB64(WT, D, 0, tid);
  facc acc[4];
  #pragma unroll
  for (int t = 0; t < 2*NH; ++t){
    if ((t & 1) == 0){
      #pragma unroll
      for (int g = 0; g < 4; ++g) acc[g] = (facc){0.f,0.f,0.f,0.f};
    }
    __syncthreads();                       // Bs writable; Aw visible
    landB64(p, Bs, tid);
    if (t + 1 < 2*NH) p = preB64(WT + (size_t)((t+1)>>1)*D*D, D, ((t+1)&1)*64, tid);
    __syncthreads();
    mfma64s(Aw + (t&1)*64, sA, Bs, acc, r0, c0, quad, l15);
    if (t & 1){
      const int h = t >> 1;
      const float* ah = aatt + (size_t)h*2*D;
      const size_t obase = (size_t)(h*8 + b)*128;
      float p1[4] = {0,0,0,0}, p2[4] = {0,0,0,0};
      #pragma unroll
      for (int g = 0; g < 4; ++g){
        const int c = c0 + g*16 + l15;
        const float a1v = ah[c], a2v = ah[D + c];
        ushort4 wv;
        wv.x = f2bf(acc[g][0]); wv.y = f2bf(acc[g][1]);
        wv.z = f2bf(acc[g][2]); wv.w = f2bf(acc[g][3]);
        *(ushort4*)&WhT[(obase + c)*N + j0 + r0 + quad*4] = wv;
        #pragma unroll
        for (int q = 0; q < 4; ++q){
          p1[q] = fmaf(acc[g][q], a1v, p1[q]);
          p2[q] = fmaf(acc[g][q], a2v, p2[q]);
        }
      }
      #pragma unroll
      for (int m = 1; m < 16; m <<= 1){
        #pragma unroll
        for (int q = 0; q < 4; ++q){ p1[q] += __shfl_xor(p1[q], m, 64); p2[q] += __shfl_xor(p2[q], m, 64); }
      }
      if (l15 == 0){
        #pragma unroll
        for (int q = 0; q < 4; ++q){
          r1s4[h][wave>>1][r0 + quad*4 + q] = p1[q];
          r2s4[h][wave>>1][r0 + quad*4 + q] = p2[q];
        }
      }
    }
  }
  __syncthreads();
  if (tid < 32*NH){
    const int h = tid >> 5, r = tid & 31;
    s1[(size_t)h*TOK + t0 + r] = r1s4[h][0][r] + r1s4[h][1][r];
    s2[(size_t)h*TOK + t0 + r] = r2s4[h][0][r] + r2s4[h][1][r];
  }
}

// ---------------- fused FEL (6 GEMMs + LN x2) + WH of att block 0 -------------
// LDS: 2x16.9K A + 18.4K B + scratch = 54.8 KB (< 64 KB).
__global__ __launch_bounds__(256) void fel_kernel(
    const float* __restrict__ x,
    const u16* __restrict__ w1T, const float* __restrict__ b1,
    const u16* __restrict__ w2T, const float* __restrict__ b2,
    const u16* __restrict__ w3T, const float* __restrict__ b3,
    const u16* __restrict__ w4T, const float* __restrict__ b4,
    const u16* __restrict__ w5T, const float* __restrict__ b5,
    const u16* __restrict__ w6T, const float* __restrict__ b6,
    const u16* __restrict__ WTatt, const float* __restrict__ aatt,
    float* __restrict__ hout, u16* __restrict__ WhT,
    float* __restrict__ s1, float* __restrict__ s2)
{
  const int tid = threadIdx.x;
  const int t0 = blockIdx.x * 32;
  __shared__ __align__(16) u16 AwA[32*ASF];
  __shared__ __align__(16) u16 AwB[32*ASF];
  __shared__ __align__(16) u16 Bs[128*LS];
  __shared__ float scrS[4][16], scrQ[4][16];
  __shared__ float r1s4[H][2][32], r2s4[H][2][32];
  const int wave = tid >> 6, lane = tid & 63, quad = lane >> 4, l15 = lane & 15;
  const int r0 = (wave & 1)*16, c0 = (wave >> 1)*64;
  facc acc[4];
  float rres[4][4];    // residual in regs: thread's (r,c) mapping identical across stages

  // ---- S1: t1 = lrelu(x@f1w1+b1)  (K=32) -> AwB
  { const int row = tid >> 3, ko = tid & 7;
    float4 a0 = *(const float4*)(x + (size_t)(t0+row)*32 + ko*4);
    uint2 u = { pk2(a0.x,a0.y), pk2(a0.z,a0.w) };
    *(uint2*)&AwA[row*ASF + ko*4] = u;
    stageB32(w1T, 32, 0, Bs, tid);
  }
  __syncthreads();
  #pragma unroll
  for (int g = 0; g < 4; ++g) acc[g] = (facc){0.f,0.f,0.f,0.f};
  mfma32s(AwA, ASF, Bs, acc, r0, c0, quad, l15);
  #pragma unroll
  for (int g = 0; g < 4; ++g){
    const int c = c0 + g*16 + l15;
    const float bv = b1[c];
    #pragma unroll
    for (int q = 0; q < 4; ++q)
      AwB[(r0 + quad*4 + q)*ASF + c] = f2bf(lrelu(acc[g][q] + bv));
  }

  // ---- S2: res = lrelu(t1@f1w2+b2) (K=128) -> AwA + rres
  #pragma unroll
  for (int g = 0; g < 4; ++g) acc[g] = (facc){0.f,0.f,0.f,0.f};
  gemmAs<2>(AwB, ASF, w2T, 128, Bs, acc, tid, r0, c0, quad, l15);
  #pragma unroll
  for (int g = 0; g < 4; ++g){
    const int c = c0 + g*16 + l15;
    const float bv = b2[c];
    #pragma unroll
    for (int q = 0; q < 4; ++q){
      float xv = lrelu(acc[g][q] + bv);
      AwA[(r0 + quad*4 + q)*ASF + c] = f2bf(xv);
      rres[g][q] = xv;
    }
  }

  // ---- S3: t3 = lrelu(res@f2w1+b3) (K=128, out 256) -> AwB
  #pragma unroll
  for (int ch = 0; ch < 2; ++ch){
    #pragma unroll
    for (int g = 0; g < 4; ++g) acc[g] = (facc){0.f,0.f,0.f,0.f};
    gemmAs<2>(AwA, ASF, w3T + (size_t)ch*128*128, 128, Bs, acc, tid, r0, c0, quad, l15);
    #pragma unroll
    for (int g = 0; g < 4; ++g){
      const int c = c0 + g*16 + l15;
      const float bv = b3[ch*128 + c];
      #pragma unroll
      for (int q = 0; q < 4; ++q)
        AwB[(r0 + quad*4 + q)*ASF + ch*128 + c] = f2bf(lrelu(acc[g][q] + bv));
    }
  }

  // ---- S4: x1 = LN(lrelu(t3@f2w2+b4) + res) (K=256) -> AwA + rres
  #pragma unroll
  for (int g = 0; g < 4; ++g) acc[g] = (facc){0.f,0.f,0.f,0.f};
  gemmAs<4>(AwB, ASF, w4T, 256, Bs, acc, tid, r0, c0, quad, l15);
  {
    float v[4][4], s[4] = {0,0,0,0}, sq[4] = {0,0,0,0};
    #pragma unroll
    for (int g = 0; g < 4; ++g){
      const int c = c0 + g*16 + l15;
      const float bv = b4[c];
      #pragma unroll
      for (int q = 0; q < 4; ++q){
        float xv = lrelu(acc[g][q] + bv) + rres[g][q];
        v[g][q] = xv; s[q] += xv; sq[q] += xv*xv;
      }
    }
    #pragma unroll
    for (int m = 1; m < 16; m <<= 1){
      #pragma unroll
      for (int q = 0; q < 4; ++q){ s[q] += __shfl_xor(s[q], m, 64); sq[q] += __shfl_xor(sq[q], m, 64); }
    }
    if (l15 == 0){
      #pragma unroll
      for (int q = 0; q < 4; ++q){ scrS[wave][quad*4+q] = s[q]; scrQ[wave][quad*4+q] = sq[q]; }
    }
    __syncthreads();
    #pragma unroll
    for (int q = 0; q < 4; ++q){
      const int r = r0 + quad*4 + q;
      const float fs = s[q] + scrS[wave^2][quad*4+q];
      const float fq = sq[q] + scrQ[wave^2][quad*4+q];
      const float mean = fs*(1.f/D);
      const float rstd = rsqrtf(fq*(1.f/D) - mean*mean + 1e-5f);
      #pragma unroll
      for (int g = 0; g < 4; ++g){
        const int c = c0 + g*16 + l15;
        float xv = (v[g][q] - mean)*rstd;
        AwA[r*ASF + c] = f2bf(xv);
        rres[g][q] = xv;
      }
    }
  }

  // ---- S5: t5 = lrelu(x1@f3w1+b5) (K=128, out 256) -> AwB
  #pragma unroll
  for (int ch = 0; ch < 2; ++ch){
    #pragma unroll
    for (int g = 0; g < 4; ++g) acc[g] = (facc){0.f,0.f,0.f,0.f};
    gemmAs<2>(AwA, ASF, w5T + (size_t)ch*128*128, 128, Bs, acc, tid, r0, c0, quad, l15);
    #pragma unroll
    for (int g = 0; g < 4; ++g){
      const int c = c0 + g*16 + l15;
      const float bv = b5[ch*128 + c];
      #pragma unroll
      for (int q = 0; q < 4; ++q)
        AwB[(r0 + quad*4 + q)*ASF + ch*128 + c] = f2bf(lrelu(acc[g][q] + bv));
    }
  }

  // ---- S6: out = LN(t5@f3w2+b6 + x1) (K=256) -> hout (fp32) + AwA (bf16)
  #pragma unroll
  for (int g = 0; g < 4; ++g) acc[g] = (facc){0.f,0.f,0.f,0.f};
  gemmAs<4>(AwB, ASF, w6T, 256, Bs, acc, tid, r0, c0, quad, l15);
  {
    float v[4][4], s[4] = {0,0,0,0}, sq[4] = {0,0,0,0};
    #pragma unroll
    for (int g = 0; g < 4; ++g){
      const int c = c0 + g*16 + l15;
      const float bv = b6[c];
      #pragma unroll
      for (int q = 0; q < 4; ++q){
        float xv = acc[g][q] + bv + rres[g][q];
        v[g][q] = xv; s[q] += xv; sq[q] += xv*xv;
      }
    }
    #pragma unroll
    for (int m = 1; m < 16; m <<= 1){
      #pragma unroll
      for (int q = 0; q < 4; ++q){ s[q] += __shfl_xor(s[q], m, 64); sq[q] += __shfl_xor(sq[q], m, 64); }
    }
    if (l15 == 0){
      #pragma unroll
      for (int q = 0; q < 4; ++q){ scrS[wave][quad*4+q] = s[q]; scrQ[wave][quad*4+q] = sq[q]; }
    }
    __syncthreads();
    #pragma unroll
    for (int q = 0; q < 4; ++q){
      const int r = r0 + quad*4 + q;
      const float fs = s[q] + scrS[wave^2][quad*4+q];
      const float fq = sq[q] + scrQ[wave^2][quad*4+q];
      const float mean = fs*(1.f/D);
      const float rstd = rsqrtf(fq*(1.f/D) - mean*mean + 1e-5f);
      #pragma unroll
      for (int g = 0; g < 4; ++g){
        const int c = c0 + g*16 + l15;
        float xv = (v[g][q] - mean)*rstd;
        hout[(size_t)(t0 + r)*128 + c] = xv;
        AwA[r*ASF + c] = f2bf(xv);
      }
    }
  }
  wh_phaseS<H>(AwA, ASF, Bs, WTatt, aatt, t0, WhT, s1, s2, r1s4, r2s4, tid);
}

// ---------------- reshwh: resh GEMM + bias + residual + LN + WH ---------------
template<int NH>
__global__ __launch_bounds__(256) void reshwh(
    const u16* __restrict__ A, const u16* __restrict__ BT, const float* __restrict__ bias,
    const float* __restrict__ res, float* __restrict__ hout,
    const u16* __restrict__ WT, const float* __restrict__ aatt,
    u16* __restrict__ WhT, float* __restrict__ s1, float* __restrict__ s2)
{
  const int tid = threadIdx.x;
  const int t0 = blockIdx.x * 32;
  __shared__ __align__(16) u16 AsU[2][32*LS];
  __shared__ __align__(16) u16 Bs[2][128*LS];
  __shared__ float scrS[4][32], scrQ[4][32];
  __shared__ float r1s4[NH][2][32], r2s4[NH][2][32];
  const int wave = tid >> 6, lane = tid & 63, quad = lane >> 4, l15 = lane & 15;
  const int c0w = wave*32;
  facc acc[2][2];
  #pragma unroll
  for (int rg = 0; rg < 2; ++rg)
    #pragma unroll
    for (int f = 0; f < 2; ++f) acc[rg][f] = (facc){0.f,0.f,0.f,0.f};

  const int arow = tid >> 3, ako = tid & 7;
  const u16* aptr = A + (size_t)(t0+arow)*512 + ako*8;
  const int bn = tid >> 1, bpart = tid & 1;
  const u16* bptr = BT + (size_t)bn*512 + bpart*32;

  { uint4 ga = *(const uint4*)aptr;
    uint4 g0 = *(const uint4*)bptr,      g1 = *(const uint4*)(bptr+8);
    uint4 g2 = *(const uint4*)(bptr+16), g3 = *(const uint4*)(bptr+24);
    *(uint4*)&AsU[0][arow*LS + ako*8] = ga;
    u16* bp = &Bs[0][bn*LS + bpart*32];
    *(uint4*)bp = g0; *(uint4*)(bp+8) = g1; *(uint4*)(bp+16) = g2; *(uint4*)(bp+24) = g3;
  }
  __syncthreads();
  #pragma unroll
  for (int k = 0; k < 7; ++k){
    const int cur = k & 1, nxt = cur ^ 1;
    uint4 na = *(const uint4*)(aptr + (k+1)*64);
    const u16* wp = bptr + (k+1)*64;
    uint4 n0 = *(const uint4*)wp,      n1 = *(const uint4*)(wp+8);
    uint4 n2 = *(const uint4*)(wp+16), n3 = *(const uint4*)(wp+24);
    mfma64w(AsU[cur], Bs[cur], acc, c0w, quad, l15);
    *(uint4*)&AsU[nxt][arow*LS + ako*8] = na;
    { u16* bp = &Bs[nxt][bn*LS + bpart*32];
      *(uint4*)bp = n0; *(uint4*)(bp+8) = n1; *(uint4*)(bp+16) = n2; *(uint4*)(bp+24) = n3; }
    __syncthreads();
  }
  mfma64w(AsU[1], Bs[1], acc, c0w, quad, l15);

  float bv[2];
  #pragma unroll
  for (int f = 0; f < 2; ++f) bv[f] = bias[c0w + f*16 + l15];
  float v[2][2][4], s[2][4], sq[2][4];
  #pragma unroll
  for (int rg = 0; rg < 2; ++rg)
    #pragma unroll
    for (int q = 0; q < 4; ++q){ s[rg][q] = 0.f; sq[rg][q] = 0.f; }
  #pragma unroll
  for (int rg = 0; rg < 2; ++rg){
    #pragma unroll
    for (int f = 0; f < 2; ++f){
      const int c = c0w + f*16 + l15;
      #pragma unroll
      for (int q = 0; q < 4; ++q){
        const int rq = t0 + rg*16 + quad*4 + q;
        float xv = acc[rg][f][q] + bv[f] + res[(size_t)rq*128 + c];
        v[rg][f][q] = xv; s[rg][q] += xv; sq[rg][q] += xv*xv;
      }
    }
  }
  #pragma unroll
  for (int m = 1; m < 16; m <<= 1){
    #pragma unroll
    for (int rg = 0; rg < 2; ++rg)
      #pragma unroll
      for (int q = 0; q < 4; ++q){ s[rg][q] += __shfl_xor(s[rg][q], m, 64); sq[rg][q] += __shfl_xor(sq[rg][q], m, 64); }
  }
  if (l15 == 0){
    #pragma unroll
    for (int rg = 0; rg < 2; ++rg)
      #pragma unroll
      for (int q = 0; q < 4; ++q){
        scrS[wave][rg*16 + quad*4 + q] = s[rg][q];
        scrQ[wave][rg*16 + quad*4 + q] = sq[rg][q];
      }
  }
  __syncthreads();
  u16* Aw = &AsU[0][0];     // stride ASW spans both AsU buffers; safe post-barrier
  #pragma unroll
  for (int rg = 0; rg < 2; ++rg){
    #pragma unroll
    for (int q = 0; q < 4; ++q){
      const int row = rg*16 + quad*4 + q;
      const float fs = scrS[0][row] + scrS[1][row] + scrS[2][row] + scrS[3][row];
      const float fq = scrQ[0][row] + scrQ[1][row] + scrQ[2][row] + scrQ[3][row];
      const float mean = fs*(1.f/D);
      const float rstd = rsqrtf(fq*(1.f/D) - mean*mean + 1e-5f);
      #pragma unroll
      for (int f = 0; f < 2; ++f){
        const int c = c0w + f*16 + l15;
        float xv = (v[rg][f][q] - mean)*rstd;
        hout[(size_t)(t0+row)*128 + c] = xv;
        Aw[row*ASW + c] = f2bf(xv);
      }
    }
  }
  wh_phaseS<NH>(Aw, ASW, &Bs[0][0], WT, aatt, t0, WhT, s1, s2, r1s4, r2s4, tid);
}

// ---- score phase helper ------------------------------------------------------
__device__ __forceinline__ float score8(const float* s2s, const unsigned char* mrow,
                                        float s1lr, int k0, int lq, u16* asp){
  float4 sa = *(const float4*)&s2s[k0 + lq*8];
  float4 sb = *(const float4*)&s2s[k0 + lq*8 + 4];
  const u32 mm = mrow[(k0 >> 3) + lq];
  float ss[8] = {sa.x,sa.y,sa.z,sa.w,sb.x,sb.y,sb.z,sb.w};
  float v[8]; float p = 0.f;
  #pragma unroll
  for (int i = 0; i < 8; ++i){
    float e = lrelu(s1lr * ss[i]);
    float ex = ((mm >> i) & 1u) ? __expf(e) : 0.f;
    v[i] = ex; p += ex;
  }
  uint4 u = { pk2(v[0],v[1]), pk2(v[2],v[3]), pk2(v[4],v[5]), pk2(v[6],v[7]) };
  *(uint4*)asp = u;
  return p;
}

// ---------------- attention pv (4 heads, elu, bf16 out) -----------------------
__global__ __launch_bounds__(256) void pv32(
    const float* __restrict__ s1, const float* __restrict__ s2,
    const u32* __restrict__ mbits, const u16* __restrict__ WhT,
    u16* __restrict__ out_)
{
  const int tid = threadIdx.x;
  const int h  = blockIdx.x >> 7;
  const int t0 = (blockIdx.x & 127) * 32;
  const int b = t0 >> 9, i0 = t0 & (N-1);
  __shared__ float s2s[N];
  __shared__ float s1s[32], sums[32];
  __shared__ u32 mbs[32*16];
  __shared__ __align__(16) u16 As[2][32*LS];
  __shared__ __align__(16) u16 Bs[2][128*LS];

  s2s[tid]     = s2[(size_t)h*TOK + b*N + tid];
  s2s[tid+256] = s2[(size_t)h*TOK + b*N + tid + 256];
  if (tid < 32) s1s[tid] = s1[(size_t)h*TOK + t0 + tid];
  { const int r = tid >> 3, wd = (tid & 7)*2;
    *(uint2*)&mbs[r*16 + wd] = *(const uint2*)&mbits[((size_t)b*N + i0 + r)*16 + wd];
  }

  const u16* BTn = WhT + (size_t)(h*8 + b)*128*N;
  const int wave = tid >> 6, lane = tid & 63, quad = lane >> 4, l15 = lane & 15;
  const int c0 = wave*32;
  facc acc[2][2];
  #pragma unroll
  for (int rg = 0; rg < 2; ++rg)
    #pragma unroll
    for (int f = 0; f < 2; ++f) acc[rg][f] = (facc){0.f,0.f,0.f,0.f};

  const int lr = tid >> 3, lq = tid & 7;
  const unsigned char* mrow = (const unsigned char*)&mbs[lr*16];
  const int bn = tid >> 1, bpart = tid & 1;
  const u16* bwp = BTn + (size_t)bn*N + bpart*32;
  float psum = 0.f;

  uint4 g0 = *(const uint4*)bwp,      g1 = *(const uint4*)(bwp+8);
  uint4 g2 = *(const uint4*)(bwp+16), g3 = *(const uint4*)(bwp+24);
  __syncthreads();
  const float s1lr = s1s[lr];
  psum += score8(s2s, mrow, s1lr, 0, lq, &As[0][lr*LS + lq*8]);
  { u16* bp = &Bs[0][bn*LS + bpart*32];
    *(uint4*)bp = g0; *(uint4*)(bp+8) = g1; *(uint4*)(bp+16) = g2; *(uint4*)(bp+24) = g3; }
  __syncthreads();

  #pragma unroll
  for (int k = 0; k < 7; ++k){
    const int cur = k & 1, nxt = cur ^ 1;
    const u16* wp = bwp + (k+1)*64;
    uint4 n0 = *(const uint4*)wp,      n1 = *(const uint4*)(wp+8);
    uint4 n2 = *(const uint4*)(wp+16), n3 = *(const uint4*)(wp+24);
    psum += score8(s2s, mrow, s1lr, (k+1)*64, lq, &As[nxt][lr*LS + lq*8]);
    mfma64w(As[cur], Bs[cur], acc, c0, quad, l15);
    { u16* bp = &Bs[nxt][bn*LS + bpart*32];
      *(uint4*)bp = n0; *(uint4*)(bp+8) = n1; *(uint4*)(bp+16) = n2; *(uint4*)(bp+24) = n3; }
    __syncthreads();
  }
  mfma64w(As[1], Bs[1], acc, c0, quad, l15);

  #pragma unroll
  for (int m = 1; m < 8; m <<= 1) psum += __shfl_xor(psum, m, 64);
  if (lq == 0) sums[lr] = psum;
  __syncthreads();

  #pragma unroll
  for (int rg = 0; rg < 2; ++rg){
    #pragma unroll
    for (int q = 0; q < 4; ++q){
      const int row = rg*16 + quad*4 + q;
      const float sv = sums[row];
      const float inv = sv > 0.f ? 1.f/sv : 0.f;
      const int rq = t0 + row;
      #pragma unroll
      for (int f = 0; f < 2; ++f){
        float xv = acc[rg][f][q] * inv;
        xv = xv > 0.f ? xv : __expf(xv) - 1.f;     // elu
        out_[(size_t)rq*512 + h*128 + c0 + f*16 + l15] = f2bf(xv);
      }
    }
  }
}

// ---------------- output-GAT pv (1 head, lrelu) + colsum (+ optional WH) ------
template<int DOWH>
__global__ __launch_bounds__(256) void pvout(
    const float* __restrict__ s1in, const float* __restrict__ s2in,
    const u32* __restrict__ mbits, const u16* __restrict__ WhTin,
    float* __restrict__ hF, float* __restrict__ colsum,
    const u16* __restrict__ WT, const float* __restrict__ aatt,
    u16* __restrict__ WhTout, float* __restrict__ s1out, float* __restrict__ s2out)
{
  const int tid = threadIdx.x;
  const int t0 = blockIdx.x * 32;
  const int b = t0 >> 9, i0 = t0 & (N-1);
  __shared__ float s2s[N];
  __shared__ float s1s[32], sums[32];
  __shared__ u32 mbs[32*16];
  __shared__ __align__(16) u16 AsU[2][32*LS];
  __shared__ __align__(16) u16 Bs[2][128*LS];
  __shared__ float r1s4[H][2][32], r2s4[H][2][32];

  s2s[tid]     = s2in[b*N + tid];
  s2s[tid+256] = s2in[b*N + tid + 256];
  if (tid < 32) s1s[tid] = s1in[t0 + tid];
  { const int r = tid >> 3, wd = (tid & 7)*2;
    *(uint2*)&mbs[r*16 + wd] = *(const uint2*)&mbits[((size_t)b*N + i0 + r)*16 + wd];
  }

  const u16* BTn = WhTin + (size_t)b*128*N;
  const int wave = tid >> 6, lane = tid & 63, quad = lane >> 4, l15 = lane & 15;
  const int c0w = wave*32;
  facc acc[2][2];
  #pragma unroll
  for (int rg = 0; rg < 2; ++rg)
    #pragma unroll
    for (int f = 0; f < 2; ++f) acc[rg][f] = (facc){0.f,0.f,0.f,0.f};

  const int lr = tid >> 3, lq = tid & 7;
  const unsigned char* mrow = (const unsigned char*)&mbs[lr*16];
  const int bn = tid >> 1, bpart = tid & 1;
  const u16* bwp = BTn + (size_t)bn*N + bpart*32;
  float psum = 0.f;

  uint4 g0 = *(const uint4*)bwp,      g1 = *(const uint4*)(bwp+8);
  uint4 g2 = *(const uint4*)(bwp+16), g3 = *(const uint4*)(bwp+24);
  __syncthreads();
  const float s1lr = s1s[lr];
  psum += score8(s2s, mrow, s1lr, 0, lq, &AsU[0][lr*LS + lq*8]);
  { u16* bp = &Bs[0][bn*LS + bpart*32];
    *(uint4*)bp = g0; *(uint4*)(bp+8) = g1; *(uint4*)(bp+16) = g2; *(uint4*)(bp+24) = g3; }
  __syncthreads();

  #pragma unroll
  for (int k = 0; k < 7; ++k){
    const int cur = k & 1, nxt = cur ^ 1;
    const u16* wp = bwp + (k+1)*64;
    uint4 n0 = *(const uint4*)wp,      n1 = *(const uint4*)(wp+8);
    uint4 n2 = *(const uint4*)(wp+16), n3 = *(const uint4*)(wp+24);
    psum += score8(s2s, mrow, s1lr, (k+1)*64, lq, &AsU[nxt][lr*LS + lq*8]);
    mfma64w(AsU[cur], Bs[cur], acc, c0w, quad, l15);
    { u16* bp = &Bs[nxt][bn*LS + bpart*32];
      *(uint4*)bp = n0; *(uint4*)(bp+8) = n1; *(uint4*)(bp+16) = n2; *(uint4*)(bp+24) = n3; }
    __syncthreads();
  }
  mfma64w(AsU[1], Bs[1], acc, c0w, quad, l15);

  #pragma unroll
  for (int m = 1; m < 8; m <<= 1) psum += __shfl_xor(psum, m, 64);
  if (lq == 0) sums[lr] = psum;
  __syncthreads();

  u16* Aw = &AsU[0][0];      // stride ASW; safe post-barrier
  float pcs[2] = {0.f, 0.f};
  #pragma unroll
  for (int rg = 0; rg < 2; ++rg){
    #pragma unroll
    for (int q = 0; q < 4; ++q){
      const int row = rg*16 + quad*4 + q;
      const float sv = sums[row];
      const float inv = sv > 0.f ? 1.f/sv : 0.f;
      #pragma unroll
      for (int f = 0; f < 2; ++f){
        const int c = c0w + f*16 + l15;
        float xv = lrelu(acc[rg][f][q] * inv);
        if (DOWH){
          hF[(size_t)(t0+row)*128 + c] = xv;
          Aw[row*ASW + c] = f2bf(xv);
        }
        pcs[f] += xv;
      }
    }
  }
  pcs[0] += __shfl_xor(pcs[0], 16, 64); pcs[0] += __shfl_xor(pcs[0], 32, 64);
  pcs[1] += __shfl_xor(pcs[1], 16, 64); pcs[1] += __shfl_xor(pcs[1], 32, 64);
  if (quad == 0){
    atomicAdd(&colsum[b*128 + c0w + l15], pcs[0]);
    atomicAdd(&colsum[b*128 + c0w + 16 + l15], pcs[1]);
  }
  if (DOWH)
    wh_phaseS<H>(Aw, ASW, &Bs[0][0], WT, aatt, t0, WhTout, s1out, s2out, r1s4, r2s4, tid);
}

// ---------------- projection from pre-reduced column sums ---------------------
__global__ void final_kernel(const float* __restrict__ colsumF, const float* __restrict__ colsumT,
                             const float* __restrict__ pW, const float* __restrict__ pb,
                             float* __restrict__ out)
{
  const int b = blockIdx.x, c = threadIdx.x;
  __shared__ float scr[4];
  float s = ((c < D) ? colsumF[b*D + c] : colsumT[b*D + (c - D)]) * (1.f/N);
  float p = s * pW[c];
  #pragma unroll
  for (int m = 32; m; m >>= 1) p += __shfl_xor(p, m, 64);
  if ((c & 63) == 0) scr[c >> 6] = p;
  __syncthreads();
  if (c == 0) out[b] = scr[0] + scr[1] + scr[2] + scr[3] + pb[0];
}

extern "C" void kernel_launch(void* const* d_in, const int* in_sizes, int n_in,
                              void* d_out, int out_size, void* d_ws, size_t ws_size,
                              hipStream_t stream)
{
  (void)in_sizes; (void)n_in; (void)out_size; (void)ws_size;
  const float* x    = (const float*)d_in[0];
  const int*   adj  = (const int*)d_in[1];
  const float* f1w1 = (const float*)d_in[3];
  const float* f1b1 = (const float*)d_in[4];
  const float* f1w2 = (const float*)d_in[5];
  const float* f1b2 = (const float*)d_in[6];
  const float* f2w1 = (const float*)d_in[7];
  const float* f2b1 = (const float*)d_in[8];
  const float* f2w2 = (const float*)d_in[9];
  const float* f2b2 = (const float*)d_in[10];
  const float* f3w1 = (const float*)d_in[11];
  const float* f3b1 = (const float*)d_in[12];
  const float* f3w2 = (const float*)d_in[13];
  const float* f3b2 = (const float*)d_in[14];
  const float* attW = (const float*)d_in[15];
  const float* attA = (const float*)d_in[16];
  const float* rshW = (const float*)d_in[17];
  const float* rshB = (const float*)d_in[18];
  const float* outW = (const float*)d_in[19];
  const float* outA = (const float*)d_in[20];
  const float* pW   = (const float*)d_in[21];
  const float* pb   = (const float*)d_in[22];

  char* w = (char*)d_ws;
  float* hA  = (float*)w; w += (size_t)TOK*128*4;
  float* hB  = (float*)w; w += (size_t)TOK*128*4;
  float* hF  = (float*)w; w += (size_t)TOK*128*4;
  u16*  hp2  = (u16*)w;  w += (size_t)TOK*512*2;
  u16*  WhT  = (u16*)w;  w += (size_t)H*8*128*N*2;
  u16*  WhT2 = (u16*)w;  w += (size_t)H*8*128*N*2;
  float* s1  = (float*)w; w += (size_t)H*TOK*4;
  float* s2  = (float*)w; w += (size_t)H*TOK*4;
  float* s1b = (float*)w; w += (size_t)H*TOK*4;
  float* s2b = (float*)w; w += (size_t)H*TOK*4;
  u32* mbits = (u32*)w;  w += (size_t)B*N*16*4;
  u32* mtbits= (u32*)w;  w += (size_t)B*N*16*4;
  float* colsumF = (float*)w; w += (size_t)B*128*4;
  float* colsumT = (float*)w; w += (size_t)B*128*4;
  u16* f1w1T = (u16*)w; w += 128*32*2;
  u16* f1w2T = (u16*)w; w += 128*128*2;
  u16* f2w1T = (u16*)w; w += 256*128*2;
  u16* f2w2T = (u16*)w; w += 128*256*2;
  u16* f3w1T = (u16*)w; w += 256*128*2;
  u16* f3w2T = (u16*)w; w += 128*256*2;
  u16* attWT = (u16*)w; w += (size_t)24*128*128*2;
  u16* outWT = (u16*)w; w += (size_t)2*128*128*2;
  u16* rshWT = (u16*)w; w += (size_t)6*128*512*2;

  prep_kernel<<<1461,256,0,stream>>>(adj, mbits, mtbits, colsumF, colsumT,
      f1w1, f1w2, f2w1, f2w2, f3w1, f3w2, attW, outW, rshW,
      f1w1T, f1w2T, f2w1T, f2w2T, f3w1T, f3w2T, attWT, outWT, rshWT);

  // FEL (6 GEMMs + 2 LN) fused + WH(att block 0) -> hA, WhT, s1, s2
  fel_kernel<<<128,256,0,stream>>>(x,
      f1w1T, f1b1, f1w2T, f1b2, f2w1T, f2b1, f2w2T, f2b2, f3w1T, f3b1, f3w2T, f3b2,
      attWT, attA, hA, WhT, s1, s2);

  // forward attention blocks 0..2
  pv32<<<H*128,256,0,stream>>>(s1, s2, mbits, WhT, hp2);
  reshwh<4><<<128,256,0,stream>>>(hp2, rshWT + 0*128*512, rshB + 0*D, hA, hB,
      attWT + (size_t)1*H*D*D, attA + (size_t)1*H*2*D, WhT, s1, s2);
  pv32<<<H*128,256,0,stream>>>(s1, s2, mbits, WhT, hp2);
  reshwh<4><<<128,256,0,stream>>>(hp2, rshWT + (size_t)1*128*512, rshB + 1*D, hB, hA,
      attWT + (size_t)2*H*D*D, attA + (size_t)2*H*2*D, WhT, s1, s2);
  pv32<<<H*128,256,0,stream>>>(s1, s2, mbits, WhT, hp2);
  reshwh<1><<<128,256,0,stream>>>(hp2, rshWT + (size_t)2*128*512, rshB + 2*D, hA, hB,
      outWT, outA, WhT, s1, s2);

  // forward output GAT + colsumF + WH(att block 3) -> hF, WhT2, s1b, s2b
  pvout<1><<<128,256,0,stream>>>(s1, s2, mbits, WhT, hF, colsumF,
      attWT + (size_t)3*H*D*D, attA + (size_t)3*H*2*D, WhT2, s1b, s2b);

  // transposed attention blocks 3..5
  pv32<<<H*128,256,0,stream>>>(s1b, s2b, mtbits, WhT2, hp2);
  reshwh<4><<<128,256,0,stream>>>(hp2, rshWT + (size_t)3*128*512, rshB + 3*D, hF, hA,
      attWT + (size_t)4*H*D*D, attA + (size_t)4*H*2*D, WhT, s1, s2);
  pv32<<<H*128,256,0,stream>>>(s1, s2, mtbits, WhT, hp2);
  reshwh<4><<<128,256,0,stream>>>(hp2, rshWT + (size_t)4*128*512, rshB + 4*D, hA, hB,
      attWT + (size_t)5*H*D*D, attA + (size_t)5*H*2*D, WhT, s1, s2);
  pv32<<<H*128,256,0,stream>>>(s1, s2, mtbits, WhT, hp2);
  reshwh<1><<<128,256,0,stream>>>(hp2, rshWT + (size_t)5*128*512, rshB + 5*D, hB, hA,
      outWT + 128*128, outA + 2*D, WhT, s1, s2);

  // transposed output GAT -> colsumT only
  pvout<0><<<128,256,0,stream>>>(s1, s2, mtbits, WhT, nullptr, colsumT,
      nullptr, nullptr, nullptr, nullptr, nullptr);

  final_kernel<<<B,2*D,0,stream>>>(colsumF, colsumT, pW, pb, (float*)d_out);
}

// Round 5
// 303.759 us; speedup vs baseline: 1.2635x; 1.0124x over previous
//
#include <hip/hip_runtime.h>
#include <math.h>

#define B 8
#define N 512
#define D 128
#define H 4
#define TOK (B*N)   // 4096

typedef __attribute__((ext_vector_type(8))) short bfrag;   // 8 bf16 (4 VGPRs)
typedef __attribute__((ext_vector_type(4))) float facc;    // 4 fp32 acc
typedef unsigned short u16;
typedef unsigned int u32;
typedef unsigned long long u64;

__device__ __forceinline__ float lrelu(float x){ return x > 0.f ? x : 0.01f*x; }
__device__ __forceinline__ u16 f2bf(float f){
  u32 u = __float_as_uint(f);
  u += 0x7fffu + ((u >> 16) & 1u);     // RTNE
  return (u16)(u >> 16);
}
__device__ __forceinline__ u32 pk2(float a, float b){
  return (u32)f2bf(a) | ((u32)f2bf(b) << 16);
}

// LDS row strides (u16): all give bank skew 4/row, 16B-aligned rows
#define LS 72        // B tiles / staged A tiles
#define ASF 264      // fel A tiles (K up to 256)
#define ASW 136      // wh-phase A tiles (K=128)

// ---------------- prep: fully parallel, 1 job per block -----------------------
__global__ void prep_kernel(const int* __restrict__ adj,
    u32* __restrict__ mbits, u32* __restrict__ mtbits,
    float* __restrict__ colsumF, float* __restrict__ colsumT,
    const float* s0, const float* s1_, const float* s2_, const float* s3,
    const float* s4, const float* s5, const float* s6, const float* s7,
    const float* s8,
    u16* d0, u16* d1, u16* d2, u16* d3, u16* d4, u16* d5, u16* d6, u16* d7, u16* d8)
{
  __shared__ int smem[64*65];
  const int tid = threadIdx.x;
  if (blockIdx.x < 512){
    const int tb = blockIdx.x;
    const int b = tb >> 6, i0 = ((tb >> 3) & 7)*64, j0 = (tb & 7)*64;
    #pragma unroll
    for (int i = 0; i < 4; ++i){
      const int r = i*16 + (tid >> 4);
      const int c = (tid & 15)*4;
      int4 v = *(const int4*)&adj[((size_t)b*N + i0 + r)*N + j0 + c];
      smem[r*65 + c]     = v.x; smem[r*65 + c + 1] = v.y;
      smem[r*65 + c + 2] = v.z; smem[r*65 + c + 3] = v.w;
    }
    __syncthreads();
    const int wv = tid >> 6, lane = tid & 63;
    #pragma unroll
    for (int q = 0; q < 16; ++q){
      const int r = wv*16 + q;
      u64 bf_ = __ballot(smem[r*65 + lane] > 0);
      if (lane == 0)
        *(u64*)&mbits[((size_t)b*N + i0 + r)*16 + (j0 >> 5)] = bf_;
      u64 bt_ = __ballot(smem[lane*65 + r] > 0);
      if (lane == 0)
        *(u64*)&mtbits[((size_t)b*N + j0 + r)*16 + (i0 >> 5)] = bt_;
    }
  } else if (blockIdx.x < 1460){
    float* ftile = (float*)smem;        // [32][33]
    const int tx = tid & 31, ty = tid >> 5;
    const float* srcs[9] = {s0,s1_,s2_,s3,s4,s5,s6,s7,s8};
    u16* dsts[9] = {d0,d1,d2,d3,d4,d5,d6,d7,d8};
    const int Ks[9] = {32,128,128,256,128,256,128,128,512};
    const int Ns[9] = {128,128,256,128,256,128,128,128,128};
    const int zs[9] = {1,1,1,1,1,1,24,2,6};
    const int job = (int)blockIdx.x - 512;      // [0,948)
    int m = 0, base = 0;
    for (; m < 9; ++m){
      int cnt = (Ks[m]>>5)*(Ns[m]>>5)*zs[m];
      if (job < base + cnt) break;
      base += cnt;
    }
    const int rem = job - base;
    const int tn = Ns[m] >> 5;
    const int per = (Ks[m] >> 5)*tn;
    const int z = rem / per, t = rem % per;
    const int k0 = (t / tn)*32, n0 = (t % tn)*32;
    const float* src = srcs[m] + (size_t)z*Ks[m]*Ns[m];
    u16* dst = dsts[m] + (size_t)z*Ks[m]*Ns[m];
    for (int r = ty; r < 32; r += 8)
      ftile[r*33 + tx] = src[(size_t)(k0+r)*Ns[m] + n0 + tx];
    __syncthreads();
    for (int r = ty; r < 32; r += 8)
      dst[(size_t)(n0+r)*Ks[m] + k0 + tx] = f2bf(ftile[tx*33 + r]);
  } else {
    float4 z = {0.f,0.f,0.f,0.f};
    *(float4*)&colsumF[tid*4] = z;
    *(float4*)&colsumT[tid*4] = z;
  }
}

// ---- staging helpers ---------------------------------------------------------
struct BPre { uint4 a,b,c,d; };
__device__ __forceinline__ BPre preB64(const u16* __restrict__ BTn, int ldb, int k0, int tid){
  const int n = tid >> 1, part = tid & 1;
  const u16* wp = BTn + (size_t)n*ldb + k0 + part*32;
  BPre r;
  r.a = *(const uint4*)wp;      r.b = *(const uint4*)(wp+8);
  r.c = *(const uint4*)(wp+16); r.d = *(const uint4*)(wp+24);
  return r;
}
__device__ __forceinline__ void landB64(const BPre& p, u16* Bs, int tid){
  const int n = tid >> 1, part = tid & 1;
  u16* bp = &Bs[n*LS + part*32];
  *(uint4*)bp = p.a; *(uint4*)(bp+8) = p.b; *(uint4*)(bp+16) = p.c; *(uint4*)(bp+24) = p.d;
}
__device__ __forceinline__ void stageB32(const u16* __restrict__ BTn, int ldb,
                                         int k0, u16* Bs, int tid){
  const int n = tid >> 1, part = tid & 1;
  const u16* wp = BTn + (size_t)n*ldb + k0 + part*16;
  uint4 w0 = *(const uint4*)wp, w1 = *(const uint4*)(wp+8);
  *(uint4*)&Bs[n*LS + part*16]     = w0;
  *(uint4*)&Bs[n*LS + part*16 + 8] = w1;
}
// 64-row (group-half) B staging: 256 group-threads, 16 u16 each
struct BPre2 { uint4 a,b; };
__device__ __forceinline__ BPre2 preBh(const u16* __restrict__ BTn, int ldb, int k0,
                                       int gtid, int rowoff){
  const u16* wp = BTn + (size_t)(rowoff + (gtid >> 2))*ldb + k0 + (gtid & 3)*16;
  BPre2 r; r.a = *(const uint4*)wp; r.b = *(const uint4*)(wp+8);
  return r;
}
__device__ __forceinline__ void landBh(const BPre2& p, u16* Bs, int gtid){
  u16* bp = &Bs[(gtid >> 2)*LS + (gtid & 3)*16];
  *(uint4*)bp = p.a; *(uint4*)(bp+8) = p.b;
}

// ---- MFMA cores --------------------------------------------------------------
// 4-wave 32x128 mapping (stride-parameterized A)
__device__ __forceinline__ void mfma64s(const u16* As, int sA, const u16* Bs,
                                        facc acc[4], int r0, int c0, int quad, int l15){
  #pragma unroll
  for (int kk = 0; kk < 2; ++kk){
    bfrag af = *(const bfrag*)&As[(r0 + l15)*sA + kk*32 + quad*8];
    #pragma unroll
    for (int g = 0; g < 4; ++g){
      bfrag bf = *(const bfrag*)&Bs[(c0 + g*16 + l15)*LS + kk*32 + quad*8];
      acc[g] = __builtin_amdgcn_mfma_f32_16x16x32_bf16(af, bf, acc[g], 0,0,0);
    }
  }
}
__device__ __forceinline__ void mfma32s(const u16* As, int sA, const u16* Bs,
                                        facc acc[4], int r0, int c0, int quad, int l15){
  bfrag af = *(const bfrag*)&As[(r0 + l15)*sA + quad*8];
  #pragma unroll
  for (int g = 0; g < 4; ++g){
    bfrag bf = *(const bfrag*)&Bs[(c0 + g*16 + l15)*LS + quad*8];
    acc[g] = __builtin_amdgcn_mfma_f32_16x16x32_bf16(af, bf, acc[g], 0,0,0);
  }
}
// wave = 32 rows x 32 cols (pvout)
__device__ __forceinline__ void mfma64w(const u16* As, const u16* Bs,
                                        facc acc[2][2], int c0,
                                        int quad, int l15){
  #pragma unroll
  for (int kk = 0; kk < 2; ++kk){
    bfrag af0 = *(const bfrag*)&As[(l15)*LS      + kk*32 + quad*8];
    bfrag af1 = *(const bfrag*)&As[(16 + l15)*LS + kk*32 + quad*8];
    #pragma unroll
    for (int f = 0; f < 2; ++f){
      bfrag bf = *(const bfrag*)&Bs[(c0 + f*16 + l15)*LS + kk*32 + quad*8];
      acc[0][f] = __builtin_amdgcn_mfma_f32_16x16x32_bf16(af0, bf, acc[0][f], 0,0,0);
      acc[1][f] = __builtin_amdgcn_mfma_f32_16x16x32_bf16(af1, bf, acc[1][f], 0,0,0);
    }
  }
}
// wave = 32 rows x 16 cols (col-split groups in pv32/reshwh)
__device__ __forceinline__ void mfma64h(const u16* As, const u16* Bs,
                                        facc acc[2], int c0, int quad, int l15){
  #pragma unroll
  for (int kk = 0; kk < 2; ++kk){
    bfrag af0 = *(const bfrag*)&As[(l15)*LS      + kk*32 + quad*8];
    bfrag af1 = *(const bfrag*)&As[(16 + l15)*LS + kk*32 + quad*8];
    bfrag bf  = *(const bfrag*)&Bs[(c0 + l15)*LS + kk*32 + quad*8];
    acc[0] = __builtin_amdgcn_mfma_f32_16x16x32_bf16(af0, bf, acc[0], 0,0,0);
    acc[1] = __builtin_amdgcn_mfma_f32_16x16x32_bf16(af1, bf, acc[1], 0,0,0);
  }
}

// ---- single-buffer A-in-LDS GEMM over T 64-wide K tiles (fel) ----------------
template<int T>
__device__ __forceinline__ void gemmAs(const u16* Aw, int sA,
    const u16* __restrict__ BT, int ldb, u16* Bs,
    facc acc[4], int tid, int r0, int c0, int quad, int l15){
  BPre p = preB64(BT, ldb, 0, tid);
  #pragma unroll
  for (int t = 0; t < T; ++t){
    __syncthreads();                       // Bs writable; A writes visible below
    landB64(p, Bs, tid);
    if (t + 1 < T) p = preB64(BT, ldb, (t+1)*64, tid);
    __syncthreads();
    mfma64s(Aw + t*64, sA, Bs, acc, r0, c0, quad, l15);
  }
}

// ---- WH phase (single-buffer, 256-thread version: fel / pvout) ---------------
template<int NH>
__device__ __forceinline__ void wh_phaseS(const u16* Aw, int sA, u16* Bs,
    const u16* __restrict__ WT, const float* __restrict__ aatt,
    int t0, u16* __restrict__ WhT, float* __restrict__ s1, float* __restrict__ s2,
    float (*r1s4)[2][32], float (*r2s4)[2][32], int tid)
{
  const int wave = tid >> 6, lane = tid & 63, quad = lane >> 4, l15 = lane & 15;
  const int r0 = (wave & 1)*16, c0 = (wave >> 1)*64;
  const int b = t0 >> 9, j0 = t0 & (N-1);
  BPre p = preB64(WT, D, 0, tid);
  facc acc[4];
  #pragma unroll
  for (int t = 0; t < 2*NH; ++t){
    if ((t & 1) == 0){
      #pragma unroll
      for (int g = 0; g < 4; ++g) acc[g] = (facc){0.f,0.f,0.f,0.f};
    }
    __syncthreads();                       // Bs writable; Aw visible
    landB64(p, Bs, tid);
    if (t + 1 < 2*NH) p = preB64(WT + (size_t)((t+1)>>1)*D*D, D, ((t+1)&1)*64, tid);
    __syncthreads();
    mfma64s(Aw + (t&1)*64, sA, Bs, acc, r0, c0, quad, l15);
    if (t & 1){
      const int h = t >> 1;
      const float* ah = aatt + (size_t)h*2*D;
      const size_t obase = (size_t)(h*8 + b)*128;
      float p1[4] = {0,0,0,0}, p2[4] = {0,0,0,0};
      #pragma unroll
      for (int g = 0; g < 4; ++g){
        const int c = c0 + g*16 + l15;
        const float a1v = ah[c], a2v = ah[D + c];
        ushort4 wv;
        wv.x = f2bf(acc[g][0]); wv.y = f2bf(acc[g][1]);
        wv.z = f2bf(acc[g][2]); wv.w = f2bf(acc[g][3]);
        *(ushort4*)&WhT[(obase + c)*N + j0 + r0 + quad*4] = wv;
        #pragma unroll
        for (int q = 0; q < 4; ++q){
          p1[q] = fmaf(acc[g][q], a1v, p1[q]);
          p2[q] = fmaf(acc[g][q], a2v, p2[q]);
        }
      }
      #pragma unroll
      for (int m = 1; m < 16; m <<= 1){
        #pragma unroll
        for (int q = 0; q < 4; ++q){ p1[q] += __shfl_xor(p1[q], m, 64); p2[q] += __shfl_xor(p2[q], m, 64); }
      }
      if (l15 == 0){
        #pragma unroll
        for (int q = 0; q < 4; ++q){
          r1s4[h][wave>>1][r0 + quad*4 + q] = p1[q];
          r2s4[h][wave>>1][r0 + quad*4 + q] = p2[q];
        }
      }
    }
  }
  __syncthreads();
  if (tid < 32*NH){
    const int h = tid >> 5, r = tid & 31;
    s1[(size_t)h*TOK + t0 + r] = r1s4[h][0][r] + r1s4[h][1][r];
    s2[(size_t)h*TOK + t0 + r] = r2s4[h][0][r] + r2s4[h][1][r];
  }
}

// ---------------- fused FEL (6 GEMMs + LN x2) + WH of att block 0 -------------
__global__ __launch_bounds__(256) void fel_kernel(
    const float* __restrict__ x,
    const u16* __restrict__ w1T, const float* __restrict__ b1,
    const u16* __restrict__ w2T, const float* __restrict__ b2,
    const u16* __restrict__ w3T, const float* __restrict__ b3,
    const u16* __restrict__ w4T, const float* __restrict__ b4,
    const u16* __restrict__ w5T, const float* __restrict__ b5,
    const u16* __restrict__ w6T, const float* __restrict__ b6,
    const u16* __restrict__ WTatt, const float* __restrict__ aatt,
    float* __restrict__ hout, u16* __restrict__ WhT,
    float* __restrict__ s1, float* __restrict__ s2)
{
  const int tid = threadIdx.x;
  const int t0 = blockIdx.x * 32;
  __shared__ __align__(16) u16 AwA[32*ASF];
  __shared__ __align__(16) u16 AwB[32*ASF];
  __shared__ __align__(16) u16 Bs[128*LS];
  __shared__ float scrS[4][16], scrQ[4][16];
  __shared__ float r1s4[H][2][32], r2s4[H][2][32];
  const int wave = tid >> 6, lane = tid & 63, quad = lane >> 4, l15 = lane & 15;
  const int r0 = (wave & 1)*16, c0 = (wave >> 1)*64;
  facc acc[4];
  float rres[4][4];

  // ---- S1: t1 = lrelu(x@f1w1+b1)  (K=32) -> AwB
  { const int row = tid >> 3, ko = tid & 7;
    float4 a0 = *(const float4*)(x + (size_t)(t0+row)*32 + ko*4);
    uint2 u = { pk2(a0.x,a0.y), pk2(a0.z,a0.w) };
    *(uint2*)&AwA[row*ASF + ko*4] = u;
    stageB32(w1T, 32, 0, Bs, tid);
  }
  __syncthreads();
  #pragma unroll
  for (int g = 0; g < 4; ++g) acc[g] = (facc){0.f,0.f,0.f,0.f};
  mfma32s(AwA, ASF, Bs, acc, r0, c0, quad, l15);
  #pragma unroll
  for (int g = 0; g < 4; ++g){
    const int c = c0 + g*16 + l15;
    const float bv = b1[c];
    #pragma unroll
    for (int q = 0; q < 4; ++q)
      AwB[(r0 + quad*4 + q)*ASF + c] = f2bf(lrelu(acc[g][q] + bv));
  }

  // ---- S2: res = lrelu(t1@f1w2+b2) (K=128) -> AwA + rres
  #pragma unroll
  for (int g = 0; g < 4; ++g) acc[g] = (facc){0.f,0.f,0.f,0.f};
  gemmAs<2>(AwB, ASF, w2T, 128, Bs, acc, tid, r0, c0, quad, l15);
  #pragma unroll
  for (int g = 0; g < 4; ++g){
    const int c = c0 + g*16 + l15;
    const float bv = b2[c];
    #pragma unroll
    for (int q = 0; q < 4; ++q){
      float xv = lrelu(acc[g][q] + bv);
      AwA[(r0 + quad*4 + q)*ASF + c] = f2bf(xv);
      rres[g][q] = xv;
    }
  }

  // ---- S3: t3 = lrelu(res@f2w1+b3) (K=128, out 256) -> AwB
  #pragma unroll
  for (int ch = 0; ch < 2; ++ch){
    #pragma unroll
    for (int g = 0; g < 4; ++g) acc[g] = (facc){0.f,0.f,0.f,0.f};
    gemmAs<2>(AwA, ASF, w3T + (size_t)ch*128*128, 128, Bs, acc, tid, r0, c0, quad, l15);
    #pragma unroll
    for (int g = 0; g < 4; ++g){
      const int c = c0 + g*16 + l15;
      const float bv = b3[ch*128 + c];
      #pragma unroll
      for (int q = 0; q < 4; ++q)
        AwB[(r0 + quad*4 + q)*ASF + ch*128 + c] = f2bf(lrelu(acc[g][q] + bv));
    }
  }

  // ---- S4: x1 = LN(lrelu(t3@f2w2+b4) + res) (K=256) -> AwA + rres
  #pragma unroll
  for (int g = 0; g < 4; ++g) acc[g] = (facc){0.f,0.f,0.f,0.f};
  gemmAs<4>(AwB, ASF, w4T, 256, Bs, acc, tid, r0, c0, quad, l15);
  {
    float v[4][4], s[4] = {0,0,0,0}, sq[4] = {0,0,0,0};
    #pragma unroll
    for (int g = 0; g < 4; ++g){
      const int c = c0 + g*16 + l15;
      const float bv = b4[c];
      #pragma unroll
      for (int q = 0; q < 4; ++q){
        float xv = lrelu(acc[g][q] + bv) + rres[g][q];
        v[g][q] = xv; s[q] += xv; sq[q] += xv*xv;
      }
    }
    #pragma unroll
    for (int m = 1; m < 16; m <<= 1){
      #pragma unroll
      for (int q = 0; q < 4; ++q){ s[q] += __shfl_xor(s[q], m, 64); sq[q] += __shfl_xor(sq[q], m, 64); }
    }
    if (l15 == 0){
      #pragma unroll
      for (int q = 0; q < 4; ++q){ scrS[wave][quad*4+q] = s[q]; scrQ[wave][quad*4+q] = sq[q]; }
    }
    __syncthreads();
    #pragma unroll
    for (int q = 0; q < 4; ++q){
      const int r = r0 + quad*4 + q;
      const float fs = s[q] + scrS[wave^2][quad*4+q];
      const float fq = sq[q] + scrQ[wave^2][quad*4+q];
      const float mean = fs*(1.f/D);
      const float rstd = rsqrtf(fq*(1.f/D) - mean*mean + 1e-5f);
      #pragma unroll
      for (int g = 0; g < 4; ++g){
        const int c = c0 + g*16 + l15;
        float xv = (v[g][q] - mean)*rstd;
        AwA[r*ASF + c] = f2bf(xv);
        rres[g][q] = xv;
      }
    }
  }

  // ---- S5: t5 = lrelu(x1@f3w1+b5) (K=128, out 256) -> AwB
  #pragma unroll
  for (int ch = 0; ch < 2; ++ch){
    #pragma unroll
    for (int g = 0; g < 4; ++g) acc[g] = (facc){0.f,0.f,0.f,0.f};
    gemmAs<2>(AwA, ASF, w5T + (size_t)ch*128*128, 128, Bs, acc, tid, r0, c0, quad, l15);
    #pragma unroll
    for (int g = 0; g < 4; ++g){
      const int c = c0 + g*16 + l15;
      const float bv = b5[ch*128 + c];
      #pragma unroll
      for (int q = 0; q < 4; ++q)
        AwB[(r0 + quad*4 + q)*ASF + ch*128 + c] = f2bf(lrelu(acc[g][q] + bv));
    }
  }

  // ---- S6: out = LN(t5@f3w2+b6 + x1) (K=256) -> hout (fp32) + AwA (bf16)
  #pragma unroll
  for (int g = 0; g < 4; ++g) acc[g] = (facc){0.f,0.f,0.f,0.f};
  gemmAs<4>(AwB, ASF, w6T, 256, Bs, acc, tid, r0, c0, quad, l15);
  {
    float v[4][4], s[4] = {0,0,0,0}, sq[4] = {0,0,0,0};
    #pragma unroll
    for (int g = 0; g < 4; ++g){
      const int c = c0 + g*16 + l15;
      const float bv = b6[c];
      #pragma unroll
      for (int q = 0; q < 4; ++q){
        float xv = acc[g][q] + bv + rres[g][q];
        v[g][q] = xv; s[q] += xv; sq[q] += xv*xv;
      }
    }
    #pragma unroll
    for (int m = 1; m < 16; m <<= 1){
      #pragma unroll
      for (int q = 0; q < 4; ++q){ s[q] += __shfl_xor(s[q], m, 64); sq[q] += __shfl_xor(sq[q], m, 64); }
    }
    if (l15 == 0){
      #pragma unroll
      for (int q = 0; q < 4; ++q){ scrS[wave][quad*4+q] = s[q]; scrQ[wave][quad*4+q] = sq[q]; }
    }
    __syncthreads();
    #pragma unroll
    for (int q = 0; q < 4; ++q){
      const int r = r0 + quad*4 + q;
      const float fs = s[q] + scrS[wave^2][quad*4+q];
      const float fq = sq[q] + scrQ[wave^2][quad*4+q];
      const float mean = fs*(1.f/D);
      const float rstd = rsqrtf(fq*(1.f/D) - mean*mean + 1e-5f);
      #pragma unroll
      for (int g = 0; g < 4; ++g){
        const int c = c0 + g*16 + l15;
        float xv = (v[g][q] - mean)*rstd;
        hout[(size_t)(t0 + r)*128 + c] = xv;
        AwA[r*ASF + c] = f2bf(xv);
      }
    }
  }
  wh_phaseS<H>(AwA, ASF, Bs, WTatt, aatt, t0, WhT, s1, s2, r1s4, r2s4, tid);
}

// ---------------- reshwh (512 thr): resh GEMM col-split + LN + WH head-split --
template<int NH>
__global__ __launch_bounds__(512) void reshwh(
    const u16* __restrict__ A, const u16* __restrict__ BT, const float* __restrict__ bias,
    const float* __restrict__ res, float* __restrict__ hout,
    const u16* __restrict__ WT, const float* __restrict__ aatt,
    u16* __restrict__ WhT, float* __restrict__ s1, float* __restrict__ s2)
{
  const int tid = threadIdx.x;
  const int t0 = blockIdx.x * 32;
  __shared__ __align__(16) u16 AsU[2][32*LS];        // A dbuf; reused as Aw (ASW)
  __shared__ __align__(16) u16 Bsg[2][2][64*LS];     // [group][buf]; wh reuses [128*LS]
  __shared__ float scrS[8][32], scrQ[8][32];
  __shared__ float r1s4[NH][2][32], r2s4[NH][2][32];
  const int g = tid >> 8, gtid = tid & 255;
  const int w8 = tid >> 6, lane = tid & 63, quad = lane >> 4, l15 = lane & 15;
  const int wv = gtid >> 6;            // group-local wave 0..3
  const int c0h = wv*16;               // col within group's 64-col half

  // ---- resh GEMM: out cols g*64 + c0h + l15, K=512, dbuf + reg prefetch ----
  facc acc2[2];
  acc2[0] = (facc){0.f,0.f,0.f,0.f}; acc2[1] = (facc){0.f,0.f,0.f,0.f};
  const int arow = tid >> 4, ako = tid & 15;
  const u16* aptr = A + (size_t)(t0+arow)*512 + ako*4;
  { uint2 a0 = *(const uint2*)aptr;
    BPre2 b0 = preBh(BT, 512, 0, gtid, g*64);
    *(uint2*)&AsU[0][arow*LS + ako*4] = a0;
    landBh(b0, Bsg[g][0], gtid);
  }
  __syncthreads();
  #pragma unroll
  for (int k = 0; k < 7; ++k){
    const int cur = k & 1, nxt = cur ^ 1;
    uint2 na = *(const uint2*)(aptr + (k+1)*64);
    BPre2 nb = preBh(BT, 512, (k+1)*64, gtid, g*64);
    mfma64h(AsU[cur], Bsg[g][cur], acc2, c0h, quad, l15);
    *(uint2*)&AsU[nxt][arow*LS + ako*4] = na;
    landBh(nb, Bsg[g][nxt], gtid);
    __syncthreads();
  }
  mfma64h(AsU[1], Bsg[g][1], acc2, c0h, quad, l15);

  // ---- bias + residual + LN (8-wave cross reduce) ----
  const int c = g*64 + c0h + l15;
  const float bv = bias[c];
  float v[2][4], s[2][4], sq[2][4];
  #pragma unroll
  for (int rg = 0; rg < 2; ++rg){
    #pragma unroll
    for (int q = 0; q < 4; ++q){
      const int rq = t0 + rg*16 + quad*4 + q;
      float xv = acc2[rg][q] + bv + res[(size_t)rq*128 + c];
      v[rg][q] = xv; s[rg][q] = xv; sq[rg][q] = xv*xv;
    }
  }
  #pragma unroll
  for (int m = 1; m < 16; m <<= 1){
    #pragma unroll
    for (int rg = 0; rg < 2; ++rg)
      #pragma unroll
      for (int q = 0; q < 4; ++q){ s[rg][q] += __shfl_xor(s[rg][q], m, 64); sq[rg][q] += __shfl_xor(sq[rg][q], m, 64); }
  }
  if (l15 == 0){
    #pragma unroll
    for (int rg = 0; rg < 2; ++rg)
      #pragma unroll
      for (int q = 0; q < 4; ++q){
        scrS[w8][rg*16 + quad*4 + q] = s[rg][q];
        scrQ[w8][rg*16 + quad*4 + q] = sq[rg][q];
      }
  }
  __syncthreads();    // scr visible; also: all resh MFMA reads of AsU/Bsg done
  u16* Aw = &AsU[0][0];                // stride ASW (32x136 fits 2x32x72)
  #pragma unroll
  for (int rg = 0; rg < 2; ++rg){
    #pragma unroll
    for (int q = 0; q < 4; ++q){
      const int row = rg*16 + quad*4 + q;
      float fs = 0.f, fq = 0.f;
      #pragma unroll
      for (int w = 0; w < 8; ++w){ fs += scrS[w][row]; fq += scrQ[w][row]; }
      const float mean = fs*(1.f/D);
      const float rstd = rsqrtf(fq*(1.f/D) - mean*mean + 1e-5f);
      float xv = (v[rg][q] - mean)*rstd;
      hout[(size_t)(t0+row)*128 + c] = xv;
      Aw[row*ASW + c] = f2bf(xv);
    }
  }
  __syncthreads();    // Aw fully written

  // ---- WH phase: group g -> heads {2g,2g+1} (NH=4) or head 0 (NH=1) ----
  const int NHg = (NH == 4) ? 2 : 1;
  const int hbase = (NH == 4) ? g*2 : 0;
  const bool st = (NH == 4) || (g == 0);
  u16* BsW = &Bsg[g][0][0];            // contiguous [128*LS]
  const int r0w = (wv & 1)*16, c0w = (wv >> 1)*64;
  const int b = t0 >> 9, j0 = t0 & (N-1);
  facc acc[4];
  BPre p = preB64(WT + (size_t)hbase*D*D, D, 0, gtid);
  #pragma unroll
  for (int t = 0; t < 2*NHg; ++t){
    if ((t & 1) == 0){
      #pragma unroll
      for (int gg = 0; gg < 4; ++gg) acc[gg] = (facc){0.f,0.f,0.f,0.f};
    }
    __syncthreads();                   // BsW writable
    landB64(p, BsW, gtid);
    if (t + 1 < 2*NHg){
      const int hn = hbase + ((t+1) >> 1);
      p = preB64(WT + (size_t)hn*D*D, D, ((t+1)&1)*64, gtid);
    }
    __syncthreads();
    mfma64s(Aw + (t&1)*64, ASW, BsW, acc, r0w, c0w, quad, l15);
    if (t & 1){
      const int h = hbase + (t >> 1);
      const float* ah = aatt + (size_t)h*2*D;
      const size_t obase = (size_t)(h*8 + b)*128;
      float p1[4] = {0,0,0,0}, p2[4] = {0,0,0,0};
      #pragma unroll
      for (int gg = 0; gg < 4; ++gg){
        const int cc = c0w + gg*16 + l15;
        const float a1v = ah[cc], a2v = ah[D + cc];
        if (st){
          ushort4 wvv;
          wvv.x = f2bf(acc[gg][0]); wvv.y = f2bf(acc[gg][1]);
          wvv.z = f2bf(acc[gg][2]); wvv.w = f2bf(acc[gg][3]);
          *(ushort4*)&WhT[(obase + cc)*N + j0 + r0w + quad*4] = wvv;
        }
        #pragma unroll
        for (int q = 0; q < 4; ++q){
          p1[q] = fmaf(acc[gg][q], a1v, p1[q]);
          p2[q] = fmaf(acc[gg][q], a2v, p2[q]);
        }
      }
      #pragma unroll
      for (int m = 1; m < 16; m <<= 1){
        #pragma unroll
        for (int q = 0; q < 4; ++q){ p1[q] += __shfl_xor(p1[q], m, 64); p2[q] += __shfl_xor(p2[q], m, 64); }
      }
      if (st && l15 == 0){
        #pragma unroll
        for (int q = 0; q < 4; ++q){
          r1s4[h][wv>>1][r0w + quad*4 + q] = p1[q];
          r2s4[h][wv>>1][r0w + quad*4 + q] = p2[q];
        }
      }
    }
  }
  __syncthreads();
  if (tid < 32*NH){
    const int h = tid >> 5, r = tid & 31;
    s1[(size_t)h*TOK + t0 + r] = r1s4[h][0][r] + r1s4[h][1][r];
    s2[(size_t)h*TOK + t0 + r] = r2s4[h][0][r] + r2s4[h][1][r];
  }
}

// ---- score helper: 4 cols of one row, bitmask from LDS -----------------------
__device__ __forceinline__ float score4(const float* s2s, const unsigned char* mrow,
                                        float s1lr, int k0, int ls, u16* asp){
  float4 sa = *(const float4*)&s2s[k0 + ls*4];
  const u32 mm = (u32)(mrow[(k0 >> 3) + (ls >> 1)]) >> ((ls & 1)*4);
  float ss[4] = {sa.x,sa.y,sa.z,sa.w};
  float v[4]; float p = 0.f;
  #pragma unroll
  for (int i = 0; i < 4; ++i){
    float e = lrelu(s1lr * ss[i]);
    float ex = ((mm >> i) & 1u) ? __expf(e) : 0.f;
    v[i] = ex; p += ex;
  }
  uint2 u = { pk2(v[0],v[1]), pk2(v[2],v[3]) };
  *(uint2*)asp = u;
  return p;
}
// 8-col variant for pvout (256 thr)
__device__ __forceinline__ float score8(const float* s2s, const unsigned char* mrow,
                                        float s1lr, int k0, int lq, u16* asp){
  float4 sa = *(const float4*)&s2s[k0 + lq*8];
  float4 sb = *(const float4*)&s2s[k0 + lq*8 + 4];
  const u32 mm = mrow[(k0 >> 3) + lq];
  float ss[8] = {sa.x,sa.y,sa.z,sa.w,sb.x,sb.y,sb.z,sb.w};
  float v[8]; float p = 0.f;
  #pragma unroll
  for (int i = 0; i < 8; ++i){
    float e = lrelu(s1lr * ss[i]);
    float ex = ((mm >> i) & 1u) ? __expf(e) : 0.f;
    v[i] = ex; p += ex;
  }
  uint4 u = { pk2(v[0],v[1]), pk2(v[2],v[3]), pk2(v[4],v[5]), pk2(v[6],v[7]) };
  *(uint4*)asp = u;
  return p;
}

// ---------------- attention pv (512 thr, col-split groups, elu, bf16 out) -----
__global__ __launch_bounds__(512) void pv32(
    const float* __restrict__ s1, const float* __restrict__ s2,
    const u32* __restrict__ mbits, const u16* __restrict__ WhT,
    u16* __restrict__ out_)
{
  const int tid = threadIdx.x;
  const int h  = blockIdx.x >> 7;
  const int t0 = (blockIdx.x & 127) * 32;
  const int b = t0 >> 9, i0 = t0 & (N-1);
  __shared__ float s2s[N];
  __shared__ float s1s[32], sums[32];
  __shared__ u32 mbs[32*16];
  __shared__ __align__(16) u16 As[2][32*LS];
  __shared__ __align__(16) u16 Bs[2][2][64*LS];     // [group][buf]

  const int g = tid >> 8, gtid = tid & 255;
  const int lane = tid & 63, quad = lane >> 4, l15 = lane & 15;
  const int wv = gtid >> 6;
  const int c0h = wv*16;

  s2s[tid] = s2[(size_t)h*TOK + b*N + tid];
  if (tid < 32) s1s[tid] = s1[(size_t)h*TOK + t0 + tid];
  mbs[tid] = mbits[((size_t)b*N + i0 + (tid >> 4))*16 + (tid & 15)];

  const u16* BTn = WhT + (size_t)(h*8 + b)*128*N;
  facc acc2[2];
  acc2[0] = (facc){0.f,0.f,0.f,0.f}; acc2[1] = (facc){0.f,0.f,0.f,0.f};

  const int lr = tid >> 4, ls = tid & 15;
  const unsigned char* mrow = (const unsigned char*)&mbs[lr*16];
  float psum = 0.f;

  // prologue
  BPre2 p0 = preBh(BTn, N, 0, gtid, g*64);
  __syncthreads();                      // s2s/s1s/mbs visible
  const float s1lr = s1s[lr];
  psum += score4(s2s, mrow, s1lr, 0, ls, &As[0][lr*LS + ls*4]);
  landBh(p0, Bs[g][0], gtid);
  __syncthreads();

  #pragma unroll
  for (int k = 0; k < 7; ++k){
    const int cur = k & 1, nxt = cur ^ 1;
    BPre2 np = preBh(BTn, N, (k+1)*64, gtid, g*64);
    psum += score4(s2s, mrow, s1lr, (k+1)*64, ls, &As[nxt][lr*LS + ls*4]);
    mfma64h(As[cur], Bs[g][cur], acc2, c0h, quad, l15);
    landBh(np, Bs[g][nxt], gtid);
    __syncthreads();
  }
  mfma64h(As[1], Bs[g][1], acc2, c0h, quad, l15);

  #pragma unroll
  for (int m = 1; m < 16; m <<= 1) psum += __shfl_xor(psum, m, 64);
  if (ls == 0) sums[lr] = psum;
  __syncthreads();

  #pragma unroll
  for (int rg = 0; rg < 2; ++rg){
    #pragma unroll
    for (int q = 0; q < 4; ++q){
      const int row = rg*16 + quad*4 + q;
      const float sv = sums[row];
      const float inv = sv > 0.f ? 1.f/sv : 0.f;
      float xv = acc2[rg][q] * inv;
      xv = xv > 0.f ? xv : __expf(xv) - 1.f;     // elu
      out_[(size_t)(t0+row)*512 + h*128 + g*64 + c0h + l15] = f2bf(xv);
    }
  }
}

// ---------------- output-GAT pv (1 head, lrelu) + colsum (+ optional WH) ------
template<int DOWH>
__global__ __launch_bounds__(256) void pvout(
    const float* __restrict__ s1in, const float* __restrict__ s2in,
    const u32* __restrict__ mbits, const u16* __restrict__ WhTin,
    float* __restrict__ hF, float* __restrict__ colsum,
    const u16* __restrict__ WT, const float* __restrict__ aatt,
    u16* __restrict__ WhTout, float* __restrict__ s1out, float* __restrict__ s2out)
{
  const int tid = threadIdx.x;
  const int t0 = blockIdx.x * 32;
  const int b = t0 >> 9, i0 = t0 & (N-1);
  __shared__ float s2s[N];
  __shared__ float s1s[32], sums[32];
  __shared__ u32 mbs[32*16];
  __shared__ __align__(16) u16 AsU[2][32*LS];
  __shared__ __align__(16) u16 Bs[2][128*LS];
  __shared__ float r1s4[H][2][32], r2s4[H][2][32];

  s2s[tid]     = s2in[b*N + tid];
  s2s[tid+256] = s2in[b*N + tid + 256];
  if (tid < 32) s1s[tid] = s1in[t0 + tid];
  { const int r = tid >> 3, wd = (tid & 7)*2;
    *(uint2*)&mbs[r*16 + wd] = *(const uint2*)&mbits[((size_t)b*N + i0 + r)*16 + wd];
  }

  const u16* BTn = WhTin + (size_t)b*128*N;
  const int wave = tid >> 6, lane = tid & 63, quad = lane >> 4, l15 = lane & 15;
  const int c0w = wave*32;
  facc acc[2][2];
  #pragma unroll
  for (int rg = 0; rg < 2; ++rg)
    #pragma unroll
    for (int f = 0; f < 2; ++f) acc[rg][f] = (facc){0.f,0.f,0.f,0.f};

  const int lr = tid >> 3, lq = tid & 7;
  const unsigned char* mrow = (const unsigned char*)&mbs[lr*16];
  const int bn = tid >> 1, bpart = tid & 1;
  const u16* bwp = BTn + (size_t)bn*N + bpart*32;
  float psum = 0.f;

  uint4 g0 = *(const uint4*)bwp,      g1 = *(const uint4*)(bwp+8);
  uint4 g2 = *(const uint4*)(bwp+16), g3 = *(const uint4*)(bwp+24);
  __syncthreads();
  const float s1lr = s1s[lr];
  psum += score8(s2s, mrow, s1lr, 0, lq, &AsU[0][lr*LS + lq*8]);
  { u16* bp = &Bs[0][bn*LS + bpart*32];
    *(uint4*)bp = g0; *(uint4*)(bp+8) = g1; *(uint4*)(bp+16) = g2; *(uint4*)(bp+24) = g3; }
  __syncthreads();

  #pragma unroll
  for (int k = 0; k < 7; ++k){
    const int cur = k & 1, nxt = cur ^ 1;
    const u16* wp = bwp + (k+1)*64;
    uint4 n0 = *(const uint4*)wp,      n1 = *(const uint4*)(wp+8);
    uint4 n2 = *(const uint4*)(wp+16), n3 = *(const uint4*)(wp+24);
    psum += score8(s2s, mrow, s1lr, (k+1)*64, lq, &AsU[nxt][lr*LS + lq*8]);
    mfma64w(AsU[cur], Bs[cur], acc, c0w, quad, l15);
    { u16* bp = &Bs[nxt][bn*LS + bpart*32];
      *(uint4*)bp = n0; *(uint4*)(bp+8) = n1; *(uint4*)(bp+16) = n2; *(uint4*)(bp+24) = n3; }
    __syncthreads();
  }
  mfma64w(AsU[1], Bs[1], acc, c0w, quad, l15);

  #pragma unroll
  for (int m = 1; m < 8; m <<= 1) psum += __shfl_xor(psum, m, 64);
  if (lq == 0) sums[lr] = psum;
  __syncthreads();

  u16* Aw = &AsU[0][0];      // stride ASW; safe post-barrier
  float pcs[2] = {0.f, 0.f};
  #pragma unroll
  for (int rg = 0; rg < 2; ++rg){
    #pragma unroll
    for (int q = 0; q < 4; ++q){
      const int row = rg*16 + quad*4 + q;
      const float sv = sums[row];
      const float inv = sv > 0.f ? 1.f/sv : 0.f;
      #pragma unroll
      for (int f = 0; f < 2; ++f){
        const int c = c0w + f*16 + l15;
        float xv = lrelu(acc[rg][f][q] * inv);
        if (DOWH){
          hF[(size_t)(t0+row)*128 + c] = xv;
          Aw[row*ASW + c] = f2bf(xv);
        }
        pcs[f] += xv;
      }
    }
  }
  pcs[0] += __shfl_xor(pcs[0], 16, 64); pcs[0] += __shfl_xor(pcs[0], 32, 64);
  pcs[1] += __shfl_xor(pcs[1], 16, 64); pcs[1] += __shfl_xor(pcs[1], 32, 64);
  if (quad == 0){
    atomicAdd(&colsum[b*128 + c0w + l15], pcs[0]);
    atomicAdd(&colsum[b*128 + c0w + 16 + l15], pcs[1]);
  }
  if (DOWH)
    wh_phaseS<H>(Aw, ASW, &Bs[0][0], WT, aatt, t0, WhTout, s1out, s2out, r1s4, r2s4, tid);
}

// ---------------- projection from pre-reduced column sums ---------------------
__global__ void final_kernel(const float* __restrict__ colsumF, const float* __restrict__ colsumT,
                             const float* __restrict__ pW, const float* __restrict__ pb,
                             float* __restrict__ out)
{
  const int b = blockIdx.x, c = threadIdx.x;
  __shared__ float scr[4];
  float s = ((c < D) ? colsumF[b*D + c] : colsumT[b*D + (c - D)]) * (1.f/N);
  float p = s * pW[c];
  #pragma unroll
  for (int m = 32; m; m >>= 1) p += __shfl_xor(p, m, 64);
  if ((c & 63) == 0) scr[c >> 6] = p;
  __syncthreads();
  if (c == 0) out[b] = scr[0] + scr[1] + scr[2] + scr[3] + pb[0];
}

extern "C" void kernel_launch(void* const* d_in, const int* in_sizes, int n_in,
                              void* d_out, int out_size, void* d_ws, size_t ws_size,
                              hipStream_t stream)
{
  (void)in_sizes; (void)n_in; (void)out_size; (void)ws_size;
  const float* x    = (const float*)d_in[0];
  const int*   adj  = (const int*)d_in[1];
  const float* f1w1 = (const float*)d_in[3];
  const float* f1b1 = (const float*)d_in[4];
  const float* f1w2 = (const float*)d_in[5];
  const float* f1b2 = (const float*)d_in[6];
  const float* f2w1 = (const float*)d_in[7];
  const float* f2b1 = (const float*)d_in[8];
  const float* f2w2 = (const float*)d_in[9];
  const float* f2b2 = (const float*)d_in[10];
  const float* f3w1 = (const float*)d_in[11];
  const float* f3b1 = (const float*)d_in[12];
  const float* f3w2 = (const float*)d_in[13];
  const float* f3b2 = (const float*)d_in[14];
  const float* attW = (const float*)d_in[15];
  const float* attA = (const float*)d_in[16];
  const float* rshW = (const float*)d_in[17];
  const float* rshB = (const float*)d_in[18];
  const float* outW = (const float*)d_in[19];
  const float* outA = (const float*)d_in[20];
  const float* pW   = (const float*)d_in[21];
  const float* pb   = (const float*)d_in[22];

  char* w = (char*)d_ws;
  float* hA  = (float*)w; w += (size_t)TOK*128*4;
  float* hB  = (float*)w; w += (size_t)TOK*128*4;
  float* hF  = (float*)w; w += (size_t)TOK*128*4;
  u16*  hp2  = (u16*)w;  w += (size_t)TOK*512*2;
  u16*  WhT  = (u16*)w;  w += (size_t)H*8*128*N*2;
  u16*  WhT2 = (u16*)w;  w += (size_t)H*8*128*N*2;
  float* s1  = (float*)w; w += (size_t)H*TOK*4;
  float* s2  = (float*)w; w += (size_t)H*TOK*4;
  float* s1b = (float*)w; w += (size_t)H*TOK*4;
  float* s2b = (float*)w; w += (size_t)H*TOK*4;
  u32* mbits = (u32*)w;  w += (size_t)B*N*16*4;
  u32* mtbits= (u32*)w;  w += (size_t)B*N*16*4;
  float* colsumF = (float*)w; w += (size_t)B*128*4;
  float* colsumT = (float*)w; w += (size_t)B*128*4;
  u16* f1w1T = (u16*)w; w += 128*32*2;
  u16* f1w2T = (u16*)w; w += 128*128*2;
  u16* f2w1T = (u16*)w; w += 256*128*2;
  u16* f2w2T = (u16*)w; w += 128*256*2;
  u16* f3w1T = (u16*)w; w += 256*128*2;
  u16* f3w2T = (u16*)w; w += 128*256*2;
  u16* attWT = (u16*)w; w += (size_t)24*128*128*2;
  u16* outWT = (u16*)w; w += (size_t)2*128*128*2;
  u16* rshWT = (u16*)w; w += (size_t)6*128*512*2;

  prep_kernel<<<1461,256,0,stream>>>(adj, mbits, mtbits, colsumF, colsumT,
      f1w1, f1w2, f2w1, f2w2, f3w1, f3w2, attW, outW, rshW,
      f1w1T, f1w2T, f2w1T, f2w2T, f3w1T, f3w2T, attWT, outWT, rshWT);

  // FEL (6 GEMMs + 2 LN) fused + WH(att block 0) -> hA, WhT, s1, s2
  fel_kernel<<<128,256,0,stream>>>(x,
      f1w1T, f1b1, f1w2T, f1b2, f2w1T, f2b1, f2w2T, f2b2, f3w1T, f3b1, f3w2T, f3b2,
      attWT, attA, hA, WhT, s1, s2);

  // forward attention blocks 0..2
  pv32<<<H*128,512,0,stream>>>(s1, s2, mbits, WhT, hp2);
  reshwh<4><<<128,512,0,stream>>>(hp2, rshWT + 0*128*512, rshB + 0*D, hA, hB,
      attWT + (size_t)1*H*D*D, attA + (size_t)1*H*2*D, WhT, s1, s2);
  pv32<<<H*128,512,0,stream>>>(s1, s2, mbits, WhT, hp2);
  reshwh<4><<<128,512,0,stream>>>(hp2, rshWT + (size_t)1*128*512, rshB + 1*D, hB, hA,
      attWT + (size_t)2*H*D*D, attA + (size_t)2*H*2*D, WhT, s1, s2);
  pv32<<<H*128,512,0,stream>>>(s1, s2, mbits, WhT, hp2);
  reshwh<1><<<128,512,0,stream>>>(hp2, rshWT + (size_t)2*128*512, rshB + 2*D, hA, hB,
      outWT, outA, WhT, s1, s2);

  // forward output GAT + colsumF + WH(att block 3) -> hF, WhT2, s1b, s2b
  pvout<1><<<128,256,0,stream>>>(s1, s2, mbits, WhT, hF, colsumF,
      attWT + (size_t)3*H*D*D, attA + (size_t)3*H*2*D, WhT2, s1b, s2b);

  // transposed attention blocks 3..5
  pv32<<<H*128,512,0,stream>>>(s1b, s2b, mtbits, WhT2, hp2);
  reshwh<4><<<128,512,0,stream>>>(hp2, rshWT + (size_t)3*128*512, rshB + 3*D, hF, hA,
      attWT + (size_t)4*H*D*D, attA + (size_t)4*H*2*D, WhT, s1, s2);
  pv32<<<H*128,512,0,stream>>>(s1, s2, mtbits, WhT, hp2);
  reshwh<4><<<128,512,0,stream>>>(hp2, rshWT + (size_t)4*128*512, rshB + 4*D, hA, hB,
      attWT + (size_t)5*H*D*D, attA + (size_t)5*H*2*D, WhT, s1, s2);
  pv32<<<H*128,512,0,stream>>>(s1, s2, mtbits, WhT, hp2);
  reshwh<1><<<128,512,0,stream>>>(hp2, rshWT + (size_t)5*128*512, rshB + 5*D, hB, hA,
      outWT + 128*128, outA + 2*D, WhT, s1, s2);

  // transposed output GAT -> colsumT only
  pvout<0><<<128,256,0,stream>>>(s1, s2, mtbits, WhT, nullptr, colsumT,
      nullptr, nullptr, nullptr, nullptr, nullptr);

  final_kernel<<<B,2*D,0,stream>>>(colsumF, colsumT, pW, pb, (float*)d_out);
}

// Round 7
// 301.045 us; speedup vs baseline: 1.2749x; 1.0090x over previous
//
#include <hip/hip_runtime.h>
#include <math.h>

#define B 8
#define N 512
#define D 128
#define H 4
#define TOK (B*N)   // 4096

typedef __attribute__((ext_vector_type(8))) short bfrag;   // 8 bf16 (4 VGPRs)
typedef __attribute__((ext_vector_type(4))) float facc;    // 4 fp32 acc
typedef unsigned short u16;
typedef unsigned int u32;
typedef unsigned long long u64;

__device__ __forceinline__ float lrelu(float x){ return x > 0.f ? x : 0.01f*x; }
__device__ __forceinline__ u16 f2bf(float f){
  u32 u = __float_as_uint(f);
  u += 0x7fffu + ((u >> 16) & 1u);     // RTNE
  return (u16)(u >> 16);
}
__device__ __forceinline__ u32 pk2(float a, float b){
  return (u32)f2bf(a) | ((u32)f2bf(b) << 16);
}

// LDS row strides (u16): all give bank skew 4/row, 16B-aligned rows
#define LS 72        // B tiles / staged A tiles
#define ASF 264      // fel A tiles (K up to 256)
#define ASW 136      // wh-phase A tiles (K=128)

// ---------------- prep: fully parallel, 1 job per block -----------------------
__global__ void prep_kernel(const int* __restrict__ adj,
    u32* __restrict__ mbits, u32* __restrict__ mtbits,
    float* __restrict__ colsumF, float* __restrict__ colsumT,
    const float* s0, const float* s1_, const float* s2_, const float* s3,
    const float* s4, const float* s5, const float* s6, const float* s7,
    const float* s8,
    u16* d0, u16* d1, u16* d2, u16* d3, u16* d4, u16* d5, u16* d6, u16* d7, u16* d8)
{
  __shared__ int smem[64*65];
  const int tid = threadIdx.x;
  if (blockIdx.x < 512){
    const int tb = blockIdx.x;
    const int b = tb >> 6, i0 = ((tb >> 3) & 7)*64, j0 = (tb & 7)*64;
    #pragma unroll
    for (int i = 0; i < 4; ++i){
      const int r = i*16 + (tid >> 4);
      const int c = (tid & 15)*4;
      int4 v = *(const int4*)&adj[((size_t)b*N + i0 + r)*N + j0 + c];
      smem[r*65 + c]     = v.x; smem[r*65 + c + 1] = v.y;
      smem[r*65 + c + 2] = v.z; smem[r*65 + c + 3] = v.w;
    }
    __syncthreads();
    const int wv = tid >> 6, lane = tid & 63;
    #pragma unroll
    for (int q = 0; q < 16; ++q){
      const int r = wv*16 + q;
      u64 bf_ = __ballot(smem[r*65 + lane] > 0);
      if (lane == 0)
        *(u64*)&mbits[((size_t)b*N + i0 + r)*16 + (j0 >> 5)] = bf_;
      u64 bt_ = __ballot(smem[lane*65 + r] > 0);
      if (lane == 0)
        *(u64*)&mtbits[((size_t)b*N + j0 + r)*16 + (i0 >> 5)] = bt_;
    }
  } else if (blockIdx.x < 1460){
    float* ftile = (float*)smem;        // [32][33]
    const int tx = tid & 31, ty = tid >> 5;
    const float* srcs[9] = {s0,s1_,s2_,s3,s4,s5,s6,s7,s8};
    u16* dsts[9] = {d0,d1,d2,d3,d4,d5,d6,d7,d8};
    const int Ks[9] = {32,128,128,256,128,256,128,128,512};
    const int Ns[9] = {128,128,256,128,256,128,128,128,128};
    const int zs[9] = {1,1,1,1,1,1,24,2,6};
    const int job = (int)blockIdx.x - 512;      // [0,948)
    int m = 0, base = 0;
    for (; m < 9; ++m){
      int cnt = (Ks[m]>>5)*(Ns[m]>>5)*zs[m];
      if (job < base + cnt) break;
      base += cnt;
    }
    const int rem = job - base;
    const int tn = Ns[m] >> 5;
    const int per = (Ks[m] >> 5)*tn;
    const int z = rem / per, t = rem % per;
    const int k0 = (t / tn)*32, n0 = (t % tn)*32;
    const float* src = srcs[m] + (size_t)z*Ks[m]*Ns[m];
    u16* dst = dsts[m] + (size_t)z*Ks[m]*Ns[m];
    for (int r = ty; r < 32; r += 8)
      ftile[r*33 + tx] = src[(size_t)(k0+r)*Ns[m] + n0 + tx];
    __syncthreads();
    for (int r = ty; r < 32; r += 8)
      dst[(size_t)(n0+r)*Ks[m] + k0 + tx] = f2bf(ftile[tx*33 + r]);
  } else {
    float4 z = {0.f,0.f,0.f,0.f};
    *(float4*)&colsumF[tid*4] = z;
    *(float4*)&colsumT[tid*4] = z;
  }
}

// ---- staging helpers ---------------------------------------------------------
struct BPre { uint4 a,b,c,d; };
__device__ __forceinline__ BPre preB64(const u16* __restrict__ BTn, int ldb, int k0, int tid){
  const int n = tid >> 1, part = tid & 1;
  const u16* wp = BTn + (size_t)n*ldb + k0 + part*32;
  BPre r;
  r.a = *(const uint4*)wp;      r.b = *(const uint4*)(wp+8);
  r.c = *(const uint4*)(wp+16); r.d = *(const uint4*)(wp+24);
  return r;
}
__device__ __forceinline__ void landB64(const BPre& p, u16* Bs, int tid){
  const int n = tid >> 1, part = tid & 1;
  u16* bp = &Bs[n*LS + part*32];
  *(uint4*)bp = p.a; *(uint4*)(bp+8) = p.b; *(uint4*)(bp+16) = p.c; *(uint4*)(bp+24) = p.d;
}
__device__ __forceinline__ void stageB32(const u16* __restrict__ BTn, int ldb,
                                         int k0, u16* Bs, int tid){
  const int n = tid >> 1, part = tid & 1;
  const u16* wp = BTn + (size_t)n*ldb + k0 + part*16;
  uint4 w0 = *(const uint4*)wp, w1 = *(const uint4*)(wp+8);
  *(uint4*)&Bs[n*LS + part*16]     = w0;
  *(uint4*)&Bs[n*LS + part*16 + 8] = w1;
}
// 64-row (group-half) B staging: 256 group-threads, 16 u16 each
struct BPre2 { uint4 a,b; };
__device__ __forceinline__ BPre2 preBh(const u16* __restrict__ BTn, int ldb, int k0,
                                       int gtid, int rowoff){
  const u16* wp = BTn + (size_t)(rowoff + (gtid >> 2))*ldb + k0 + (gtid & 3)*16;
  BPre2 r; r.a = *(const uint4*)wp; r.b = *(const uint4*)(wp+8);
  return r;
}
__device__ __forceinline__ void landBh(const BPre2& p, u16* Bs, int gtid){
  u16* bp = &Bs[(gtid >> 2)*LS + (gtid & 3)*16];
  *(uint4*)bp = p.a; *(uint4*)(bp+8) = p.b;
}

// ---- MFMA cores --------------------------------------------------------------
// 4-wave 32x128 mapping (stride-parameterized A)
__device__ __forceinline__ void mfma64s(const u16* As, int sA, const u16* Bs,
                                        facc acc[4], int r0, int c0, int quad, int l15){
  #pragma unroll
  for (int kk = 0; kk < 2; ++kk){
    bfrag af = *(const bfrag*)&As[(r0 + l15)*sA + kk*32 + quad*8];
    #pragma unroll
    for (int g = 0; g < 4; ++g){
      bfrag bf = *(const bfrag*)&Bs[(c0 + g*16 + l15)*LS + kk*32 + quad*8];
      acc[g] = __builtin_amdgcn_mfma_f32_16x16x32_bf16(af, bf, acc[g], 0,0,0);
    }
  }
}
__device__ __forceinline__ void mfma32s(const u16* As, int sA, const u16* Bs,
                                        facc acc[4], int r0, int c0, int quad, int l15){
  bfrag af = *(const bfrag*)&As[(r0 + l15)*sA + quad*8];
  #pragma unroll
  for (int g = 0; g < 4; ++g){
    bfrag bf = *(const bfrag*)&Bs[(c0 + g*16 + l15)*LS + quad*8];
    acc[g] = __builtin_amdgcn_mfma_f32_16x16x32_bf16(af, bf, acc[g], 0,0,0);
  }
}
// wave = 32 rows x 16 cols (col-split groups in pv32/reshwh)
__device__ __forceinline__ void mfma64h(const u16* As, const u16* Bs,
                                        facc acc[2], int c0, int quad, int l15){
  #pragma unroll
  for (int kk = 0; kk < 2; ++kk){
    bfrag af0 = *(const bfrag*)&As[(l15)*LS      + kk*32 + quad*8];
    bfrag af1 = *(const bfrag*)&As[(16 + l15)*LS + kk*32 + quad*8];
    bfrag bf  = *(const bfrag*)&Bs[(c0 + l15)*LS + kk*32 + quad*8];
    acc[0] = __builtin_amdgcn_mfma_f32_16x16x32_bf16(af0, bf, acc[0], 0,0,0);
    acc[1] = __builtin_amdgcn_mfma_f32_16x16x32_bf16(af1, bf, acc[1], 0,0,0);
  }
}
// wave = 32 rows x 32 cols (pvout)
__device__ __forceinline__ void mfma64w(const u16* As, const u16* Bs,
                                        facc acc[2][2], int c0,
                                        int quad, int l15){
  #pragma unroll
  for (int kk = 0; kk < 2; ++kk){
    bfrag af0 = *(const bfrag*)&As[(l15)*LS      + kk*32 + quad*8];
    bfrag af1 = *(const bfrag*)&As[(16 + l15)*LS + kk*32 + quad*8];
    #pragma unroll
    for (int f = 0; f < 2; ++f){
      bfrag bf = *(const bfrag*)&Bs[(c0 + f*16 + l15)*LS + kk*32 + quad*8];
      acc[0][f] = __builtin_amdgcn_mfma_f32_16x16x32_bf16(af0, bf, acc[0][f], 0,0,0);
      acc[1][f] = __builtin_amdgcn_mfma_f32_16x16x32_bf16(af1, bf, acc[1][f], 0,0,0);
    }
  }
}

// ---- single-buffer A-in-LDS GEMM over T 64-wide K tiles (fel) ----------------
template<int T>
__device__ __forceinline__ void gemmAs(const u16* Aw, int sA,
    const u16* __restrict__ BT, int ldb, u16* Bs,
    facc acc[4], int tid, int r0, int c0, int quad, int l15){
  BPre p = preB64(BT, ldb, 0, tid);
  #pragma unroll
  for (int t = 0; t < T; ++t){
    __syncthreads();                       // Bs writable; A writes visible below
    landB64(p, Bs, tid);
    if (t + 1 < T) p = preB64(BT, ldb, (t+1)*64, tid);
    __syncthreads();
    mfma64s(Aw + t*64, sA, Bs, acc, r0, c0, quad, l15);
  }
}

// ---- WH phase (single-buffer, 256-thread version: fel / pvout) ---------------
template<int NH>
__device__ __forceinline__ void wh_phaseS(const u16* Aw, int sA, u16* Bs,
    const u16* __restrict__ WT, const float* __restrict__ aatt,
    int t0, u16* __restrict__ WhT, float* __restrict__ s1, float* __restrict__ s2,
    float (*r1s4)[2][32], float (*r2s4)[2][32], int tid)
{
  const int wave = tid >> 6, lane = tid & 63, quad = lane >> 4, l15 = lane & 15;
  const int r0 = (wave & 1)*16, c0 = (wave >> 1)*64;
  const int b = t0 >> 9, j0 = t0 & (N-1);
  BPre p = preB64(WT, D, 0, tid);
  facc acc[4];
  #pragma unroll
  for (int t = 0; t < 2*NH; ++t){
    if ((t & 1) == 0){
      #pragma unroll
      for (int g = 0; g < 4; ++g) acc[g] = (facc){0.f,0.f,0.f,0.f};
    }
    __syncthreads();                       // Bs writable; Aw visible
    landB64(p, Bs, tid);
    if (t + 1 < 2*NH) p = preB64(WT + (size_t)((t+1)>>1)*D*D, D, ((t+1)&1)*64, tid);
    __syncthreads();
    mfma64s(Aw + (t&1)*64, sA, Bs, acc, r0, c0, quad, l15);
    if (t & 1){
      const int h = t >> 1;
      const float* ah = aatt + (size_t)h*2*D;
      const size_t obase = (size_t)(h*8 + b)*128;
      float p1[4] = {0,0,0,0}, p2[4] = {0,0,0,0};
      #pragma unroll
      for (int g = 0; g < 4; ++g){
        const int c = c0 + g*16 + l15;
        const float a1v = ah[c], a2v = ah[D + c];
        ushort4 wv;
        wv.x = f2bf(acc[g][0]); wv.y = f2bf(acc[g][1]);
        wv.z = f2bf(acc[g][2]); wv.w = f2bf(acc[g][3]);
        *(ushort4*)&WhT[(obase + c)*N + j0 + r0 + quad*4] = wv;
        #pragma unroll
        for (int q = 0; q < 4; ++q){
          p1[q] = fmaf(acc[g][q], a1v, p1[q]);
          p2[q] = fmaf(acc[g][q], a2v, p2[q]);
        }
      }
      #pragma unroll
      for (int m = 1; m < 16; m <<= 1){
        #pragma unroll
        for (int q = 0; q < 4; ++q){ p1[q] += __shfl_xor(p1[q], m, 64); p2[q] += __shfl_xor(p2[q], m, 64); }
      }
      if (l15 == 0){
        #pragma unroll
        for (int q = 0; q < 4; ++q){
          r1s4[h][wave>>1][r0 + quad*4 + q] = p1[q];
          r2s4[h][wave>>1][r0 + quad*4 + q] = p2[q];
        }
      }
    }
  }
  __syncthreads();
  if (tid < 32*NH){
    const int h = tid >> 5, r = tid & 31;
    s1[(size_t)h*TOK + t0 + r] = r1s4[h][0][r] + r1s4[h][1][r];
    s2[(size_t)h*TOK + t0 + r] = r2s4[h][0][r] + r2s4[h][1][r];
  }
}

// ---------------- fused FEL (6 GEMMs + LN x2) + WH of att block 0 -------------
__global__ __launch_bounds__(256) void fel_kernel(
    const float* __restrict__ x,
    const u16* __restrict__ w1T, const float* __restrict__ b1,
    const u16* __restrict__ w2T, const float* __restrict__ b2,
    const u16* __restrict__ w3T, const float* __restrict__ b3,
    const u16* __restrict__ w4T, const float* __restrict__ b4,
    const u16* __restrict__ w5T, const float* __restrict__ b5,
    const u16* __restrict__ w6T, const float* __restrict__ b6,
    const u16* __restrict__ WTatt, const float* __restrict__ aatt,
    float* __restrict__ hout, u16* __restrict__ WhT,
    float* __restrict__ s1, float* __restrict__ s2)
{
  const int tid = threadIdx.x;
  const int t0 = blockIdx.x * 32;
  __shared__ __align__(16) u16 AwA[32*ASF];
  __shared__ __align__(16) u16 AwB[32*ASF];
  __shared__ __align__(16) u16 Bs[128*LS];
  __shared__ float scrS[4][16], scrQ[4][16];
  __shared__ float r1s4[H][2][32], r2s4[H][2][32];
  const int wave = tid >> 6, lane = tid & 63, quad = lane >> 4, l15 = lane & 15;
  const int r0 = (wave & 1)*16, c0 = (wave >> 1)*64;
  facc acc[4];
  float rres[4][4];

  // ---- S1: t1 = lrelu(x@f1w1+b1)  (K=32) -> AwB
  { const int row = tid >> 3, ko = tid & 7;
    float4 a0 = *(const float4*)(x + (size_t)(t0+row)*32 + ko*4);
    uint2 u = { pk2(a0.x,a0.y), pk2(a0.z,a0.w) };
    *(uint2*)&AwA[row*ASF + ko*4] = u;
    stageB32(w1T, 32, 0, Bs, tid);
  }
  __syncthreads();
  #pragma unroll
  for (int g = 0; g < 4; ++g) acc[g] = (facc){0.f,0.f,0.f,0.f};
  mfma32s(AwA, ASF, Bs, acc, r0, c0, quad, l15);
  #pragma unroll
  for (int g = 0; g < 4; ++g){
    const int c = c0 + g*16 + l15;
    const float bv = b1[c];
    #pragma unroll
    for (int q = 0; q < 4; ++q)
      AwB[(r0 + quad*4 + q)*ASF + c] = f2bf(lrelu(acc[g][q] + bv));
  }

  // ---- S2: res = lrelu(t1@f1w2+b2) (K=128) -> AwA + rres
  #pragma unroll
  for (int g = 0; g < 4; ++g) acc[g] = (facc){0.f,0.f,0.f,0.f};
  gemmAs<2>(AwB, ASF, w2T, 128, Bs, acc, tid, r0, c0, quad, l15);
  #pragma unroll
  for (int g = 0; g < 4; ++g){
    const int c = c0 + g*16 + l15;
    const float bv = b2[c];
    #pragma unroll
    for (int q = 0; q < 4; ++q){
      float xv = lrelu(acc[g][q] + bv);
      AwA[(r0 + quad*4 + q)*ASF + c] = f2bf(xv);
      rres[g][q] = xv;
    }
  }

  // ---- S3: t3 = lrelu(res@f2w1+b3) (K=128, out 256) -> AwB
  #pragma unroll
  for (int ch = 0; ch < 2; ++ch){
    #pragma unroll
    for (int g = 0; g < 4; ++g) acc[g] = (facc){0.f,0.f,0.f,0.f};
    gemmAs<2>(AwA, ASF, w3T + (size_t)ch*128*128, 128, Bs, acc, tid, r0, c0, quad, l15);
    #pragma unroll
    for (int g = 0; g < 4; ++g){
      const int c = c0 + g*16 + l15;
      const float bv = b3[ch*128 + c];
      #pragma unroll
      for (int q = 0; q < 4; ++q)
        AwB[(r0 + quad*4 + q)*ASF + ch*128 + c] = f2bf(lrelu(acc[g][q] + bv));
    }
  }

  // ---- S4: x1 = LN(lrelu(t3@f2w2+b4) + res) (K=256) -> AwA + rres
  #pragma unroll
  for (int g = 0; g < 4; ++g) acc[g] = (facc){0.f,0.f,0.f,0.f};
  gemmAs<4>(AwB, ASF, w4T, 256, Bs, acc, tid, r0, c0, quad, l15);
  {
    float v[4][4], s[4] = {0,0,0,0}, sq[4] = {0,0,0,0};
    #pragma unroll
    for (int g = 0; g < 4; ++g){
      const int c = c0 + g*16 + l15;
      const float bv = b4[c];
      #pragma unroll
      for (int q = 0; q < 4; ++q){
        float xv = lrelu(acc[g][q] + bv) + rres[g][q];
        v[g][q] = xv; s[q] += xv; sq[q] += xv*xv;
      }
    }
    #pragma unroll
    for (int m = 1; m < 16; m <<= 1){
      #pragma unroll
      for (int q = 0; q < 4; ++q){ s[q] += __shfl_xor(s[q], m, 64); sq[q] += __shfl_xor(sq[q], m, 64); }
    }
    if (l15 == 0){
      #pragma unroll
      for (int q = 0; q < 4; ++q){ scrS[wave][quad*4+q] = s[q]; scrQ[wave][quad*4+q] = sq[q]; }
    }
    __syncthreads();
    #pragma unroll
    for (int q = 0; q < 4; ++q){
      const int r = r0 + quad*4 + q;
      const float fs = s[q] + scrS[wave^2][quad*4+q];
      const float fq = sq[q] + scrQ[wave^2][quad*4+q];
      const float mean = fs*(1.f/D);
      const float rstd = rsqrtf(fq*(1.f/D) - mean*mean + 1e-5f);
      #pragma unroll
      for (int g = 0; g < 4; ++g){
        const int c = c0 + g*16 + l15;
        float xv = (v[g][q] - mean)*rstd;
        AwA[r*ASF + c] = f2bf(xv);
        rres[g][q] = xv;
      }
    }
  }

  // ---- S5: t5 = lrelu(x1@f3w1+b5) (K=128, out 256) -> AwB
  #pragma unroll
  for (int ch = 0; ch < 2; ++ch){
    #pragma unroll
    for (int g = 0; g < 4; ++g) acc[g] = (facc){0.f,0.f,0.f,0.f};
    gemmAs<2>(AwA, ASF, w5T + (size_t)ch*128*128, 128, Bs, acc, tid, r0, c0, quad, l15);
    #pragma unroll
    for (int g = 0; g < 4; ++g){
      const int c = c0 + g*16 + l15;
      const float bv = b5[ch*128 + c];
      #pragma unroll
      for (int q = 0; q < 4; ++q)
        AwB[(r0 + quad*4 + q)*ASF + ch*128 + c] = f2bf(lrelu(acc[g][q] + bv));
    }
  }

  // ---- S6: out = LN(t5@f3w2+b6 + x1) (K=256) -> hout (fp32) + AwA (bf16)
  #pragma unroll
  for (int g = 0; g < 4; ++g) acc[g] = (facc){0.f,0.f,0.f,0.f};
  gemmAs<4>(AwB, ASF, w6T, 256, Bs, acc, tid, r0, c0, quad, l15);
  {
    float v[4][4], s[4] = {0,0,0,0}, sq[4] = {0,0,0,0};
    #pragma unroll
    for (int g = 0; g < 4; ++g){
      const int c = c0 + g*16 + l15;
      const float bv = b6[c];
      #pragma unroll
      for (int q = 0; q < 4; ++q){
        float xv = acc[g][q] + bv + rres[g][q];
        v[g][q] = xv; s[q] += xv; sq[q] += xv*xv;
      }
    }
    #pragma unroll
    for (int m = 1; m < 16; m <<= 1){
      #pragma unroll
      for (int q = 0; q < 4; ++q){ s[q] += __shfl_xor(s[q], m, 64); sq[q] += __shfl_xor(sq[q], m, 64); }
    }
    if (l15 == 0){
      #pragma unroll
      for (int q = 0; q < 4; ++q){ scrS[wave][quad*4+q] = s[q]; scrQ[wave][quad*4+q] = sq[q]; }
    }
    __syncthreads();
    #pragma unroll
    for (int q = 0; q < 4; ++q){
      const int r = r0 + quad*4 + q;
      const float fs = s[q] + scrS[wave^2][quad*4+q];
      const float fq = sq[q] + scrQ[wave^2][quad*4+q];
      const float mean = fs*(1.f/D);
      const float rstd = rsqrtf(fq*(1.f/D) - mean*mean + 1e-5f);
      #pragma unroll
      for (int g = 0; g < 4; ++g){
        const int c = c0 + g*16 + l15;
        float xv = (v[g][q] - mean)*rstd;
        hout[(size_t)(t0 + r)*128 + c] = xv;
        AwA[r*ASF + c] = f2bf(xv);
      }
    }
  }
  wh_phaseS<H>(AwA, ASF, Bs, WTatt, aatt, t0, WhT, s1, s2, r1s4, r2s4, tid);
}

// ---------------- reshwh (512 thr): resh GEMM col-split + LN + WH head-split --
// 2-deep global prefetch: tile k+2 issued at iter k; tile k+1 lands with a full
// iteration of score/MFMA/barrier latency coverage.
template<int NH>
__global__ __launch_bounds__(512) void reshwh(
    const u16* __restrict__ A, const u16* __restrict__ BT, const float* __restrict__ bias,
    const float* __restrict__ res, float* __restrict__ hout,
    const u16* __restrict__ WT, const float* __restrict__ aatt,
    u16* __restrict__ WhT, float* __restrict__ s1, float* __restrict__ s2)
{
  const int tid = threadIdx.x;
  const int t0 = blockIdx.x * 32;
  __shared__ __align__(16) u16 AsU[2][32*LS];        // A dbuf; reused as Aw (ASW)
  __shared__ __align__(16) u16 Bsg[2][2][64*LS];     // [group][buf]; wh reuses [128*LS]
  __shared__ float scrS[8][32], scrQ[8][32];
  __shared__ float r1s4[NH][2][32], r2s4[NH][2][32];
  const int g = tid >> 8, gtid = tid & 255;
  const int w8 = tid >> 6, lane = tid & 63, quad = lane >> 4, l15 = lane & 15;
  const int wv = gtid >> 6;            // group-local wave 0..3
  const int c0h = wv*16;               // col within group's 64-col half

  // ---- resh GEMM: out cols g*64 + c0h + l15, K=512, dbuf + 2-deep prefetch ----
  facc acc2[2];
  acc2[0] = (facc){0.f,0.f,0.f,0.f}; acc2[1] = (facc){0.f,0.f,0.f,0.f};
  const int arow = tid >> 4, ako = tid & 15;
  const u16* aptr = A + (size_t)(t0+arow)*512 + ako*4;
  uint2 aC = *(const uint2*)aptr;                 // tile 0 A
  BPre2 bC = preBh(BT, 512, 0, gtid, g*64);       // tile 0 B
  uint2 aP = *(const uint2*)(aptr + 64);          // tile 1 A (in flight)
  BPre2 bP = preBh(BT, 512, 64, gtid, g*64);      // tile 1 B (in flight)
  *(uint2*)&AsU[0][arow*LS + ako*4] = aC;
  landBh(bC, Bsg[g][0], gtid);
  __syncthreads();
  #pragma unroll
  for (int k = 0; k < 7; ++k){
    const int cur = k & 1, nxt = cur ^ 1;
    uint2 a2 = aP; BPre2 b2 = bP;
    if (k + 2 < 8){                               // issue tile k+2 (2 ahead)
      a2 = *(const uint2*)(aptr + (k+2)*64);
      b2 = preBh(BT, 512, (k+2)*64, gtid, g*64);
    }
    mfma64h(AsU[cur], Bsg[g][cur], acc2, c0h, quad, l15);
    *(uint2*)&AsU[nxt][arow*LS + ako*4] = aP;     // land tile k+1
    landBh(bP, Bsg[g][nxt], gtid);
    aP = a2; bP = b2;
    __syncthreads();
  }
  mfma64h(AsU[1], Bsg[g][1], acc2, c0h, quad, l15);

  // ---- bias + residual + LN (8-wave cross reduce) ----
  const int c = g*64 + c0h + l15;
  const float bv = bias[c];
  float v[2][4], s[2][4], sq[2][4];
  #pragma unroll
  for (int rg = 0; rg < 2; ++rg){
    #pragma unroll
    for (int q = 0; q < 4; ++q){
      const int rq = t0 + rg*16 + quad*4 + q;
      float xv = acc2[rg][q] + bv + res[(size_t)rq*128 + c];
      v[rg][q] = xv; s[rg][q] = xv; sq[rg][q] = xv*xv;
    }
  }
  #pragma unroll
  for (int m = 1; m < 16; m <<= 1){
    #pragma unroll
    for (int rg = 0; rg < 2; ++rg)
      #pragma unroll
      for (int q = 0; q < 4; ++q){ s[rg][q] += __shfl_xor(s[rg][q], m, 64); sq[rg][q] += __shfl_xor(sq[rg][q], m, 64); }
  }
  if (l15 == 0){
    #pragma unroll
    for (int rg = 0; rg < 2; ++rg)
      #pragma unroll
      for (int q = 0; q < 4; ++q){
        scrS[w8][rg*16 + quad*4 + q] = s[rg][q];
        scrQ[w8][rg*16 + quad*4 + q] = sq[rg][q];
      }
  }
  __syncthreads();    // scr visible; also: all resh MFMA reads of AsU/Bsg done
  u16* Aw = &AsU[0][0];                // stride ASW (32x136 fits 2x32x72)
  #pragma unroll
  for (int rg = 0; rg < 2; ++rg){
    #pragma unroll
    for (int q = 0; q < 4; ++q){
      const int row = rg*16 + quad*4 + q;
      float fs = 0.f, fq = 0.f;
      #pragma unroll
      for (int w = 0; w < 8; ++w){ fs += scrS[w][row]; fq += scrQ[w][row]; }
      const float mean = fs*(1.f/D);
      const float rstd = rsqrtf(fq*(1.f/D) - mean*mean + 1e-5f);
      float xv = (v[rg][q] - mean)*rstd;
      hout[(size_t)(t0+row)*128 + c] = xv;
      Aw[row*ASW + c] = f2bf(xv);
    }
  }
  __syncthreads();    // Aw fully written

  // ---- WH phase: group g -> heads {2g,2g+1} (NH=4) or head 0 (NH=1) ----
  const int NHg = (NH == 4) ? 2 : 1;
  const int hbase = (NH == 4) ? g*2 : 0;
  const bool st = (NH == 4) || (g == 0);
  u16* BsW = &Bsg[g][0][0];            // contiguous [128*LS]
  const int r0w = (wv & 1)*16, c0w = (wv >> 1)*64;
  const int b = t0 >> 9, j0 = t0 & (N-1);
  facc acc[4];
  BPre p = preB64(WT + (size_t)hbase*D*D, D, 0, gtid);
  #pragma unroll
  for (int t = 0; t < 2*NHg; ++t){
    if ((t & 1) == 0){
      #pragma unroll
      for (int gg = 0; gg < 4; ++gg) acc[gg] = (facc){0.f,0.f,0.f,0.f};
    }
    __syncthreads();                   // BsW writable
    landB64(p, BsW, gtid);
    if (t + 1 < 2*NHg){
      const int hn = hbase + ((t+1) >> 1);
      p = preB64(WT + (size_t)hn*D*D, D, ((t+1)&1)*64, gtid);
    }
    __syncthreads();
    mfma64s(Aw + (t&1)*64, ASW, BsW, acc, r0w, c0w, quad, l15);
    if (t & 1){
      const int h = hbase + (t >> 1);
      const float* ah = aatt + (size_t)h*2*D;
      const size_t obase = (size_t)(h*8 + b)*128;
      float p1[4] = {0,0,0,0}, p2[4] = {0,0,0,0};
      #pragma unroll
      for (int gg = 0; gg < 4; ++gg){
        const int cc = c0w + gg*16 + l15;
        const float a1v = ah[cc], a2v = ah[D + cc];
        if (st){
          ushort4 wvv;
          wvv.x = f2bf(acc[gg][0]); wvv.y = f2bf(acc[gg][1]);
          wvv.z = f2bf(acc[gg][2]); wvv.w = f2bf(acc[gg][3]);
          *(ushort4*)&WhT[(obase + cc)*N + j0 + r0w + quad*4] = wvv;
        }
        #pragma unroll
        for (int q = 0; q < 4; ++q){
          p1[q] = fmaf(acc[gg][q], a1v, p1[q]);
          p2[q] = fmaf(acc[gg][q], a2v, p2[q]);
        }
      }
      #pragma unroll
      for (int m = 1; m < 16; m <<= 1){
        #pragma unroll
        for (int q = 0; q < 4; ++q){ p1[q] += __shfl_xor(p1[q], m, 64); p2[q] += __shfl_xor(p2[q], m, 64); }
      }
      if (st && l15 == 0){
        #pragma unroll
        for (int q = 0; q < 4; ++q){
          r1s4[h][wv>>1][r0w + quad*4 + q] = p1[q];
          r2s4[h][wv>>1][r0w + quad*4 + q] = p2[q];
        }
      }
    }
  }
  __syncthreads();
  if (tid < 32*NH){
    const int h = tid >> 5, r = tid & 31;
    s1[(size_t)h*TOK + t0 + r] = r1s4[h][0][r] + r1s4[h][1][r];
    s2[(size_t)h*TOK + t0 + r] = r2s4[h][0][r] + r2s4[h][1][r];
  }
}

// ---- score helper: 4 cols of one row, bitmask from LDS -----------------------
__device__ __forceinline__ float score4(const float* s2s, const unsigned char* mrow,
                                        float s1lr, int k0, int ls, u16* asp){
  float4 sa = *(const float4*)&s2s[k0 + ls*4];
  const u32 mm = (u32)(mrow[(k0 >> 3) + (ls >> 1)]) >> ((ls & 1)*4);
  float ss[4] = {sa.x,sa.y,sa.z,sa.w};
  float v[4]; float p = 0.f;
  #pragma unroll
  for (int i = 0; i < 4; ++i){
    float e = lrelu(s1lr * ss[i]);
    float ex = ((mm >> i) & 1u) ? __expf(e) : 0.f;
    v[i] = ex; p += ex;
  }
  uint2 u = { pk2(v[0],v[1]), pk2(v[2],v[3]) };
  *(uint2*)asp = u;
  return p;
}
// 8-col variant for pvout (256 thr)
__device__ __forceinline__ float score8(const float* s2s, const unsigned char* mrow,
                                        float s1lr, int k0, int lq, u16* asp){
  float4 sa = *(const float4*)&s2s[k0 + lq*8];
  float4 sb = *(const float4*)&s2s[k0 + lq*8 + 4];
  const u32 mm = mrow[(k0 >> 3) + lq];
  float ss[8] = {sa.x,sa.y,sa.z,sa.w,sb.x,sb.y,sb.z,sb.w};
  float v[8]; float p = 0.f;
  #pragma unroll
  for (int i = 0; i < 8; ++i){
    float e = lrelu(s1lr * ss[i]);
    float ex = ((mm >> i) & 1u) ? __expf(e) : 0.f;
    v[i] = ex; p += ex;
  }
  uint4 u = { pk2(v[0],v[1]), pk2(v[2],v[3]), pk2(v[4],v[5]), pk2(v[6],v[7]) };
  *(uint4*)asp = u;
  return p;
}

// ---------------- attention pv (512 thr, col-split groups, elu, bf16 out) -----
// 2-deep B prefetch.
__global__ __launch_bounds__(512) void pv32(
    const float* __restrict__ s1, const float* __restrict__ s2,
    const u32* __restrict__ mbits, const u16* __restrict__ WhT,
    u16* __restrict__ out_)
{
  const int tid = threadIdx.x;
  const int h  = blockIdx.x >> 7;
  const int t0 = (blockIdx.x & 127) * 32;
  const int b = t0 >> 9, i0 = t0 & (N-1);
  __shared__ float s2s[N];
  __shared__ float s1s[32], sums[32];
  __shared__ u32 mbs[32*16];
  __shared__ __align__(16) u16 As[2][32*LS];
  __shared__ __align__(16) u16 Bs[2][2][64*LS];     // [group][buf]

  const int g = tid >> 8, gtid = tid & 255;
  const int lane = tid & 63, quad = lane >> 4, l15 = lane & 15;
  const int wv = gtid >> 6;
  const int c0h = wv*16;

  s2s[tid] = s2[(size_t)h*TOK + b*N + tid];
  if (tid < 32) s1s[tid] = s1[(size_t)h*TOK + t0 + tid];
  mbs[tid] = mbits[((size_t)b*N + i0 + (tid >> 4))*16 + (tid & 15)];

  const u16* BTn = WhT + (size_t)(h*8 + b)*128*N;
  facc acc2[2];
  acc2[0] = (facc){0.f,0.f,0.f,0.f}; acc2[1] = (facc){0.f,0.f,0.f,0.f};

  const int lr = tid >> 4, ls = tid & 15;
  const unsigned char* mrow = (const unsigned char*)&mbs[lr*16];
  float psum = 0.f;

  // prologue: tiles 0 and 1 in flight
  BPre2 pC = preBh(BTn, N, 0, gtid, g*64);
  BPre2 pP = preBh(BTn, N, 64, gtid, g*64);
  __syncthreads();                      // s2s/s1s/mbs visible
  const float s1lr = s1s[lr];
  psum += score4(s2s, mrow, s1lr, 0, ls, &As[0][lr*LS + ls*4]);
  landBh(pC, Bs[g][0], gtid);
  __syncthreads();

  #pragma unroll
  for (int k = 0; k < 7; ++k){
    const int cur = k & 1, nxt = cur ^ 1;
    BPre2 p2 = pP;
    if (k + 2 < 8) p2 = preBh(BTn, N, (k+2)*64, gtid, g*64);   // issue 2 ahead
    psum += score4(s2s, mrow, s1lr, (k+1)*64, ls, &As[nxt][lr*LS + ls*4]);
    mfma64h(As[cur], Bs[g][cur], acc2, c0h, quad, l15);
    landBh(pP, Bs[g][nxt], gtid);                              // land tile k+1
    pP = p2;
    __syncthreads();
  }
  mfma64h(As[1], Bs[g][1], acc2, c0h, quad, l15);

  #pragma unroll
  for (int m = 1; m < 16; m <<= 1) psum += __shfl_xor(psum, m, 64);
  if (ls == 0) sums[lr] = psum;
  __syncthreads();

  #pragma unroll
  for (int rg = 0; rg < 2; ++rg){
    #pragma unroll
    for (int q = 0; q < 4; ++q){
      const int row = rg*16 + quad*4 + q;
      const float sv = sums[row];
      const float inv = sv > 0.f ? 1.f/sv : 0.f;
      float xv = acc2[rg][q] * inv;
      xv = xv > 0.f ? xv : __expf(xv) - 1.f;     // elu
      out_[(size_t)(t0+row)*512 + h*128 + g*64 + c0h + l15] = f2bf(xv);
    }
  }
}

// ---------------- output-GAT pv (1 head, lrelu) + colsum (+ optional WH) ------
template<int DOWH>
__global__ __launch_bounds__(256) void pvout(
    const float* __restrict__ s1in, const float* __restrict__ s2in,
    const u32* __restrict__ mbits, const u16* __restrict__ WhTin,
    float* __restrict__ hF, float* __restrict__ colsum,
    const u16* __restrict__ WT, const float* __restrict__ aatt,
    u16* __restrict__ WhTout, float* __restrict__ s1out, float* __restrict__ s2out)
{
  const int tid = threadIdx.x;
  const int t0 = blockIdx.x * 32;
  const int b = t0 >> 9, i0 = t0 & (N-1);
  __shared__ float s2s[N];
  __shared__ float s1s[32], sums[32];
  __shared__ u32 mbs[32*16];
  __shared__ __align__(16) u16 AsU[2][32*LS];
  __shared__ __align__(16) u16 Bs[2][128*LS];
  __shared__ float r1s4[H][2][32], r2s4[H][2][32];

  s2s[tid]     = s2in[b*N + tid];
  s2s[tid+256] = s2in[b*N + tid + 256];
  if (tid < 32) s1s[tid] = s1in[t0 + tid];
  { const int r = tid >> 3, wd = (tid & 7)*2;
    *(uint2*)&mbs[r*16 + wd] = *(const uint2*)&mbits[((size_t)b*N + i0 + r)*16 + wd];
  }

  const u16* BTn = WhTin + (size_t)b*128*N;
  const int wave = tid >> 6, lane = tid & 63, quad = lane >> 4, l15 = lane & 15;
  const int c0w = wave*32;
  facc acc[2][2];
  #pragma unroll
  for (int rg = 0; rg < 2; ++rg)
    #pragma unroll
    for (int f = 0; f < 2; ++f) acc[rg][f] = (facc){0.f,0.f,0.f,0.f};

  const int lr = tid >> 3, lq = tid & 7;
  const unsigned char* mrow = (const unsigned char*)&mbs[lr*16];
  const int bn = tid >> 1, bpart = tid & 1;
  const u16* bwp = BTn + (size_t)bn*N + bpart*32;
  float psum = 0.f;

  uint4 g0 = *(const uint4*)bwp,      g1 = *(const uint4*)(bwp+8);
  uint4 g2 = *(const uint4*)(bwp+16), g3 = *(const uint4*)(bwp+24);
  __syncthreads();
  const float s1lr = s1s[lr];
  psum += score8(s2s, mrow, s1lr, 0, lq, &AsU[0][lr*LS + lq*8]);
  { u16* bp = &Bs[0][bn*LS + bpart*32];
    *(uint4*)bp = g0; *(uint4*)(bp+8) = g1; *(uint4*)(bp+16) = g2; *(uint4*)(bp+24) = g3; }
  __syncthreads();

  #pragma unroll
  for (int k = 0; k < 7; ++k){
    const int cur = k & 1, nxt = cur ^ 1;
    const u16* wp = bwp + (k+1)*64;
    uint4 n0 = *(const uint4*)wp,      n1 = *(const uint4*)(wp+8);
    uint4 n2 = *(const uint4*)(wp+16), n3 = *(const uint4*)(wp+24);
    psum += score8(s2s, mrow, s1lr, (k+1)*64, lq, &AsU[nxt][lr*LS + lq*8]);
    mfma64w(AsU[cur], Bs[cur], acc, c0w, quad, l15);
    { u16* bp = &Bs[nxt][bn*LS + bpart*32];
      *(uint4*)bp = n0; *(uint4*)(bp+8) = n1; *(uint4*)(bp+16) = n2; *(uint4*)(bp+24) = n3; }
    __syncthreads();
  }
  mfma64w(AsU[1], Bs[1], acc, c0w, quad, l15);

  #pragma unroll
  for (int m = 1; m < 8; m <<= 1) psum += __shfl_xor(psum, m, 64);
  if (lq == 0) sums[lr] = psum;
  __syncthreads();

  u16* Aw = &AsU[0][0];      // stride ASW; safe post-barrier
  float pcs[2] = {0.f, 0.f};
  #pragma unroll
  for (int rg = 0; rg < 2; ++rg){
    #pragma unroll
    for (int q = 0; q < 4; ++q){
      const int row = rg*16 + quad*4 + q;
      const float sv = sums[row];
      const float inv = sv > 0.f ? 1.f/sv : 0.f;
      #pragma unroll
      for (int f = 0; f < 2; ++f){
        const int c = c0w + f*16 + l15;
        float xv = lrelu(acc[rg][f][q] * inv);
        if (DOWH){
          hF[(size_t)(t0+row)*128 + c] = xv;
          Aw[row*ASW + c] = f2bf(xv);
        }
        pcs[f] += xv;
      }
    }
  }
  pcs[0] += __shfl_xor(pcs[0], 16, 64); pcs[0] += __shfl_xor(pcs[0], 32, 64);
  pcs[1] += __shfl_xor(pcs[1], 16, 64); pcs[1] += __shfl_xor(pcs[1], 32, 64);
  if (quad == 0){
    atomicAdd(&colsum[b*128 + c0w + l15], pcs[0]);
    atomicAdd(&colsum[b*128 + c0w + 16 + l15], pcs[1]);
  }
  if (DOWH)
    wh_phaseS<H>(Aw, ASW, &Bs[0][0], WT, aatt, t0, WhTout, s1out, s2out, r1s4, r2s4, tid);
}

// ---------------- projection from pre-reduced column sums ---------------------
__global__ void final_kernel(const float* __restrict__ colsumF, const float* __restrict__ colsumT,
                             const float* __restrict__ pW, const float* __restrict__ pb,
                             float* __restrict__ out)
{
  const int b = blockIdx.x, c = threadIdx.x;
  __shared__ float scr[4];
  float s = ((c < D) ? colsumF[b*D + c] : colsumT[b*D + (c - D)]) * (1.f/N);
  float p = s * pW[c];
  #pragma unroll
  for (int m = 32; m; m >>= 1) p += __shfl_xor(p, m, 64);
  if ((c & 63) == 0) scr[c >> 6] = p;
  __syncthreads();
  if (c == 0) out[b] = scr[0] + scr[1] + scr[2] + scr[3] + pb[0];
}

extern "C" void kernel_launch(void* const* d_in, const int* in_sizes, int n_in,
                              void* d_out, int out_size, void* d_ws, size_t ws_size,
                              hipStream_t stream)
{
  (void)in_sizes; (void)n_in; (void)out_size; (void)ws_size;
  const float* x    = (const float*)d_in[0];
  const int*   adj  = (const int*)d_in[1];
  const float* f1w1 = (const float*)d_in[3];
  const float* f1b1 = (const float*)d_in[4];
  const float* f1w2 = (const float*)d_in[5];
  const float* f1b2 = (const float*)d_in[6];
  const float* f2w1 = (const float*)d_in[7];
  const float* f2b1 = (const float*)d_in[8];
  const float* f2w2 = (const float*)d_in[9];
  const float* f2b2 = (const float*)d_in[10];
  const float* f3w1 = (const float*)d_in[11];
  const float* f3b1 = (const float*)d_in[12];
  const float* f3w2 = (const float*)d_in[13];
  const float* f3b2 = (const float*)d_in[14];
  const float* attW = (const float*)d_in[15];
  const float* attA = (const float*)d_in[16];
  const float* rshW = (const float*)d_in[17];
  const float* rshB = (const float*)d_in[18];
  const float* outW = (const float*)d_in[19];
  const float* outA = (const float*)d_in[20];
  const float* pW   = (const float*)d_in[21];
  const float* pb   = (const float*)d_in[22];

  char* w = (char*)d_ws;
  float* hA  = (float*)w; w += (size_t)TOK*128*4;
  float* hB  = (float*)w; w += (size_t)TOK*128*4;
  float* hF  = (float*)w; w += (size_t)TOK*128*4;
  u16*  hp2  = (u16*)w;  w += (size_t)TOK*512*2;
  u16*  WhT  = (u16*)w;  w += (size_t)H*8*128*N*2;
  u16*  WhT2 = (u16*)w;  w += (size_t)H*8*128*N*2;
  float* s1  = (float*)w; w += (size_t)H*TOK*4;
  float* s2  = (float*)w; w += (size_t)H*TOK*4;
  float* s1b = (float*)w; w += (size_t)H*TOK*4;
  float* s2b = (float*)w; w += (size_t)H*TOK*4;
  u32* mbits = (u32*)w;  w += (size_t)B*N*16*4;
  u32* mtbits= (u32*)w;  w += (size_t)B*N*16*4;
  float* colsumF = (float*)w; w += (size_t)B*128*4;
  float* colsumT = (float*)w; w += (size_t)B*128*4;
  u16* f1w1T = (u16*)w; w += 128*32*2;
  u16* f1w2T = (u16*)w; w += 128*128*2;
  u16* f2w1T = (u16*)w; w += 256*128*2;
  u16* f2w2T = (u16*)w; w += 128*256*2;
  u16* f3w1T = (u16*)w; w += 256*128*2;
  u16* f3w2T = (u16*)w; w += 128*256*2;
  u16* attWT = (u16*)w; w += (size_t)24*128*128*2;
  u16* outWT = (u16*)w; w += (size_t)2*128*128*2;
  u16* rshWT = (u16*)w; w += (size_t)6*128*512*2;

  prep_kernel<<<1461,256,0,stream>>>(adj, mbits, mtbits, colsumF, colsumT,
      f1w1, f1w2, f2w1, f2w2, f3w1, f3w2, attW, outW, rshW,
      f1w1T, f1w2T, f2w1T, f2w2T, f3w1T, f3w2T, attWT, outWT, rshWT);

  // FEL (6 GEMMs + 2 LN) fused + WH(att block 0) -> hA, WhT, s1, s2
  fel_kernel<<<128,256,0,stream>>>(x,
      f1w1T, f1b1, f1w2T, f1b2, f2w1T, f2b1, f2w2T, f2b2, f3w1T, f3b1, f3w2T, f3b2,
      attWT, attA, hA, WhT, s1, s2);

  // forward attention blocks 0..2
  pv32<<<H*128,512,0,stream>>>(s1, s2, mbits, WhT, hp2);
  reshwh<4><<<128,512,0,stream>>>(hp2, rshWT + 0*128*512, rshB + 0*D, hA, hB,
      attWT + (size_t)1*H*D*D, attA + (size_t)1*H*2*D, WhT, s1, s2);
  pv32<<<H*128,512,0,stream>>>(s1, s2, mbits, WhT, hp2);
  reshwh<4><<<128,512,0,stream>>>(hp2, rshWT + (size_t)1*128*512, rshB + 1*D, hB, hA,
      attWT + (size_t)2*H*D*D, attA + (size_t)2*H*2*D, WhT, s1, s2);
  pv32<<<H*128,512,0,stream>>>(s1, s2, mbits, WhT, hp2);
  reshwh<1><<<128,512,0,stream>>>(hp2, rshWT + (size_t)2*128*512, rshB + 2*D, hA, hB,
      outWT, outA, WhT, s1, s2);

  // forward output GAT + colsumF + WH(att block 3) -> hF, WhT2, s1b, s2b
  pvout<1><<<128,256,0,stream>>>(s1, s2, mbits, WhT, hF, colsumF,
      attWT + (size_t)3*H*D*D, attA + (size_t)3*H*2*D, WhT2, s1b, s2b);

  // transposed attention blocks 3..5
  pv32<<<H*128,512,0,stream>>>(s1b, s2b, mtbits, WhT2, hp2);
  reshwh<4><<<128,512,0,stream>>>(hp2, rshWT + (size_t)3*128*512, rshB + 3*D, hF, hA,
      attWT + (size_t)4*H*D*D, attA + (size_t)4*H*2*D, WhT, s1, s2);
  pv32<<<H*128,512,0,stream>>>(s1, s2, mtbits, WhT, hp2);
  reshwh<4><<<128,512,0,stream>>>(hp2, rshWT + (size_t)4*128*512, rshB + 4*D, hA, hB,
      attWT + (size_t)5*H*D*D, attA + (size_t)5*H*2*D, WhT, s1, s2);
  pv32<<<H*128,512,0,stream>>>(s1, s2, mtbits, WhT, hp2);
  reshwh<1><<<128,512,0,stream>>>(hp2, rshWT + (size_t)5*128*512, rshB + 5*D, hB, hA,
      outWT + 128*128, outA + 2*D, WhT, s1, s2);

  // transposed output GAT -> colsumT only
  pvout<0><<<128,256,0,stream>>>(s1, s2, mtbits, WhT, nullptr, colsumT,
      nullptr, nullptr, nullptr, nullptr, nullptr);

  final_kernel<<<B,2*D,0,stream>>>(colsumF, colsumT, pW, pb, (float*)d_out);
}